// Round 5
// baseline (6627.217 us; speedup 1.0000x reference)
//
#include <hip/hip_runtime.h>
#include <math.h>

static constexpr int BATCH = 64;
static constexpr int NR  = 512;    // rows per matrix (n)
static constexpr int ND  = 384;    // feature dim (N)
static constexpr int RK  = 24;     // rank
static constexpr int POLAR_ITERS = 36;
static constexpr int PNB = 32;     // tridiag panel width (U+W panels live in LDS)
static constexpr long SZC = (long)BATCH * ND * ND;      // 9,437,184 floats
static constexpr int SSTR = BATCH * RK;                 // 1536 (inverse-iter solve stride)

#define MODE_PLAIN 0
#define MODE_COV   1
#define MODE_SCALE 3
#define MODE_ACC   4

typedef _Float16 half8 __attribute__((ext_vector_type(8)));
typedef _Float16 half4 __attribute__((ext_vector_type(4)));
typedef float floatx4 __attribute__((ext_vector_type(4)));

// ---------------- batched split-fp16 MFMA GEMM (128x128 tile, 4 waves) ----------
// C = A*B (TA=0, A row-major MxK) or C = A^T*B (TA=1, A stored KxM row-major).
// fp32 emulated via 2-term fp16 split, 3 MFMA passes: lo*hi + hi*lo + hi*hi.
// sym=1: output known symmetric -> grid enumerates upper-triangle tiles only,
// epilogue mirrors off-diagonal tiles (square M=N only).
// tmask bit0/bit1: transform A/B operand on the fly: v -> 1.5*delta(r,c) - 0.5*v
// (forms the Newton-Schulz T = 1.5I - 0.5M during staging; no T buffer).
template<int TA>
__global__ __launch_bounds__(256)
void gemm_kernel(const float* __restrict__ Ag, const float* __restrict__ Bg,
                 float* __restrict__ Cg, int M, int N, int K,
                 long sA, long sB, long sC, int lda, int ldb, int ldc,
                 int mode, const float* __restrict__ scale, int sym, int tmask)
{
    const int batch = blockIdx.y;
    const int tilesN = N >> 7;            // N/128
    int ti, tj;
    if (sym) {
        int idx = blockIdx.x;
        ti = 0; int rem = tilesN;
        while (idx >= rem) { idx -= rem; ti++; rem--; }
        tj = ti + idx;
    } else {
        tj = blockIdx.x % tilesN;
        ti = blockIdx.x / tilesN;
    }
    const int n0 = tj * 128, m0 = ti * 128;
    const float* A = Ag + (long)batch * sA;
    const float* Bm = Bg + (long)batch * sB;
    float* C = Cg + (long)batch * sC;

    __shared__ _Float16 Ah[128][40], Al[128][40];
    __shared__ _Float16 Bh[128][40], Bl[128][40];

    const int tid = threadIdx.x;
    const int wave = tid >> 6, lane = tid & 63;
    const int wm0 = (wave >> 1) * 64, wn0 = (wave & 1) * 64;
    const int fm = lane & 15;       // frag row (A) / col (B,D)
    const int fq = lane >> 4;       // quad

    floatx4 acc[4][4];
#pragma unroll
    for (int i = 0; i < 4; i++)
#pragma unroll
        for (int j = 0; j < 4; j++) acc[i][j] = (floatx4){0.f, 0.f, 0.f, 0.f};

    for (int k0 = 0; k0 < K; k0 += 32) {
        if (TA == 0) {
#pragma unroll
            for (int q = 0; q < 4; q++) {
                int idx = tid + q * 256;          // 1024 float4 = 128x32
                int row = idx >> 3, kq = (idx & 7) * 4;
                float4 v = *(const float4*)&A[(long)(m0 + row) * lda + k0 + kq];
                if (tmask & 1) {
                    int gr = m0 + row, gc = k0 + kq;
                    v.x = ((gr == gc    ) ? 1.5f : 0.f) - 0.5f * v.x;
                    v.y = ((gr == gc + 1) ? 1.5f : 0.f) - 0.5f * v.y;
                    v.z = ((gr == gc + 2) ? 1.5f : 0.f) - 0.5f * v.z;
                    v.w = ((gr == gc + 3) ? 1.5f : 0.f) - 0.5f * v.w;
                }
                _Float16 h0 = (_Float16)v.x; _Float16 l0 = (_Float16)(v.x - (float)h0);
                _Float16 h1 = (_Float16)v.y; _Float16 l1 = (_Float16)(v.y - (float)h1);
                _Float16 h2 = (_Float16)v.z; _Float16 l2 = (_Float16)(v.z - (float)h2);
                _Float16 h3 = (_Float16)v.w; _Float16 l3 = (_Float16)(v.w - (float)h3);
                half4 hv, lv;
                hv[0] = h0; hv[1] = h1; hv[2] = h2; hv[3] = h3;
                lv[0] = l0; lv[1] = l1; lv[2] = l2; lv[3] = l3;
                *(half4*)&Ah[row][kq] = hv;
                *(half4*)&Al[row][kq] = lv;
            }
        } else {
            int m = tid & 127, kb = (tid >> 7) * 16;
            _Float16 hbuf[16], lbuf[16];
#pragma unroll
            for (int i = 0; i < 16; i++) {
                float v = A[(long)(k0 + kb + i) * lda + m0 + m];
                _Float16 hh = (_Float16)v;
                hbuf[i] = hh; lbuf[i] = (_Float16)(v - (float)hh);
            }
#pragma unroll
            for (int i = 0; i < 16; i += 4) {
                half4 hv, lv;
                hv[0] = hbuf[i]; hv[1] = hbuf[i + 1]; hv[2] = hbuf[i + 2]; hv[3] = hbuf[i + 3];
                lv[0] = lbuf[i]; lv[1] = lbuf[i + 1]; lv[2] = lbuf[i + 2]; lv[3] = lbuf[i + 3];
                *(half4*)&Ah[m][kb + i] = hv;
                *(half4*)&Al[m][kb + i] = lv;
            }
        }
        {
            int n = tid & 127, kb = (tid >> 7) * 16;
            _Float16 hbuf[16], lbuf[16];
#pragma unroll
            for (int i = 0; i < 16; i++) {
                float v = Bm[(long)(k0 + kb + i) * ldb + n0 + n];
                if (tmask & 2) v = (((k0 + kb + i) == (n0 + n)) ? 1.5f : 0.f) - 0.5f * v;
                _Float16 hh = (_Float16)v;
                hbuf[i] = hh; lbuf[i] = (_Float16)(v - (float)hh);
            }
#pragma unroll
            for (int i = 0; i < 16; i += 4) {
                half4 hv, lv;
                hv[0] = hbuf[i]; hv[1] = hbuf[i + 1]; hv[2] = hbuf[i + 2]; hv[3] = hbuf[i + 3];
                lv[0] = lbuf[i]; lv[1] = lbuf[i + 1]; lv[2] = lbuf[i + 2]; lv[3] = lbuf[i + 3];
                *(half4*)&Bh[n][kb + i] = hv;
                *(half4*)&Bl[n][kb + i] = lv;
            }
        }
        __syncthreads();

        half8 ah[4], alv[4], bh[4], blv[4];
#pragma unroll
        for (int mt = 0; mt < 4; mt++) {
            ah[mt]  = *(const half8*)&Ah[wm0 + mt * 16 + fm][fq * 8];
            alv[mt] = *(const half8*)&Al[wm0 + mt * 16 + fm][fq * 8];
        }
#pragma unroll
        for (int nt = 0; nt < 4; nt++) {
            bh[nt]  = *(const half8*)&Bh[wn0 + nt * 16 + fm][fq * 8];
            blv[nt] = *(const half8*)&Bl[wn0 + nt * 16 + fm][fq * 8];
        }
#pragma unroll
        for (int mt = 0; mt < 4; mt++) {
#pragma unroll
            for (int nt = 0; nt < 4; nt++) {
                floatx4 a = acc[mt][nt];
                a = __builtin_amdgcn_mfma_f32_16x16x32_f16(alv[mt], bh[nt], a, 0, 0, 0);
                a = __builtin_amdgcn_mfma_f32_16x16x32_f16(ah[mt], blv[nt], a, 0, 0, 0);
                a = __builtin_amdgcn_mfma_f32_16x16x32_f16(ah[mt], bh[nt], a, 0, 0, 0);
                acc[mt][nt] = a;
            }
        }
        __syncthreads();
    }

    float scl = 1.f;
    if (mode == MODE_SCALE) scl = 1.0f / sqrtf(scale[batch]);

#pragma unroll
    for (int mt = 0; mt < 4; mt++) {
#pragma unroll
        for (int nt = 0; nt < 4; nt++) {
            int gn = n0 + wn0 + nt * 16 + fm;
#pragma unroll
            for (int r = 0; r < 4; r++) {
                int gm = m0 + wm0 + mt * 16 + fq * 4 + r;
                float a = acc[mt][nt][r];
                float* cp = C + (long)gm * ldc + gn;
                float v = a;
                if (mode == MODE_COV)      v = a * (1.0f / 512.0f) + ((gm == gn) ? 1e-5f : 0.f);
                else if (mode == MODE_SCALE) v = a * scl;
                else if (mode == MODE_ACC) v = a + *cp;
                *cp = v;
                if (sym && ti != tj) {
                    float* cq = C + (long)gn * ldc + gm;
                    float vq = v;
                    if (mode == MODE_ACC) vq = a + *cq;
                    *cq = vq;
                }
            }
        }
    }
}

// ---------------- Frobenius norm per batch ----------------
__global__ __launch_bounds__(256)
void frob_kernel(const float* __restrict__ Cm, float* __restrict__ nrm)
{
    int b = blockIdx.x;
    const float* p = Cm + (long)b * ND * ND;
    float s = 0.f;
    for (int i = threadIdx.x; i < ND * ND; i += 256) { float v = p[i]; s += v * v; }
    __shared__ float red[256];
    red[threadIdx.x] = s; __syncthreads();
    for (int off = 128; off > 0; off >>= 1) {
        if (threadIdx.x < off) red[threadIdx.x] += red[threadIdx.x + off];
        __syncthreads();
    }
    if (threadIdx.x == 0) nrm[b] = sqrtf(red[0]);
}

// ---------------- M0 = C/normC (in place), Z1 = T0 = 1.5I - 0.5*M0 ----------------
__global__ __launch_bounds__(256)
void initns_kernel(float* __restrict__ Mb, float* __restrict__ Z, const float* __restrict__ nrm)
{
    const int total = BATCH * ND * ND;
    for (int idx = blockIdx.x * 256 + threadIdx.x; idx < total; idx += gridDim.x * 256) {
        int b = idx / (ND * ND);
        int rem = idx - b * (ND * ND);
        int r = rem / ND, c = rem - r * ND;
        float v = Mb[idx] / nrm[b];
        Mb[idx] = v;
        Z[idx] = ((r == c) ? 1.5f : 0.f) - 0.5f * v;
    }
}

// ---------------- block reduction over 768 threads ----------------
__device__ __forceinline__ float bred768(float v, float* red12, int t)
{
#pragma unroll
    for (int off = 32; off > 0; off >>= 1) v += __shfl_down(v, off);
    if ((t & 63) == 0) red12[t >> 6] = v;
    __syncthreads();
    float r = 0.f;
#pragma unroll
    for (int i = 0; i < 12; i++) r += red12[i];
    __syncthreads();
    return r;
}

// Partial row dot over the strict upper triangle: sum_{C > rAbs} A[rAbs][C]*u[C-(k+1)],
// chunk-parity h2 in {0,1} (this thread takes every other aligned float4 chunk).
__device__ __forceinline__ float sym_rowdot(const float* __restrict__ A,
                                            const float* __restrict__ u_s,
                                            int k, int r, int h2)
{
    const int rAbs = k + 1 + r;
    const float* row = A + (long)rAbs * ND;
    const int S = rAbs + 1;          // first valid column (strictly above diag)
    int base = (S & ~3) + 4 * h2;
    float accr = 0.f;
    if (base < S) {                  // partial leading chunk (only possible for h2==0)
        floatx4 a0 = *(const floatx4*)&row[base];
#pragma unroll
        for (int jj = 0; jj < 4; jj++) {
            int C = base + jj;
            if (C >= S) accr += a0[jj] * u_s[C - (k + 1)];
        }
        base += 8;
    }
    for (; base <= 372; base += 16) {
        floatx4 a0 = *(const floatx4*)&row[base];
        floatx4 a1 = *(const floatx4*)&row[base + 8];
        int ui = base - (k + 1);
        accr += a0[0] * u_s[ui]     + a0[1] * u_s[ui + 1] + a0[2] * u_s[ui + 2] + a0[3] * u_s[ui + 3]
              + a1[0] * u_s[ui + 8] + a1[1] * u_s[ui + 9] + a1[2] * u_s[ui + 10] + a1[3] * u_s[ui + 11];
    }
    for (; base <= 380; base += 8) {
        floatx4 a0 = *(const floatx4*)&row[base];
        int ui = base - (k + 1);
        accr += a0[0] * u_s[ui] + a0[1] * u_s[ui + 1] + a0[2] * u_s[ui + 2] + a0[3] * u_s[ui + 3];
    }
    return accr;
}

// ---------------- Blocked Householder tridiagonalization: panel kernel ----------
// The trailing block is exactly/near-exactly symmetric, so the matvec reads ONLY
// the upper triangle: col-pass (C >= R, masked at the diagonal) + mirror row-pass
// (C > R, contiguous row reads, rows paired p <-> m-1-p for load balance).
// Distinct footprint halves -> 8 batches/XCD fit the 4 MB L2 -> HBM fetch is
// first-touch only instead of ~10 refetches per panel.
__global__ __launch_bounds__(768)
void tridiag_panel(float* __restrict__ Gall, float* __restrict__ dA,
                   float* __restrict__ eA, float* __restrict__ tauA,
                   float* __restrict__ Wgall, int k0)
{
    int b = blockIdx.x;
    float* A = Gall + (long)b * ND * ND;
    float* Wg = Wgall + (long)b * (PNB * ND);
    float* d = dA + b * ND; float* e = eA + b * ND; float* tau = tauA + b * ND;
    const int t = threadIdx.x;
    const int h = (t >= ND) ? 1 : 0;
    const int c = t - h * ND;            // 0..383
    const int g = t % 96;                // column quad (4 cols)
    const int s = t / 96;                // row slice 0..7
    __shared__ float Ul[PNB][ND];        // 48 KiB  (u vectors, columns k+1..383)
    __shared__ float Wl[PNB][ND];        // 48 KiB  (w vectors, columns k+1..383)
    __shared__ float u_s[ND];
    __shared__ float pp4s[8][392];
    __shared__ float mirp[ND][2];        // mirror partial sums (2 per row)
    __shared__ float al[PNB], be[PNB];
    __shared__ float red12[12];
    __shared__ float s_tau;

    const int jcnt = min(PNB, ND - 2 - k0);

    for (int j = 0; j < jcnt; j++) {
        const int k = k0 + j;
        const int m = ND - 1 - k;
        float x = 0.f;
        if (!h && c < m) {
            const int kc = (k + 1) + c;
            x = A[(long)k * ND + kc];
#pragma unroll 4
            for (int l = 0; l < j; l++) {
                x -= Ul[l][k] * Wl[l][kc] + Wl[l][k] * Ul[l][kc];
            }
            u_s[c] = x;
        }
        float sigma = bred768(x * x, red12, t);
        if (t == 0) {
            float v0 = u_s[0];
            float normx = sqrtf(sigma);
            float alpha = (v0 >= 0.f) ? -normx : normx;
            float denom = sigma - alpha * v0;
            float tk = (denom > 1e-30f) ? 1.f / denom : 0.f;
            s_tau = tk;
            float diag = A[(long)k * ND + k];
            for (int l = 0; l < j; l++) diag -= 2.f * Ul[l][k] * Wl[l][k];
            e[k] = alpha; tau[k] = tk; d[k] = diag;
            u_s[0] = v0 - alpha;
        }
        __syncthreads();
        const float tk = s_tau;

        // ---- symmetric matvec, col-pass (upper triangle incl. diagonal) ----
        // aligned column window [kk4, 384); <=3 garbage front columns masked+discarded.
        const int kk4 = (k + 1) & ~3;
        const int off = (k + 1) - kk4;
        const int ncol4 = 96 - (kk4 >> 2);
        if (g < ncol4) {
            const int ri0 = (m * s) >> 3;
            const int ri1 = (m * (s + 1)) >> 3;
            const float* base = A + (long)(k + 1) * ND + kk4 + 4 * g;
            const int C0 = kk4 + 4 * g;
            const int I0 = C0 - (k + 1);       // rows i <= I0: full quad valid (Cmin >= R)
            floatx4 p4 = (floatx4){0.f, 0.f, 0.f, 0.f};
            int iEnd = I0 + 1; if (iEnd > ri1) iEnd = ri1;
            int i = ri0;
            for (; i + 8 <= iEnd; i += 8) {
                floatx4 a0 = *(const floatx4*)&base[(long)(i    ) * ND];
                floatx4 a1 = *(const floatx4*)&base[(long)(i + 1) * ND];
                floatx4 a2 = *(const floatx4*)&base[(long)(i + 2) * ND];
                floatx4 a3 = *(const floatx4*)&base[(long)(i + 3) * ND];
                floatx4 a4 = *(const floatx4*)&base[(long)(i + 4) * ND];
                floatx4 a5 = *(const floatx4*)&base[(long)(i + 5) * ND];
                floatx4 a6 = *(const floatx4*)&base[(long)(i + 6) * ND];
                floatx4 a7 = *(const floatx4*)&base[(long)(i + 7) * ND];
                p4 += a0 * u_s[i]     + a1 * u_s[i + 1] + a2 * u_s[i + 2] + a3 * u_s[i + 3]
                    + a4 * u_s[i + 4] + a5 * u_s[i + 5] + a6 * u_s[i + 6] + a7 * u_s[i + 7];
            }
            for (; i < iEnd; i++) {
                floatx4 a0 = *(const floatx4*)&base[(long)i * ND];
                p4 += a0 * u_s[i];
            }
            // boundary rows: per-element mask C >= R (covers diagonal sliver + garbage cols)
            int iBnd = I0 + 4; if (iBnd > ri1) iBnd = ri1;
            for (; i < iBnd; i++) {
                floatx4 a0 = *(const floatx4*)&base[(long)i * ND];
                const int R = k + 1 + i;
                a0[0] = (C0     >= R) ? a0[0] : 0.f;
                a0[1] = (C0 + 1 >= R) ? a0[1] : 0.f;
                a0[2] = (C0 + 2 >= R) ? a0[2] : 0.f;
                a0[3] = (C0 + 3 >= R) ? a0[3] : 0.f;
                p4 += a0 * u_s[i];
            }
            *(floatx4*)&pp4s[s][4 * g] = p4;
        }
        // ---- symmetric matvec, mirror row-pass: mirp[r] = sum_{C>R} A[R][C]*u[C-(k+1)] ----
        {
            const int p2 = t >> 1, h2 = t & 1;
            const int rB = m - 1 - p2;
            if (rB >= p2) {
                float mrA = sym_rowdot(A, u_s, k, p2, h2);
                mirp[p2][h2] = mrA;
                if (rB > p2) {
                    float mrB = sym_rowdot(A, u_s, k, rB, h2);
                    mirp[rB][h2] = mrB;
                }
            }
        }
        // wave-parallel dots from LDS panels: al[l] = w_l . u, be[l] = u_l . u
        {
            int wv = t >> 6, ln = t & 63;
            for (int l = wv; l < j; l += 12) {
                float sa = 0.f, sb = 0.f;
                const float* wrow = &Wl[l][k + 1];
                const float* urow = &Ul[l][k + 1];
                for (int i = ln; i < m; i += 64) { sa += wrow[i] * u_s[i]; sb += urow[i] * u_s[i]; }
#pragma unroll
                for (int off2 = 32; off2 > 0; off2 >>= 1) {
                    sa += __shfl_down(sa, off2); sb += __shfl_down(sb, off2);
                }
                if (ln == 0) { al[l] = sa; be[l] = sb; }
            }
        }
        __syncthreads();
        float contrib = 0.f, pc = 0.f;
        if (!h && c < m) {
            int ca = c + off;
            pc = pp4s[0][ca] + pp4s[1][ca] + pp4s[2][ca] + pp4s[3][ca]
               + pp4s[4][ca] + pp4s[5][ca] + pp4s[6][ca] + pp4s[7][ca]
               + mirp[c][0] + mirp[c][1];
            const int kc = (k + 1) + c;
#pragma unroll 4
            for (int l = 0; l < j; l++) {
                pc -= al[l] * Ul[l][kc] + be[l] * Wl[l][kc];
            }
            pc *= tk;
            contrib = u_s[c] * pc;
        }
        float dotup = bred768(contrib, red12, t);
        float sc = 0.5f * tk * dotup;
        if (!h && c < m) {
            const int kc = (k + 1) + c;
            float uv = u_s[c];
            float w = pc - sc * uv;
            Wl[j][kc] = w;
            Ul[j][kc] = uv;
            Wg[j * ND + kc] = w;
            A[(long)k * ND + kc] = uv;
        }
        __syncthreads();
    }
    if (k0 + PNB >= ND - 2 && t == 0) {
        float d0 = A[(long)(ND - 2) * ND + (ND - 2)];
        float e0 = A[(long)(ND - 2) * ND + (ND - 1)];
        float d1 = A[(long)(ND - 1) * ND + (ND - 1)];
        for (int l = 0; l < jcnt; l++) {
            float u0 = A[(long)(k0 + l) * ND + (ND - 2)];
            float u1 = A[(long)(k0 + l) * ND + (ND - 1)];
            float w0 = Wg[l * ND + (ND - 2)];
            float w1 = Wg[l * ND + (ND - 1)];
            d0 -= 2.f * u0 * w0;
            e0 -= u0 * w1 + w0 * u1;
            d1 -= 2.f * u1 * w1;
        }
        d[ND - 2] = d0; d[ND - 1] = d1; e[ND - 2] = e0;
        e[ND - 1] = 0.f; tau[ND - 2] = 0.f; tau[ND - 1] = 0.f;
    }
}

// ---------------- trailing update: A -= U W^T + W U^T (full device, 32x32 tiles) ----
__global__ __launch_bounds__(256)
void syr2k_update(float* __restrict__ Gall, const float* __restrict__ Wgall, int k0)
{
    const int k1 = k0 + PNB;
    const int tiles = (ND - k1) >> 5;
    int b = blockIdx.y;
    int ti = blockIdx.x / tiles, tj = blockIdx.x % tiles;
    int i0 = k1 + ti * 32, c0 = k1 + tj * 32;
    float* A = Gall + (long)b * ND * ND;
    const float* Wg = Wgall + (long)b * (PNB * ND);

    __shared__ float Us[PNB][36], Ws[PNB][36], Uc[PNB][36], Wc[PNB][36];
    int t = threadIdx.x;
    for (int q = t; q < PNB * 8; q += 256) {
        int l = q >> 3, c4 = (q & 7) * 4;
        *(float4*)&Us[l][c4] = *(const float4*)&A[(long)(k0 + l) * ND + i0 + c4];
        *(float4*)&Ws[l][c4] = *(const float4*)&Wg[l * ND + i0 + c4];
        *(float4*)&Uc[l][c4] = *(const float4*)&A[(long)(k0 + l) * ND + c0 + c4];
        *(float4*)&Wc[l][c4] = *(const float4*)&Wg[l * ND + c0 + c4];
    }
    __syncthreads();
    int tr = t >> 4, tc = t & 15;
    float acc00 = 0.f, acc01 = 0.f, acc10 = 0.f, acc11 = 0.f;
#pragma unroll 4
    for (int l = 0; l < PNB; l++) {
        float ua0 = Us[l][tr * 2], ua1 = Us[l][tr * 2 + 1];
        float wa0 = Ws[l][tr * 2], wa1 = Ws[l][tr * 2 + 1];
        float ub0 = Uc[l][tc * 2], ub1 = Uc[l][tc * 2 + 1];
        float wb0 = Wc[l][tc * 2], wb1 = Wc[l][tc * 2 + 1];
        acc00 += ua0 * wb0 + wa0 * ub0;
        acc01 += ua0 * wb1 + wa0 * ub1;
        acc10 += ua1 * wb0 + wa1 * ub0;
        acc11 += ua1 * wb1 + wa1 * ub1;
    }
    {
        float* r0 = &A[(long)(i0 + tr * 2) * ND + c0 + tc * 2];
        float* r1 = r0 + ND;
        float2 o0 = *(const float2*)r0, o1 = *(const float2*)r1;
        o0.x -= acc00; o0.y -= acc01;
        o1.x -= acc10; o1.y -= acc11;
        *(float2*)r0 = o0; *(float2*)r1 = o1;
    }
}

// ---------------- Sturm bisection: top-24 eigenvalues ----------------
__global__ __launch_bounds__(64)
void eigvals_kernel(const float* __restrict__ dA, const float* __restrict__ eA,
                    float* __restrict__ lamA)
{
    int b = blockIdx.x, t = threadIdx.x;   // 64 threads
    __shared__ float2 de[ND];
    __shared__ float d_s[ND], ea[ND], red[64];
    for (int i = t; i < ND; i += 64) {
        float dv = dA[b * ND + i];
        float ev = eA[b * ND + i];
        float ep = (i > 0) ? eA[b * ND + i - 1] : 0.f;
        d_s[i] = dv; ea[i] = fabsf(ev);
        de[i] = make_float2(dv, ep * ep + 1e-38f);
    }
    __syncthreads();
    float lo = 1e30f, hi = -1e30f;
    for (int i = t; i < ND; i += 64) {
        float r = ea[i] + ((i > 0) ? ea[i - 1] : 0.f);
        lo = fminf(lo, d_s[i] - r); hi = fmaxf(hi, d_s[i] + r);
    }
    red[t] = lo; __syncthreads();
    for (int off = 32; off > 0; off >>= 1) {
        if (t < off) red[t] = fminf(red[t], red[t + off]);
        __syncthreads();
    }
    lo = red[0]; __syncthreads();
    red[t] = hi; __syncthreads();
    for (int off = 32; off > 0; off >>= 1) {
        if (t < off) red[t] = fmaxf(red[t], red[t + off]);
        __syncthreads();
    }
    hi = red[0];
    if (t < RK) {
        int idx = ND - 1 - t;          // ascending index (t=0 -> largest)
        float a = lo, c = hi;
        for (int it = 0; it < 42; it++) {
            float mid = 0.5f * (a + c);
            int cnt = 0;
            float qinv = 0.f;
            for (int i = 0; i < ND; i += 8) {
                float2 v0 = de[i    ], v1 = de[i + 1], v2 = de[i + 2], v3 = de[i + 3];
                float2 v4 = de[i + 4], v5 = de[i + 5], v6 = de[i + 6], v7 = de[i + 7];
                float q;
                q = (v0.x - mid) - v0.y * qinv; cnt += (q < 0.f); qinv = __builtin_amdgcn_rcpf(q);
                q = (v1.x - mid) - v1.y * qinv; cnt += (q < 0.f); qinv = __builtin_amdgcn_rcpf(q);
                q = (v2.x - mid) - v2.y * qinv; cnt += (q < 0.f); qinv = __builtin_amdgcn_rcpf(q);
                q = (v3.x - mid) - v3.y * qinv; cnt += (q < 0.f); qinv = __builtin_amdgcn_rcpf(q);
                q = (v4.x - mid) - v4.y * qinv; cnt += (q < 0.f); qinv = __builtin_amdgcn_rcpf(q);
                q = (v5.x - mid) - v5.y * qinv; cnt += (q < 0.f); qinv = __builtin_amdgcn_rcpf(q);
                q = (v6.x - mid) - v6.y * qinv; cnt += (q < 0.f); qinv = __builtin_amdgcn_rcpf(q);
                q = (v7.x - mid) - v7.y * qinv; cnt += (q < 0.f); qinv = __builtin_amdgcn_rcpf(q);
            }
            if (cnt > idx) c = mid; else a = mid;
        }
        lamA[b * RK + t] = 0.5f * (a + c);
    }
}

// ---------------- tridiagonal inverse iteration (pivoted LU, all in LDS) ----------
__global__ __launch_bounds__(64)
void invit_kernel(const float* __restrict__ dA, const float* __restrict__ eA,
                  const float* __restrict__ lamA, float* __restrict__ scr)
{
    int b = blockIdx.x, t = threadIdx.x;
    __shared__ float d[ND], e[ND];
    __shared__ float ua[ND][RK], ub[ND][RK], uc[ND][RK];
    __shared__ float y[ND][RK];
    for (int i = t; i < ND; i += 64) { d[i] = dA[b * ND + i]; e[i] = eA[b * ND + i]; }
    __syncthreads();
    if (t >= RK) return;
    const int s = b * RK + t;
    float* yout = scr + 5L * ND * SSTR;
    const float lam = lamA[s];

    for (int pass = 0; pass < 2; pass++) {
        if (pass == 0) {
            for (int i = 0; i < ND; i++) {
                unsigned h = ((unsigned)i * 1103515245u) ^ ((unsigned)s * 747796405u);
                h *= 2654435769u; h ^= h >> 16;
                y[i][t] = ((float)(h & 0xFFFFu) * (1.f / 65536.f)) - 0.5f;
            }
        }
        float ai = d[0] - lam;
        float bc = e[0];
        float ycur = y[0][t];
        for (int i = 0; i < ND - 1; i++) {
            float sub = e[i];
            float dn = d[i + 1] - lam;
            float en = (i + 1 < ND - 1) ? e[i + 1] : 0.f;
            float ynext = y[i + 1][t];
            if (fabsf(ai) >= fabsf(sub)) {
                float aa = (ai == 0.f) ? 1e-20f : ai;
                float mlt = sub / aa;
                ua[i][t] = aa; ub[i][t] = bc; uc[i][t] = 0.f;
                y[i][t] = ycur;
                ycur = ynext - mlt * ycur;
                ai = dn - mlt * bc;
                bc = en;
            } else {
                float mlt = ai / sub;
                ua[i][t] = sub; ub[i][t] = dn; uc[i][t] = en;
                y[i][t] = ynext;
                ycur = ycur - mlt * ynext;
                ai = bc - mlt * dn;
                bc = -mlt * en;
            }
        }
        float uaN = (ai == 0.f) ? 1e-20f : ai;
        float x1 = ycur / uaN;           // x[ND-1]
        y[ND - 1][t] = x1;
        float x2 = x1;
        {
            float xm = (y[ND - 2][t] - ub[ND - 2][t] * x1) / ua[ND - 2][t];
            y[ND - 2][t] = xm; x2 = x1; x1 = xm;
        }
        for (int i = ND - 3; i >= 0; i--) {
            float xi = (y[i][t] - ub[i][t] * x1 - uc[i][t] * x2) / ua[i][t];
            y[i][t] = xi; x2 = x1; x1 = xi;
        }
        float nn = 0.f;
        for (int i = 0; i < ND; i++) { float v = y[i][t]; nn += v * v; }
        float inv = (nn > 0.f) ? 1.f / sqrtf(nn) : 0.f;
        for (int i = 0; i < ND; i++) y[i][t] *= inv;
    }
    for (int i = 0; i < ND; i++) yout[(long)i * SSTR + s] = y[i][t];
}

// ---------------- fast MGS + register-pipelined Householder back-transform ------
__global__ __launch_bounds__(384)
void orthbt_kernel(const float* __restrict__ xx, const float* __restrict__ Gall,
                   const float* __restrict__ tauA, float* __restrict__ Qout)
{
    int b = blockIdx.x, t = threadIdx.x;   // 384 threads
    __shared__ float Y[ND][RK + 1];
    __shared__ float red[ND];
    __shared__ float dts[RK];
    __shared__ float tls[ND];

    for (int j = 0; j < RK; j++) Y[t][j] = xx[(long)t * SSTR + b * RK + j];
    tls[t] = tauA[b * ND + t];
    __syncthreads();

    const int mcol = t % RK;      // 0..23
    const int msl  = t / RK;      // 0..15 (24-row slices)
    const int r0m  = msl * 24;
    for (int j = 0; j < RK; j++) {
        float pp = 0.f;
        for (int i = 0; i < 24; i++) {
            pp += Y[r0m + i][j] * Y[r0m + i][mcol];
        }
        red[mcol * 16 + msl] = pp;
        __syncthreads();
        if (t < RK) {
            float ssum = 0.f;
            for (int q = 0; q < 16; q++) ssum += red[t * 16 + q];
            dts[t] = ssum;
        }
        __syncthreads();
        float nv = dts[j];
        float inv = (nv > 1e-30f) ? (1.f / sqrtf(nv)) : 0.f;
        if (mcol > j) {
            float coef = dts[mcol] * inv * inv;
            for (int i = 0; i < 24; i++) Y[r0m + i][mcol] -= coef * Y[r0m + i][j];
        } else if (mcol == j) {
            for (int i = 0; i < 24; i++) Y[r0m + i][j] *= inv;
        }
        __syncthreads();
    }

    const int wv = t >> 6, ln = t & 63;
    float yr[4][6];
#pragma unroll
    for (int cc = 0; cc < 4; cc++)
#pragma unroll
        for (int q = 0; q < 6; q++)
            yr[cc][q] = Y[ln + 64 * q][4 * wv + cc];
    __syncthreads();

    const float* A = Gall + (long)b * ND * ND;
    float un[6];
    {
        const int k = ND - 3;
#pragma unroll
        for (int q = 0; q < 6; q++) un[q] = A[(long)k * ND + ln + 64 * q];
    }
    for (int k = ND - 3; k >= 0; k--) {
        float cu[6];
#pragma unroll
        for (int q = 0; q < 6; q++) {
            int r = ln + 64 * q;
            cu[q] = (r > k) ? un[q] : 0.f;
        }
        if (k > 0) {
#pragma unroll
            for (int q = 0; q < 6; q++) un[q] = A[(long)(k - 1) * ND + ln + 64 * q];
        }
        const float tk = tls[k];
#pragma unroll
        for (int cc = 0; cc < 4; cc++) {
            float p = 0.f;
#pragma unroll
            for (int q = 0; q < 6; q++) p += cu[q] * yr[cc][q];
#pragma unroll
            for (int off = 32; off > 0; off >>= 1) p += __shfl_xor(p, off);
            float sv = tk * p;
#pragma unroll
            for (int q = 0; q < 6; q++) yr[cc][q] -= sv * cu[q];
        }
    }

#pragma unroll
    for (int cc = 0; cc < 4; cc++)
#pragma unroll
        for (int q = 0; q < 6; q++)
            Y[ln + 64 * q][4 * wv + cc] = yr[cc][q];
    __syncthreads();
    for (int l = t; l < ND * RK; l += 384) {
        int i = l / RK, j = l - i * RK;
        Qout[(long)b * ND * RK + l] = Y[i][j];
    }
}

// ---------------- Sp = X_w @ Q ----------------
__global__ __launch_bounds__(256)
void proj_kernel(const float* __restrict__ Xw, const float* __restrict__ Qall,
                 float* __restrict__ P)
{
    int b = blockIdx.y;
    int r0 = blockIdx.x * 256;
    __shared__ float Qs[ND][RK + 1];
    const float* Q = Qall + (long)b * ND * RK;
    for (int l = threadIdx.x; l < ND * RK; l += 256) {
        int i = l / RK, j = l - i * RK;
        Qs[i][j] = Q[l];
    }
    __syncthreads();
    int r = r0 + threadIdx.x;
    const float* X = Xw + (long)b * NR * ND + (long)r * ND;
    float acc[RK];
#pragma unroll
    for (int j = 0; j < RK; j++) acc[j] = 0.f;
    for (int k = 0; k < ND; k++) {
        float xv = X[k];
#pragma unroll
        for (int j = 0; j < RK; j++) acc[j] += xv * Qs[k][j];
    }
    float* Pr = P + (long)b * NR * RK + (long)r * RK;
#pragma unroll
    for (int j = 0; j < RK; j++) Pr[j] = acc[j];
}

// ---------------- M = Sp^T Tp ; R = polar(M) via Newton-Schulz ; write R - I ----------------
__global__ __launch_bounds__(256)
void polar_kernel(const float* __restrict__ Sp, const float* __restrict__ Tp,
                  float* __restrict__ RmI)
{
    int b = blockIdx.x, t = threadIdx.x;
    __shared__ float Sb[128][RK + 1], Tb[128][RK + 1];
    __shared__ float Xm[RK][RK + 1], Bm[RK][RK + 1], Mm[RK][RK + 1];
    __shared__ float red[256];

    float accM[3] = {0.f, 0.f, 0.f};
    for (int c = 0; c < 4; c++) {
        for (int l = t; l < 128 * RK; l += 256) {
            int row = l / RK, colj = l - row * RK;
            Sb[row][colj] = Sp[(long)b * NR * RK + (long)(c * 128 + row) * RK + colj];
            Tb[row][colj] = Tp[(long)b * NR * RK + (long)(c * 128 + row) * RK + colj];
        }
        __syncthreads();
        for (int q = 0; q < 3; q++) {
            int e = t + q * 256;
            if (e < RK * RK) {
                int r = e / RK, s2 = e - r * RK;
                float a = 0.f;
                for (int n = 0; n < 128; n++) a += Sb[n][r] * Tb[n][s2];
                accM[q] += a;
            }
        }
        __syncthreads();
    }
    float ss = 0.f;
    for (int q = 0; q < 3; q++) {
        int e = t + q * 256;
        if (e < RK * RK) {
            int r = e / RK, s2 = e - r * RK;
            Mm[r][s2] = accM[q];
            ss += accM[q] * accM[q];
        }
    }
    red[t] = ss; __syncthreads();
    for (int off = 128; off > 0; off >>= 1) {
        if (t < off) red[t] += red[t + off];
        __syncthreads();
    }
    float fro = sqrtf(red[0]);
    float inv = (fro > 1e-30f) ? 1.f / fro : 0.f;
    for (int q = 0; q < 3; q++) {
        int e = t + q * 256;
        if (e < RK * RK) { int r = e / RK, s2 = e - r * RK; Xm[r][s2] = Mm[r][s2] * inv; }
    }
    __syncthreads();
    for (int it = 0; it < POLAR_ITERS; it++) {
        for (int q = 0; q < 3; q++) {
            int e = t + q * 256;
            if (e < RK * RK) {
                int r = e / RK, s2 = e - r * RK;
                float a = 0.f;
                for (int k = 0; k < RK; k++) a += Xm[k][r] * Xm[k][s2];
                Bm[r][s2] = a;
            }
        }
        __syncthreads();
        for (int q = 0; q < 3; q++) {
            int e = t + q * 256;
            if (e < RK * RK) {
                int r = e / RK, s2 = e - r * RK;
                float a = 0.f;
                for (int k = 0; k < RK; k++) a += Xm[r][k] * Bm[k][s2];
                Mm[r][s2] = 1.5f * Xm[r][s2] - 0.5f * a;
            }
        }
        __syncthreads();
        for (int q = 0; q < 3; q++) {
            int e = t + q * 256;
            if (e < RK * RK) { int r = e / RK, s2 = e - r * RK; Xm[r][s2] = Mm[r][s2]; }
        }
        __syncthreads();
    }
    for (int q = 0; q < 3; q++) {
        int e = t + q * 256;
        if (e < RK * RK) {
            int r = e / RK, s2 = e - r * RK;
            RmI[(long)b * RK * RK + e] = Xm[r][s2] - ((r == s2) ? 1.f : 0.f);
        }
    }
}

// ---------------- aligned = S_w + Sp (R-I) Q^T  (writes d_out) ----------------
__global__ __launch_bounds__(256)
void align_kernel(const float* __restrict__ Sw, const float* __restrict__ Sp,
                  const float* __restrict__ RmI, const float* __restrict__ Qall,
                  float* __restrict__ out)
{
    int b = blockIdx.y;
    int r0 = blockIdx.x * 64;
    int t = threadIdx.x;
    __shared__ float Qs[ND][RK + 1];
    __shared__ float Rm[RK][RK + 1];
    __shared__ float Ss[64][RK + 1];
    __shared__ float W[64][RK + 1];

    for (int l = t; l < ND * RK; l += 256) {
        int i = l / RK, j = l - i * RK;
        Qs[i][j] = Qall[(long)b * ND * RK + l];
    }
    for (int l = t; l < RK * RK; l += 256) {
        int i = l / RK, j = l - i * RK;
        Rm[i][j] = RmI[(long)b * RK * RK + l];
    }
    for (int l = t; l < 64 * RK; l += 256) {
        int i = l / RK, j = l - i * RK;
        Ss[i][j] = Sp[(long)b * NR * RK + (long)(r0 + i) * RK + j];
    }
    __syncthreads();
    for (int l = t; l < 64 * RK; l += 256) {
        int r = l / RK, j = l - r * RK;
        float a = 0.f;
        for (int k = 0; k < RK; k++) a += Ss[r][k] * Rm[k][j];
        W[r][j] = a;
    }
    __syncthreads();
    for (int r = 0; r < 64; r++) {
        for (int c = t; c < ND; c += 256) {
            float a = Sw[(long)b * NR * ND + (long)(r0 + r) * ND + c];
            float s2 = 0.f;
#pragma unroll
            for (int j = 0; j < RK; j++) s2 += W[r][j] * Qs[c][j];
            out[(long)b * NR * ND + (long)(r0 + r) * ND + c] = a + s2;
        }
    }
}

// ---------------- mean cosine ----------------
__global__ __launch_bounds__(256)
void cos_kernel(const float* __restrict__ out, const float* __restrict__ tgt,
                float* __restrict__ acc)
{
    int row = blockIdx.x * 4 + (threadIdx.x >> 6);
    int lane = threadIdx.x & 63;
    const float* a = out + (long)row * ND;
    const float* tg = tgt + (long)row * ND;
    float sd = 0.f, sa = 0.f, st = 0.f;
    for (int i = lane; i < ND; i += 64) {
        float av = a[i], tv = tg[i];
        sd += av * tv; sa += av * av; st += tv * tv;
    }
#pragma unroll
    for (int off = 32; off > 0; off >>= 1) {
        sd += __shfl_down(sd, off); sa += __shfl_down(sa, off); st += __shfl_down(st, off);
    }
    __shared__ float part[4];
    if (lane == 0) part[threadIdx.x >> 6] = sd / (sqrtf(sa) * sqrtf(st) + 1e-8f);
    __syncthreads();
    if (threadIdx.x == 0) atomicAdd(acc, part[0] + part[1] + part[2] + part[3]);
}

__global__ void finalize_kernel(const float* __restrict__ acc, float* __restrict__ out)
{
    out[0] = acc[0] / 32768.0f;
}

// ---------------- host ----------------
static inline void launch_gemm(int TA, const float* A, const float* Bm, float* C,
                               int M, int N, int K, long sA, long sB, long sC,
                               int lda, int ldb, int ldc, int mode,
                               const float* scale, int sym, int tmask, hipStream_t stream)
{
    int tiles;
    if (sym) { int tn = N >> 7; tiles = tn * (tn + 1) / 2; }
    else tiles = (M / 128) * (N / 128);
    dim3 grid(tiles, BATCH);
    if (TA)
        gemm_kernel<1><<<grid, dim3(256), 0, stream>>>(A, Bm, C, M, N, K, sA, sB, sC, lda, ldb, ldc, mode, scale, sym, tmask);
    else
        gemm_kernel<0><<<grid, dim3(256), 0, stream>>>(A, Bm, C, M, N, K, sA, sB, sC, lda, ldb, ldc, mode, scale, sym, tmask);
}

extern "C" void kernel_launch(void* const* d_in, const int* in_sizes, int n_in,
                              void* d_out, int out_size, void* d_ws, size_t ws_size,
                              hipStream_t stream)
{
    const float* src = (const float*)d_in[0];
    const float* tgt = (const float*)d_in[1];
    float* out = (float*)d_out;
    float* ws = (float*)d_ws;

    float* A0 = ws;
    float* A1 = ws + 1 * SZC;
    float* A2 = ws + 2 * SZC;
    float* A3 = ws + 3 * SZC;
    float* A4 = ws + 4 * SZC;
    float* S5 = ws + 5 * SZC;
    float* nrm_s = S5;
    float* nrm_t = S5 + 64;
    float* dd = S5 + 128;
    float* ee = dd + BATCH * ND;
    float* tt = ee + BATCH * ND;
    float* lam = tt + BATCH * ND;
    float* accp = lam + BATCH * RK;

    float* Tm = out;                       // square scratch in d_out
    float* SW = A0;                        // 512x384 per batch (spans A0..A1 third)
    float* TW = A0 + (long)BATCH * NR * ND;
    float* B4 = TW;                        // square scratch inside TW region (phase T only)
    float* G  = A3;
    float* scr = A4;                       // 6 * 384 * 1536
    float* Qp  = A4 + 6L * ND * SSTR;
    float* Spp = Qp + (long)BATCH * ND * RK;
    float* Tpp = Spp + (long)BATCH * NR * RK;
    float* Rp  = Tpp + (long)BATCH * NR * RK;
    float* Wg  = Rp + (long)BATCH * RK * RK;           // PNB*ND per batch
    float* yarr = scr + 5L * ND * SSTR;

    const long sXin = (long)NR * ND;     // 196608
    const long sSq  = (long)ND * ND;     // 147456

    // ==== phase S: covariance + Newton-Schulz (M-form: T formed on the fly) ====
    launch_gemm(1, src, src, A3, ND, ND, NR, sXin, sXin, sSq, ND, ND, ND, MODE_COV, nullptr, 1, 0, stream);
    frob_kernel<<<BATCH, 256, 0, stream>>>(A3, nrm_s);
    initns_kernel<<<dim3(2048), 256, 0, stream>>>(A3, A4, nrm_s);   // A3=M0, A4=Z1=T0
    launch_gemm(0, A3, A3, Tm, ND, ND, ND, sSq, sSq, sSq, ND, ND, ND, MODE_PLAIN, nullptr, 1, 3, stream);
    launch_gemm(0, A3, Tm, A0, ND, ND, ND, sSq, sSq, sSq, ND, ND, ND, MODE_PLAIN, nullptr, 1, 0, stream);
    launch_gemm(0, A0, A4, A3, ND, ND, ND, sSq, sSq, sSq, ND, ND, ND, MODE_PLAIN, nullptr, 1, 1, stream);
    launch_gemm(0, A0, A0, Tm, ND, ND, ND, sSq, sSq, sSq, ND, ND, ND, MODE_PLAIN, nullptr, 1, 3, stream);
    launch_gemm(0, A0, Tm, A4, ND, ND, ND, sSq, sSq, sSq, ND, ND, ND, MODE_PLAIN, nullptr, 1, 0, stream);
    launch_gemm(0, A4, A3, A0, ND, ND, ND, sSq, sSq, sSq, ND, ND, ND, MODE_PLAIN, nullptr, 1, 1, stream);
    launch_gemm(0, A4, A4, Tm, ND, ND, ND, sSq, sSq, sSq, ND, ND, ND, MODE_PLAIN, nullptr, 1, 3, stream);
    launch_gemm(0, A4, Tm, A3, ND, ND, ND, sSq, sSq, sSq, ND, ND, ND, MODE_PLAIN, nullptr, 1, 0, stream);
    launch_gemm(0, A3, A0, A4, ND, ND, ND, sSq, sSq, sSq, ND, ND, ND, MODE_PLAIN, nullptr, 1, 1, stream);
    launch_gemm(0, A3, A3, Tm, ND, ND, ND, sSq, sSq, sSq, ND, ND, ND, MODE_PLAIN, nullptr, 1, 3, stream);
    launch_gemm(0, A3, Tm, A0, ND, ND, ND, sSq, sSq, sSq, ND, ND, ND, MODE_PLAIN, nullptr, 1, 0, stream);
    launch_gemm(0, A0, A4, A3, ND, ND, ND, sSq, sSq, sSq, ND, ND, ND, MODE_PLAIN, nullptr, 1, 1, stream);
    launch_gemm(0, src, A3, SW, NR, ND, ND, sXin, sSq, sXin, ND, ND, ND, MODE_SCALE, nrm_s, 0, 0, stream);

    // ==== phase T (buffers: A3, A4, Tm, B4=TW region) ====
    launch_gemm(1, tgt, tgt, A3, ND, ND, NR, sXin, sXin, sSq, ND, ND, ND, MODE_COV, nullptr, 1, 0, stream);
    frob_kernel<<<BATCH, 256, 0, stream>>>(A3, nrm_t);
    initns_kernel<<<dim3(2048), 256, 0, stream>>>(A3, A4, nrm_t);   // A3=M0, A4=Z1
    launch_gemm(0, A3, A3, Tm, ND, ND, ND, sSq, sSq, sSq, ND, ND, ND, MODE_PLAIN, nullptr, 1, 3, stream);
    launch_gemm(0, A3, Tm, B4, ND, ND, ND, sSq, sSq, sSq, ND, ND, ND, MODE_PLAIN, nullptr, 1, 0, stream);
    launch_gemm(0, B4, A4, A3, ND, ND, ND, sSq, sSq, sSq, ND, ND, ND, MODE_PLAIN, nullptr, 1, 1, stream);
    launch_gemm(0, B4, B4, Tm, ND, ND, ND, sSq, sSq, sSq, ND, ND, ND, MODE_PLAIN, nullptr, 1, 3, stream);
    launch_gemm(0, B4, Tm, A4, ND, ND, ND, sSq, sSq, sSq, ND, ND, ND, MODE_PLAIN, nullptr, 1, 0, stream);
    launch_gemm(0, A4, A3, B4, ND, ND, ND, sSq, sSq, sSq, ND, ND, ND, MODE_PLAIN, nullptr, 1, 1, stream);
    launch_gemm(0, A4, A4, Tm, ND, ND, ND, sSq, sSq, sSq, ND, ND, ND, MODE_PLAIN, nullptr, 1, 3, stream);
    launch_gemm(0, A4, Tm, A3, ND, ND, ND, sSq, sSq, sSq, ND, ND, ND, MODE_PLAIN, nullptr, 1, 0, stream);
    launch_gemm(0, A3, B4, A4, ND, ND, ND, sSq, sSq, sSq, ND, ND, ND, MODE_PLAIN, nullptr, 1, 1, stream);
    launch_gemm(0, A3, A3, Tm, ND, ND, ND, sSq, sSq, sSq, ND, ND, ND, MODE_PLAIN, nullptr, 1, 3, stream);
    launch_gemm(0, A3, Tm, B4, ND, ND, ND, sSq, sSq, sSq, ND, ND, ND, MODE_PLAIN, nullptr, 1, 0, stream);
    launch_gemm(0, B4, A4, A3, ND, ND, ND, sSq, sSq, sSq, ND, ND, ND, MODE_PLAIN, nullptr, 1, 1, stream);
    launch_gemm(0, tgt, A3, TW, NR, ND, ND, sXin, sSq, sXin, ND, ND, ND, MODE_SCALE, nrm_t, 0, 0, stream);

    // ---- G = S_w^T S_w + T_w^T T_w ----
    launch_gemm(1, SW, SW, G, ND, ND, NR, sXin, sXin, sSq, ND, ND, ND, MODE_PLAIN, nullptr, 1, 0, stream);
    launch_gemm(1, TW, TW, G, ND, ND, NR, sXin, sXin, sSq, ND, ND, ND, MODE_ACC, nullptr, 1, 0, stream);
    // ---- blocked tridiagonalization: panels + full-device trailing updates ----
    for (int p = 0; p < ND / PNB; p++) {
        tridiag_panel<<<BATCH, 768, 0, stream>>>(G, dd, ee, tt, Wg, p * PNB);
        int k1 = (p + 1) * PNB;
        if (k1 < ND - 2) {
            int tiles = (ND - k1) >> 5;
            syr2k_update<<<dim3(tiles * tiles, BATCH), 256, 0, stream>>>(G, Wg, p * PNB);
        }
    }
    eigvals_kernel<<<BATCH, 64, 0, stream>>>(dd, ee, lam);
    invit_kernel<<<BATCH, 64, 0, stream>>>(dd, ee, lam, scr);
    orthbt_kernel<<<BATCH, 384, 0, stream>>>(yarr, G, tt, Qp);
    // ---- projections, Procrustes, output ----
    proj_kernel<<<dim3(2, BATCH), 256, 0, stream>>>(SW, Qp, Spp);
    proj_kernel<<<dim3(2, BATCH), 256, 0, stream>>>(TW, Qp, Tpp);
    polar_kernel<<<BATCH, 256, 0, stream>>>(Spp, Tpp, Rp);
    align_kernel<<<dim3(8, BATCH), 256, 0, stream>>>(SW, Spp, Rp, Qp, out);
    hipMemsetAsync((void*)accp, 0, 4, stream);
    cos_kernel<<<dim3(8192), 256, 0, stream>>>(out, tgt, accp);
    finalize_kernel<<<1, 1, 0, stream>>>(accp, out + (long)BATCH * NR * ND);
    (void)in_sizes; (void)n_in; (void)out_size; (void)ws_size;
}

// Round 6
// 5586.620 us; speedup vs baseline: 1.1863x; 1.1863x over previous
//
#include <hip/hip_runtime.h>
#include <math.h>

static constexpr int BATCH = 64;
static constexpr int NR  = 512;    // rows per matrix (n)
static constexpr int ND  = 384;    // feature dim (N)
static constexpr int RK  = 24;     // rank
static constexpr int POLAR_ITERS = 36;
static constexpr int PNB = 32;     // tridiag panel width (U+W panels live in LDS)
static constexpr long SZC = (long)BATCH * ND * ND;      // 9,437,184 floats
static constexpr int SSTR = BATCH * RK;                 // 1536 (inverse-iter solve stride)

#define MODE_PLAIN 0
#define MODE_COV   1
#define MODE_SCALE 3
#define MODE_ACC   4

typedef _Float16 half8 __attribute__((ext_vector_type(8)));
typedef _Float16 half4 __attribute__((ext_vector_type(4)));
typedef float floatx4 __attribute__((ext_vector_type(4)));

// ---------------- batched split-fp16 MFMA GEMM (128x128 tile, 4 waves) ----------
// C = A*B (TA=0, A row-major MxK) or C = A^T*B (TA=1, A stored KxM row-major).
// fp32 emulated via 2-term fp16 split, 3 MFMA passes.
// sym=1: upper-triangle tiles only, epilogue mirrors (square M=N).
// tmask bit0/bit1: operand transform v -> 1.5*delta - 0.5*v (NS T on the fly).
// DUAL: grid.y up to 128; batches >= 64 use the second pointer/mode set, so two
// independent 64-batch GEMMs run in one dispatch (2x WGs in flight).
// PIPELINE: next k-tile is prefetched into registers during the MFMA phase, so
// global-load latency hides under compute instead of serializing per k-step.
template<int TA>
__global__ __launch_bounds__(256)
void gemm_kernel(const float* __restrict__ Ag, const float* __restrict__ Bg,
                 float* __restrict__ Cg,
                 const float* __restrict__ Ag2, const float* __restrict__ Bg2,
                 float* __restrict__ Cg2,
                 int M, int N, int K,
                 long sA, long sB, long sC, int lda, int ldb, int ldc,
                 int mode, const float* __restrict__ scale,
                 int mode2, const float* __restrict__ scale2,
                 int sym, int tmask, int tmask2)
{
    const int by = blockIdx.y;
    int bloc;
    const float* A; const float* Bm; float* C;
    if (by < BATCH) {
        bloc = by;
        A = Ag + (long)bloc * sA; Bm = Bg + (long)bloc * sB; C = Cg + (long)bloc * sC;
    } else {
        bloc = by - BATCH;
        A = Ag2 + (long)bloc * sA; Bm = Bg2 + (long)bloc * sB; C = Cg2 + (long)bloc * sC;
        mode = mode2; scale = scale2; tmask = tmask2;
    }
    const int tilesN = N >> 7;            // N/128
    int ti, tj;
    if (sym) {
        int idx = blockIdx.x;
        ti = 0; int rem = tilesN;
        while (idx >= rem) { idx -= rem; ti++; rem--; }
        tj = ti + idx;
    } else {
        tj = blockIdx.x % tilesN;
        ti = blockIdx.x / tilesN;
    }
    const int n0 = tj * 128, m0 = ti * 128;

    __shared__ _Float16 Ah[128][40], Al[128][40];
    __shared__ _Float16 Bh[128][40], Bl[128][40];

    const int tid = threadIdx.x;
    const int wave = tid >> 6, lane = tid & 63;
    const int wm0 = (wave >> 1) * 64, wn0 = (wave & 1) * 64;
    const int fm = lane & 15;       // frag row (A) / col (B,D)
    const int fq = lane >> 4;       // quad

    floatx4 acc[4][4];
#pragma unroll
    for (int i = 0; i < 4; i++)
#pragma unroll
        for (int j = 0; j < 4; j++) acc[i][j] = (floatx4){0.f, 0.f, 0.f, 0.f};

    // ---- prefetch registers ----
    float4 pA4[4];
    float  pAs[16];
    float  pBs[16];

    // initial load (k-tile 0)
    if (TA == 0) {
#pragma unroll
        for (int q = 0; q < 4; q++) {
            int idx = tid + q * 256;
            int row = idx >> 3, kq = (idx & 7) * 4;
            pA4[q] = *(const float4*)&A[(long)(m0 + row) * lda + kq];
        }
    } else {
        int m = tid & 127, kb = (tid >> 7) * 16;
#pragma unroll
        for (int i = 0; i < 16; i++)
            pAs[i] = A[(long)(kb + i) * lda + m0 + m];
    }
    {
        int n = tid & 127, kb = (tid >> 7) * 16;
#pragma unroll
        for (int i = 0; i < 16; i++)
            pBs[i] = Bm[(long)(kb + i) * ldb + n0 + n];
    }

    for (int k0 = 0; k0 < K; k0 += 32) {
        // ---- stage prefetched regs -> LDS (identical arithmetic to unpipelined) ----
        if (TA == 0) {
#pragma unroll
            for (int q = 0; q < 4; q++) {
                int idx = tid + q * 256;          // 1024 float4 = 128x32
                int row = idx >> 3, kq = (idx & 7) * 4;
                float4 v = pA4[q];
                if (tmask & 1) {
                    int gr = m0 + row, gc = k0 + kq;
                    v.x = ((gr == gc    ) ? 1.5f : 0.f) - 0.5f * v.x;
                    v.y = ((gr == gc + 1) ? 1.5f : 0.f) - 0.5f * v.y;
                    v.z = ((gr == gc + 2) ? 1.5f : 0.f) - 0.5f * v.z;
                    v.w = ((gr == gc + 3) ? 1.5f : 0.f) - 0.5f * v.w;
                }
                _Float16 h0 = (_Float16)v.x; _Float16 l0 = (_Float16)(v.x - (float)h0);
                _Float16 h1 = (_Float16)v.y; _Float16 l1 = (_Float16)(v.y - (float)h1);
                _Float16 h2 = (_Float16)v.z; _Float16 l2 = (_Float16)(v.z - (float)h2);
                _Float16 h3 = (_Float16)v.w; _Float16 l3 = (_Float16)(v.w - (float)h3);
                half4 hv, lv;
                hv[0] = h0; hv[1] = h1; hv[2] = h2; hv[3] = h3;
                lv[0] = l0; lv[1] = l1; lv[2] = l2; lv[3] = l3;
                *(half4*)&Ah[row][kq] = hv;
                *(half4*)&Al[row][kq] = lv;
            }
        } else {
            int m = tid & 127, kb = (tid >> 7) * 16;
#pragma unroll
            for (int i = 0; i < 16; i += 4) {
                half4 hv, lv;
#pragma unroll
                for (int jj = 0; jj < 4; jj++) {
                    float v = pAs[i + jj];
                    _Float16 hh = (_Float16)v;
                    hv[jj] = hh; lv[jj] = (_Float16)(v - (float)hh);
                }
                *(half4*)&Ah[m][kb + i] = hv;
                *(half4*)&Al[m][kb + i] = lv;
            }
        }
        {
            int n = tid & 127, kb = (tid >> 7) * 16;
#pragma unroll
            for (int i = 0; i < 16; i += 4) {
                half4 hv, lv;
#pragma unroll
                for (int jj = 0; jj < 4; jj++) {
                    float v = pBs[i + jj];
                    if (tmask & 2) v = (((k0 + kb + i + jj) == (n0 + n)) ? 1.5f : 0.f) - 0.5f * v;
                    _Float16 hh = (_Float16)v;
                    hv[jj] = hh; lv[jj] = (_Float16)(v - (float)hh);
                }
                *(half4*)&Bh[n][kb + i] = hv;
                *(half4*)&Bl[n][kb + i] = lv;
            }
        }
        __syncthreads();

        half8 ah[4], alv[4], bh[4], blv[4];
#pragma unroll
        for (int mt = 0; mt < 4; mt++) {
            ah[mt]  = *(const half8*)&Ah[wm0 + mt * 16 + fm][fq * 8];
            alv[mt] = *(const half8*)&Al[wm0 + mt * 16 + fm][fq * 8];
        }
#pragma unroll
        for (int nt = 0; nt < 4; nt++) {
            bh[nt]  = *(const half8*)&Bh[wn0 + nt * 16 + fm][fq * 8];
            blv[nt] = *(const half8*)&Bl[wn0 + nt * 16 + fm][fq * 8];
        }

        // ---- prefetch next k-tile (flies during MFMA + barrier + next stage) ----
        if (k0 + 32 < K) {
            const int kn = k0 + 32;
            if (TA == 0) {
#pragma unroll
                for (int q = 0; q < 4; q++) {
                    int idx = tid + q * 256;
                    int row = idx >> 3, kq = (idx & 7) * 4;
                    pA4[q] = *(const float4*)&A[(long)(m0 + row) * lda + kn + kq];
                }
            } else {
                int m = tid & 127, kb = (tid >> 7) * 16;
#pragma unroll
                for (int i = 0; i < 16; i++)
                    pAs[i] = A[(long)(kn + kb + i) * lda + m0 + m];
            }
            {
                int n = tid & 127, kb = (tid >> 7) * 16;
#pragma unroll
                for (int i = 0; i < 16; i++)
                    pBs[i] = Bm[(long)(kn + kb + i) * ldb + n0 + n];
            }
        }

#pragma unroll
        for (int mt = 0; mt < 4; mt++) {
#pragma unroll
            for (int nt = 0; nt < 4; nt++) {
                floatx4 a = acc[mt][nt];
                a = __builtin_amdgcn_mfma_f32_16x16x32_f16(alv[mt], bh[nt], a, 0, 0, 0);
                a = __builtin_amdgcn_mfma_f32_16x16x32_f16(ah[mt], blv[nt], a, 0, 0, 0);
                a = __builtin_amdgcn_mfma_f32_16x16x32_f16(ah[mt], bh[nt], a, 0, 0, 0);
                acc[mt][nt] = a;
            }
        }
        __syncthreads();
    }

    float scl = 1.f;
    if (mode == MODE_SCALE) scl = 1.0f / sqrtf(scale[bloc]);

#pragma unroll
    for (int mt = 0; mt < 4; mt++) {
#pragma unroll
        for (int nt = 0; nt < 4; nt++) {
            int gn = n0 + wn0 + nt * 16 + fm;
#pragma unroll
            for (int r = 0; r < 4; r++) {
                int gm = m0 + wm0 + mt * 16 + fq * 4 + r;
                float a = acc[mt][nt][r];
                float* cp = C + (long)gm * ldc + gn;
                float v = a;
                if (mode == MODE_COV)      v = a * (1.0f / 512.0f) + ((gm == gn) ? 1e-5f : 0.f);
                else if (mode == MODE_SCALE) v = a * scl;
                else if (mode == MODE_ACC) v = a + *cp;
                *cp = v;
                if (sym && ti != tj) {
                    float* cq = C + (long)gn * ldc + gm;
                    float vq = v;
                    if (mode == MODE_ACC) vq = a + *cq;
                    *cq = vq;
                }
            }
        }
    }
}

// ---------------- Frobenius norm per batch (dual: 128 blocks, 2 sources) ----------
__global__ __launch_bounds__(256)
void frob_kernel(const float* __restrict__ Cm1, const float* __restrict__ Cm2,
                 float* __restrict__ nrm)
{
    int b = blockIdx.x;
    const float* p = (b < BATCH) ? (Cm1 + (long)b * ND * ND)
                                 : (Cm2 + (long)(b - BATCH) * ND * ND);
    float s = 0.f;
    for (int i = threadIdx.x; i < ND * ND; i += 256) { float v = p[i]; s += v * v; }
    __shared__ float red[256];
    red[threadIdx.x] = s; __syncthreads();
    for (int off = 128; off > 0; off >>= 1) {
        if (threadIdx.x < off) red[threadIdx.x] += red[threadIdx.x + off];
        __syncthreads();
    }
    if (threadIdx.x == 0) nrm[b] = sqrtf(red[0]);
}

// ---------------- M0 = C/normC (in place), Z1 = T0 = 1.5I - 0.5*M0 ----------------
__global__ __launch_bounds__(256)
void initns_kernel(float* __restrict__ Mb, float* __restrict__ Z, const float* __restrict__ nrm)
{
    const int total = BATCH * ND * ND;
    for (int idx = blockIdx.x * 256 + threadIdx.x; idx < total; idx += gridDim.x * 256) {
        int b = idx / (ND * ND);
        int rem = idx - b * (ND * ND);
        int r = rem / ND, c = rem - r * ND;
        float v = Mb[idx] / nrm[b];
        Mb[idx] = v;
        Z[idx] = ((r == c) ? 1.5f : 0.f) - 0.5f * v;
    }
}

// ---------------- block reduction over 768 threads ----------------
__device__ __forceinline__ float bred768(float v, float* red12, int t)
{
#pragma unroll
    for (int off = 32; off > 0; off >>= 1) v += __shfl_down(v, off);
    if ((t & 63) == 0) red12[t >> 6] = v;
    __syncthreads();
    float r = 0.f;
#pragma unroll
    for (int i = 0; i < 12; i++) r += red12[i];
    __syncthreads();
    return r;
}

// ---------------- Blocked Householder tridiagonalization: panel kernel ----------
// Round-4 version (full dwordx4 matvec). For the first two panels the host splits
// the launch into two 32-batch halves: 4 blocks/XCD x 539 KB = 2.2 MB fits the
// 4 MB per-XCD L2, so the per-step matvec streams from L2 instead of HBM.
__global__ __launch_bounds__(768)
void tridiag_panel(float* __restrict__ Gall, float* __restrict__ dA,
                   float* __restrict__ eA, float* __restrict__ tauA,
                   float* __restrict__ Wgall, int k0)
{
    int b = blockIdx.x;
    float* A = Gall + (long)b * ND * ND;
    float* Wg = Wgall + (long)b * (PNB * ND);
    float* d = dA + b * ND; float* e = eA + b * ND; float* tau = tauA + b * ND;
    const int t = threadIdx.x;
    const int h = (t >= ND) ? 1 : 0;
    const int c = t - h * ND;            // 0..383
    const int g = t % 96;                // column quad (4 cols)
    const int s = t / 96;                // row slice 0..7
    __shared__ float Ul[PNB][ND];        // 48 KiB  (u vectors, columns k+1..383)
    __shared__ float Wl[PNB][ND];        // 48 KiB  (w vectors, columns k+1..383)
    __shared__ float u_s[ND];
    __shared__ float pp4s[8][392];
    __shared__ float al[PNB], be[PNB];
    __shared__ float red12[12];
    __shared__ float s_tau;

    const int jcnt = min(PNB, ND - 2 - k0);

    for (int j = 0; j < jcnt; j++) {
        const int k = k0 + j;
        const int m = ND - 1 - k;
        float x = 0.f;
        if (!h && c < m) {
            const int kc = (k + 1) + c;
            x = A[(long)k * ND + kc];
#pragma unroll 4
            for (int l = 0; l < j; l++) {
                x -= Ul[l][k] * Wl[l][kc] + Wl[l][k] * Ul[l][kc];
            }
            u_s[c] = x;
        }
        float sigma = bred768(x * x, red12, t);
        if (t == 0) {
            float v0 = u_s[0];
            float normx = sqrtf(sigma);
            float alpha = (v0 >= 0.f) ? -normx : normx;
            float denom = sigma - alpha * v0;
            float tk = (denom > 1e-30f) ? 1.f / denom : 0.f;
            s_tau = tk;
            float diag = A[(long)k * ND + k];
            for (int l = 0; l < j; l++) diag -= 2.f * Ul[l][k] * Wl[l][k];
            e[k] = alpha; tau[k] = tk; d[k] = diag;
            u_s[0] = v0 - alpha;
        }
        __syncthreads();
        const float tk = s_tau;

        // ---- matvec over the clean trailing block: dwordx4, 8-way row split ----
        const int kk4 = (k + 1) & ~3;
        const int off = (k + 1) - kk4;
        const int ncol4 = 96 - (kk4 >> 2);
        if (g < ncol4) {
            const int ri0 = (m * s) >> 3;
            const int ri1 = (m * (s + 1)) >> 3;
            const float* base = A + (long)(k + 1) * ND + kk4 + 4 * g;
            floatx4 p4 = (floatx4){0.f, 0.f, 0.f, 0.f};
            int i = ri0;
            for (; i + 8 <= ri1; i += 8) {
                floatx4 a0 = *(const floatx4*)&base[(long)(i    ) * ND];
                floatx4 a1 = *(const floatx4*)&base[(long)(i + 1) * ND];
                floatx4 a2 = *(const floatx4*)&base[(long)(i + 2) * ND];
                floatx4 a3 = *(const floatx4*)&base[(long)(i + 3) * ND];
                floatx4 a4 = *(const floatx4*)&base[(long)(i + 4) * ND];
                floatx4 a5 = *(const floatx4*)&base[(long)(i + 5) * ND];
                floatx4 a6 = *(const floatx4*)&base[(long)(i + 6) * ND];
                floatx4 a7 = *(const floatx4*)&base[(long)(i + 7) * ND];
                p4 += a0 * u_s[i]     + a1 * u_s[i + 1] + a2 * u_s[i + 2] + a3 * u_s[i + 3]
                    + a4 * u_s[i + 4] + a5 * u_s[i + 5] + a6 * u_s[i + 6] + a7 * u_s[i + 7];
            }
            for (; i < ri1; i++) {
                floatx4 a0 = *(const floatx4*)&base[(long)i * ND];
                p4 += a0 * u_s[i];
            }
            *(floatx4*)&pp4s[s][4 * g] = p4;
        }
        // wave-parallel dots from LDS panels: al[l] = w_l . u, be[l] = u_l . u
        {
            int wv = t >> 6, ln = t & 63;
            for (int l = wv; l < j; l += 12) {
                float sa = 0.f, sb = 0.f;
                const float* wrow = &Wl[l][k + 1];
                const float* urow = &Ul[l][k + 1];
                for (int i = ln; i < m; i += 64) { sa += wrow[i] * u_s[i]; sb += urow[i] * u_s[i]; }
#pragma unroll
                for (int off2 = 32; off2 > 0; off2 >>= 1) {
                    sa += __shfl_down(sa, off2); sb += __shfl_down(sb, off2);
                }
                if (ln == 0) { al[l] = sa; be[l] = sb; }
            }
        }
        __syncthreads();
        float contrib = 0.f, pc = 0.f;
        if (!h && c < m) {
            int ca = c + off;
            pc = pp4s[0][ca] + pp4s[1][ca] + pp4s[2][ca] + pp4s[3][ca]
               + pp4s[4][ca] + pp4s[5][ca] + pp4s[6][ca] + pp4s[7][ca];
            const int kc = (k + 1) + c;
#pragma unroll 4
            for (int l = 0; l < j; l++) {
                pc -= al[l] * Ul[l][kc] + be[l] * Wl[l][kc];
            }
            pc *= tk;
            contrib = u_s[c] * pc;
        }
        float dotup = bred768(contrib, red12, t);
        float sc = 0.5f * tk * dotup;
        if (!h && c < m) {
            const int kc = (k + 1) + c;
            float uv = u_s[c];
            float w = pc - sc * uv;
            Wl[j][kc] = w;
            Ul[j][kc] = uv;
            Wg[j * ND + kc] = w;
            A[(long)k * ND + kc] = uv;
        }
        __syncthreads();
    }
    if (k0 + PNB >= ND - 2 && t == 0) {
        float d0 = A[(long)(ND - 2) * ND + (ND - 2)];
        float e0 = A[(long)(ND - 2) * ND + (ND - 1)];
        float d1 = A[(long)(ND - 1) * ND + (ND - 1)];
        for (int l = 0; l < jcnt; l++) {
            float u0 = A[(long)(k0 + l) * ND + (ND - 2)];
            float u1 = A[(long)(k0 + l) * ND + (ND - 1)];
            float w0 = Wg[l * ND + (ND - 2)];
            float w1 = Wg[l * ND + (ND - 1)];
            d0 -= 2.f * u0 * w0;
            e0 -= u0 * w1 + w0 * u1;
            d1 -= 2.f * u1 * w1;
        }
        d[ND - 2] = d0; d[ND - 1] = d1; e[ND - 2] = e0;
        e[ND - 1] = 0.f; tau[ND - 2] = 0.f; tau[ND - 1] = 0.f;
    }
}

// ---------------- trailing update: A -= U W^T + W U^T (full device, 32x32 tiles) ----
__global__ __launch_bounds__(256)
void syr2k_update(float* __restrict__ Gall, const float* __restrict__ Wgall, int k0)
{
    const int k1 = k0 + PNB;
    const int tiles = (ND - k1) >> 5;
    int b = blockIdx.y;
    int ti = blockIdx.x / tiles, tj = blockIdx.x % tiles;
    int i0 = k1 + ti * 32, c0 = k1 + tj * 32;
    float* A = Gall + (long)b * ND * ND;
    const float* Wg = Wgall + (long)b * (PNB * ND);

    __shared__ float Us[PNB][36], Ws[PNB][36], Uc[PNB][36], Wc[PNB][36];
    int t = threadIdx.x;
    for (int q = t; q < PNB * 8; q += 256) {
        int l = q >> 3, c4 = (q & 7) * 4;
        *(float4*)&Us[l][c4] = *(const float4*)&A[(long)(k0 + l) * ND + i0 + c4];
        *(float4*)&Ws[l][c4] = *(const float4*)&Wg[l * ND + i0 + c4];
        *(float4*)&Uc[l][c4] = *(const float4*)&A[(long)(k0 + l) * ND + c0 + c4];
        *(float4*)&Wc[l][c4] = *(const float4*)&Wg[l * ND + c0 + c4];
    }
    __syncthreads();
    int tr = t >> 4, tc = t & 15;
    float acc00 = 0.f, acc01 = 0.f, acc10 = 0.f, acc11 = 0.f;
#pragma unroll 4
    for (int l = 0; l < PNB; l++) {
        float ua0 = Us[l][tr * 2], ua1 = Us[l][tr * 2 + 1];
        float wa0 = Ws[l][tr * 2], wa1 = Ws[l][tr * 2 + 1];
        float ub0 = Uc[l][tc * 2], ub1 = Uc[l][tc * 2 + 1];
        float wb0 = Wc[l][tc * 2], wb1 = Wc[l][tc * 2 + 1];
        acc00 += ua0 * wb0 + wa0 * ub0;
        acc01 += ua0 * wb1 + wa0 * ub1;
        acc10 += ua1 * wb0 + wa1 * ub0;
        acc11 += ua1 * wb1 + wa1 * ub1;
    }
    {
        float* r0 = &A[(long)(i0 + tr * 2) * ND + c0 + tc * 2];
        float* r1 = r0 + ND;
        float2 o0 = *(const float2*)r0, o1 = *(const float2*)r1;
        o0.x -= acc00; o0.y -= acc01;
        o1.x -= acc10; o1.y -= acc11;
        *(float2*)r0 = o0; *(float2*)r1 = o1;
    }
}

// ---------------- Sturm bisection: top-24 eigenvalues ----------------
__global__ __launch_bounds__(64)
void eigvals_kernel(const float* __restrict__ dA, const float* __restrict__ eA,
                    float* __restrict__ lamA)
{
    int b = blockIdx.x, t = threadIdx.x;   // 64 threads
    __shared__ float2 de[ND];
    __shared__ float d_s[ND], ea[ND], red[64];
    for (int i = t; i < ND; i += 64) {
        float dv = dA[b * ND + i];
        float ev = eA[b * ND + i];
        float ep = (i > 0) ? eA[b * ND + i - 1] : 0.f;
        d_s[i] = dv; ea[i] = fabsf(ev);
        de[i] = make_float2(dv, ep * ep + 1e-38f);
    }
    __syncthreads();
    float lo = 1e30f, hi = -1e30f;
    for (int i = t; i < ND; i += 64) {
        float r = ea[i] + ((i > 0) ? ea[i - 1] : 0.f);
        lo = fminf(lo, d_s[i] - r); hi = fmaxf(hi, d_s[i] + r);
    }
    red[t] = lo; __syncthreads();
    for (int off = 32; off > 0; off >>= 1) {
        if (t < off) red[t] = fminf(red[t], red[t + off]);
        __syncthreads();
    }
    lo = red[0]; __syncthreads();
    red[t] = hi; __syncthreads();
    for (int off = 32; off > 0; off >>= 1) {
        if (t < off) red[t] = fmaxf(red[t], red[t + off]);
        __syncthreads();
    }
    hi = red[0];
    if (t < RK) {
        int idx = ND - 1 - t;          // ascending index (t=0 -> largest)
        float a = lo, c = hi;
        for (int it = 0; it < 42; it++) {
            float mid = 0.5f * (a + c);
            int cnt = 0;
            float qinv = 0.f;
            for (int i = 0; i < ND; i += 8) {
                float2 v0 = de[i    ], v1 = de[i + 1], v2 = de[i + 2], v3 = de[i + 3];
                float2 v4 = de[i + 4], v5 = de[i + 5], v6 = de[i + 6], v7 = de[i + 7];
                float q;
                q = (v0.x - mid) - v0.y * qinv; cnt += (q < 0.f); qinv = __builtin_amdgcn_rcpf(q);
                q = (v1.x - mid) - v1.y * qinv; cnt += (q < 0.f); qinv = __builtin_amdgcn_rcpf(q);
                q = (v2.x - mid) - v2.y * qinv; cnt += (q < 0.f); qinv = __builtin_amdgcn_rcpf(q);
                q = (v3.x - mid) - v3.y * qinv; cnt += (q < 0.f); qinv = __builtin_amdgcn_rcpf(q);
                q = (v4.x - mid) - v4.y * qinv; cnt += (q < 0.f); qinv = __builtin_amdgcn_rcpf(q);
                q = (v5.x - mid) - v5.y * qinv; cnt += (q < 0.f); qinv = __builtin_amdgcn_rcpf(q);
                q = (v6.x - mid) - v6.y * qinv; cnt += (q < 0.f); qinv = __builtin_amdgcn_rcpf(q);
                q = (v7.x - mid) - v7.y * qinv; cnt += (q < 0.f); qinv = __builtin_amdgcn_rcpf(q);
            }
            if (cnt > idx) c = mid; else a = mid;
        }
        lamA[b * RK + t] = 0.5f * (a + c);
    }
}

// ---------------- tridiagonal inverse iteration (pivoted LU, all in LDS) ----------
__global__ __launch_bounds__(64)
void invit_kernel(const float* __restrict__ dA, const float* __restrict__ eA,
                  const float* __restrict__ lamA, float* __restrict__ scr)
{
    int b = blockIdx.x, t = threadIdx.x;
    __shared__ float d[ND], e[ND];
    __shared__ float ua[ND][RK], ub[ND][RK], uc[ND][RK];
    __shared__ float y[ND][RK];
    for (int i = t; i < ND; i += 64) { d[i] = dA[b * ND + i]; e[i] = eA[b * ND + i]; }
    __syncthreads();
    if (t >= RK) return;
    const int s = b * RK + t;
    float* yout = scr + 5L * ND * SSTR;
    const float lam = lamA[s];

    for (int pass = 0; pass < 2; pass++) {
        if (pass == 0) {
            for (int i = 0; i < ND; i++) {
                unsigned h = ((unsigned)i * 1103515245u) ^ ((unsigned)s * 747796405u);
                h *= 2654435769u; h ^= h >> 16;
                y[i][t] = ((float)(h & 0xFFFFu) * (1.f / 65536.f)) - 0.5f;
            }
        }
        float ai = d[0] - lam;
        float bc = e[0];
        float ycur = y[0][t];
        for (int i = 0; i < ND - 1; i++) {
            float sub = e[i];
            float dn = d[i + 1] - lam;
            float en = (i + 1 < ND - 1) ? e[i + 1] : 0.f;
            float ynext = y[i + 1][t];
            if (fabsf(ai) >= fabsf(sub)) {
                float aa = (ai == 0.f) ? 1e-20f : ai;
                float mlt = sub / aa;
                ua[i][t] = aa; ub[i][t] = bc; uc[i][t] = 0.f;
                y[i][t] = ycur;
                ycur = ynext - mlt * ycur;
                ai = dn - mlt * bc;
                bc = en;
            } else {
                float mlt = ai / sub;
                ua[i][t] = sub; ub[i][t] = dn; uc[i][t] = en;
                y[i][t] = ynext;
                ycur = ycur - mlt * ynext;
                ai = bc - mlt * dn;
                bc = -mlt * en;
            }
        }
        float uaN = (ai == 0.f) ? 1e-20f : ai;
        float x1 = ycur / uaN;           // x[ND-1]
        y[ND - 1][t] = x1;
        float x2 = x1;
        {
            float xm = (y[ND - 2][t] - ub[ND - 2][t] * x1) / ua[ND - 2][t];
            y[ND - 2][t] = xm; x2 = x1; x1 = xm;
        }
        for (int i = ND - 3; i >= 0; i--) {
            float xi = (y[i][t] - ub[i][t] * x1 - uc[i][t] * x2) / ua[i][t];
            y[i][t] = xi; x2 = x1; x1 = xi;
        }
        float nn = 0.f;
        for (int i = 0; i < ND; i++) { float v = y[i][t]; nn += v * v; }
        float inv = (nn > 0.f) ? 1.f / sqrtf(nn) : 0.f;
        for (int i = 0; i < ND; i++) y[i][t] *= inv;
    }
    for (int i = 0; i < ND; i++) yout[(long)i * SSTR + s] = y[i][t];
}

// ---------------- fast MGS + register-pipelined Householder back-transform ------
__global__ __launch_bounds__(384)
void orthbt_kernel(const float* __restrict__ xx, const float* __restrict__ Gall,
                   const float* __restrict__ tauA, float* __restrict__ Qout)
{
    int b = blockIdx.x, t = threadIdx.x;   // 384 threads
    __shared__ float Y[ND][RK + 1];
    __shared__ float red[ND];
    __shared__ float dts[RK];
    __shared__ float tls[ND];

    for (int j = 0; j < RK; j++) Y[t][j] = xx[(long)t * SSTR + b * RK + j];
    tls[t] = tauA[b * ND + t];
    __syncthreads();

    const int mcol = t % RK;      // 0..23
    const int msl  = t / RK;      // 0..15 (24-row slices)
    const int r0m  = msl * 24;
    for (int j = 0; j < RK; j++) {
        float pp = 0.f;
        for (int i = 0; i < 24; i++) {
            pp += Y[r0m + i][j] * Y[r0m + i][mcol];
        }
        red[mcol * 16 + msl] = pp;
        __syncthreads();
        if (t < RK) {
            float ssum = 0.f;
            for (int q = 0; q < 16; q++) ssum += red[t * 16 + q];
            dts[t] = ssum;
        }
        __syncthreads();
        float nv = dts[j];
        float inv = (nv > 1e-30f) ? (1.f / sqrtf(nv)) : 0.f;
        if (mcol > j) {
            float coef = dts[mcol] * inv * inv;
            for (int i = 0; i < 24; i++) Y[r0m + i][mcol] -= coef * Y[r0m + i][j];
        } else if (mcol == j) {
            for (int i = 0; i < 24; i++) Y[r0m + i][j] *= inv;
        }
        __syncthreads();
    }

    const int wv = t >> 6, ln = t & 63;
    float yr[4][6];
#pragma unroll
    for (int cc = 0; cc < 4; cc++)
#pragma unroll
        for (int q = 0; q < 6; q++)
            yr[cc][q] = Y[ln + 64 * q][4 * wv + cc];
    __syncthreads();

    const float* A = Gall + (long)b * ND * ND;
    float un[6];
    {
        const int k = ND - 3;
#pragma unroll
        for (int q = 0; q < 6; q++) un[q] = A[(long)k * ND + ln + 64 * q];
    }
    for (int k = ND - 3; k >= 0; k--) {
        float cu[6];
#pragma unroll
        for (int q = 0; q < 6; q++) {
            int r = ln + 64 * q;
            cu[q] = (r > k) ? un[q] : 0.f;
        }
        if (k > 0) {
#pragma unroll
            for (int q = 0; q < 6; q++) un[q] = A[(long)(k - 1) * ND + ln + 64 * q];
        }
        const float tk = tls[k];
#pragma unroll
        for (int cc = 0; cc < 4; cc++) {
            float p = 0.f;
#pragma unroll
            for (int q = 0; q < 6; q++) p += cu[q] * yr[cc][q];
#pragma unroll
            for (int off = 32; off > 0; off >>= 1) p += __shfl_xor(p, off);
            float sv = tk * p;
#pragma unroll
            for (int q = 0; q < 6; q++) yr[cc][q] -= sv * cu[q];
        }
    }

#pragma unroll
    for (int cc = 0; cc < 4; cc++)
#pragma unroll
        for (int q = 0; q < 6; q++)
            Y[ln + 64 * q][4 * wv + cc] = yr[cc][q];
    __syncthreads();
    for (int l = t; l < ND * RK; l += 384) {
        int i = l / RK, j = l - i * RK;
        Qout[(long)b * ND * RK + l] = Y[i][j];
    }
}

// ---------------- Sp = X_w @ Q ----------------
__global__ __launch_bounds__(256)
void proj_kernel(const float* __restrict__ Xw, const float* __restrict__ Qall,
                 float* __restrict__ P)
{
    int b = blockIdx.y;
    int r0 = blockIdx.x * 256;
    __shared__ float Qs[ND][RK + 1];
    const float* Q = Qall + (long)b * ND * RK;
    for (int l = threadIdx.x; l < ND * RK; l += 256) {
        int i = l / RK, j = l - i * RK;
        Qs[i][j] = Q[l];
    }
    __syncthreads();
    int r = r0 + threadIdx.x;
    const float* X = Xw + (long)b * NR * ND + (long)r * ND;
    float acc[RK];
#pragma unroll
    for (int j = 0; j < RK; j++) acc[j] = 0.f;
    for (int k = 0; k < ND; k++) {
        float xv = X[k];
#pragma unroll
        for (int j = 0; j < RK; j++) acc[j] += xv * Qs[k][j];
    }
    float* Pr = P + (long)b * NR * RK + (long)r * RK;
#pragma unroll
    for (int j = 0; j < RK; j++) Pr[j] = acc[j];
}

// ---------------- M = Sp^T Tp ; R = polar(M) via Newton-Schulz ; write R - I ----------------
__global__ __launch_bounds__(256)
void polar_kernel(const float* __restrict__ Sp, const float* __restrict__ Tp,
                  float* __restrict__ RmI)
{
    int b = blockIdx.x, t = threadIdx.x;
    __shared__ float Sb[128][RK + 1], Tb[128][RK + 1];
    __shared__ float Xm[RK][RK + 1], Bm[RK][RK + 1], Mm[RK][RK + 1];
    __shared__ float red[256];

    float accM[3] = {0.f, 0.f, 0.f};
    for (int c = 0; c < 4; c++) {
        for (int l = t; l < 128 * RK; l += 256) {
            int row = l / RK, colj = l - row * RK;
            Sb[row][colj] = Sp[(long)b * NR * RK + (long)(c * 128 + row) * RK + colj];
            Tb[row][colj] = Tp[(long)b * NR * RK + (long)(c * 128 + row) * RK + colj];
        }
        __syncthreads();
        for (int q = 0; q < 3; q++) {
            int e = t + q * 256;
            if (e < RK * RK) {
                int r = e / RK, s2 = e - r * RK;
                float a = 0.f;
                for (int n = 0; n < 128; n++) a += Sb[n][r] * Tb[n][s2];
                accM[q] += a;
            }
        }
        __syncthreads();
    }
    float ss = 0.f;
    for (int q = 0; q < 3; q++) {
        int e = t + q * 256;
        if (e < RK * RK) {
            int r = e / RK, s2 = e - r * RK;
            Mm[r][s2] = accM[q];
            ss += accM[q] * accM[q];
        }
    }
    red[t] = ss; __syncthreads();
    for (int off = 128; off > 0; off >>= 1) {
        if (t < off) red[t] += red[t + off];
        __syncthreads();
    }
    float fro = sqrtf(red[0]);
    float inv = (fro > 1e-30f) ? 1.f / fro : 0.f;
    for (int q = 0; q < 3; q++) {
        int e = t + q * 256;
        if (e < RK * RK) { int r = e / RK, s2 = e - r * RK; Xm[r][s2] = Mm[r][s2] * inv; }
    }
    __syncthreads();
    for (int it = 0; it < POLAR_ITERS; it++) {
        for (int q = 0; q < 3; q++) {
            int e = t + q * 256;
            if (e < RK * RK) {
                int r = e / RK, s2 = e - r * RK;
                float a = 0.f;
                for (int k = 0; k < RK; k++) a += Xm[k][r] * Xm[k][s2];
                Bm[r][s2] = a;
            }
        }
        __syncthreads();
        for (int q = 0; q < 3; q++) {
            int e = t + q * 256;
            if (e < RK * RK) {
                int r = e / RK, s2 = e - r * RK;
                float a = 0.f;
                for (int k = 0; k < RK; k++) a += Xm[r][k] * Bm[k][s2];
                Mm[r][s2] = 1.5f * Xm[r][s2] - 0.5f * a;
            }
        }
        __syncthreads();
        for (int q = 0; q < 3; q++) {
            int e = t + q * 256;
            if (e < RK * RK) { int r = e / RK, s2 = e - r * RK; Xm[r][s2] = Mm[r][s2]; }
        }
        __syncthreads();
    }
    for (int q = 0; q < 3; q++) {
        int e = t + q * 256;
        if (e < RK * RK) {
            int r = e / RK, s2 = e - r * RK;
            RmI[(long)b * RK * RK + e] = Xm[r][s2] - ((r == s2) ? 1.f : 0.f);
        }
    }
}

// ---------------- aligned = S_w + Sp (R-I) Q^T  (writes d_out) ----------------
__global__ __launch_bounds__(256)
void align_kernel(const float* __restrict__ Sw, const float* __restrict__ Sp,
                  const float* __restrict__ RmI, const float* __restrict__ Qall,
                  float* __restrict__ out)
{
    int b = blockIdx.y;
    int r0 = blockIdx.x * 64;
    int t = threadIdx.x;
    __shared__ float Qs[ND][RK + 1];
    __shared__ float Rm[RK][RK + 1];
    __shared__ float Ss[64][RK + 1];
    __shared__ float W[64][RK + 1];

    for (int l = t; l < ND * RK; l += 256) {
        int i = l / RK, j = l - i * RK;
        Qs[i][j] = Qall[(long)b * ND * RK + l];
    }
    for (int l = t; l < RK * RK; l += 256) {
        int i = l / RK, j = l - i * RK;
        Rm[i][j] = RmI[(long)b * RK * RK + l];
    }
    for (int l = t; l < 64 * RK; l += 256) {
        int i = l / RK, j = l - i * RK;
        Ss[i][j] = Sp[(long)b * NR * RK + (long)(r0 + i) * RK + j];
    }
    __syncthreads();
    for (int l = t; l < 64 * RK; l += 256) {
        int r = l / RK, j = l - r * RK;
        float a = 0.f;
        for (int k = 0; k < RK; k++) a += Ss[r][k] * Rm[k][j];
        W[r][j] = a;
    }
    __syncthreads();
    for (int r = 0; r < 64; r++) {
        for (int c = t; c < ND; c += 256) {
            float a = Sw[(long)b * NR * ND + (long)(r0 + r) * ND + c];
            float s2 = 0.f;
#pragma unroll
            for (int j = 0; j < RK; j++) s2 += W[r][j] * Qs[c][j];
            out[(long)b * NR * ND + (long)(r0 + r) * ND + c] = a + s2;
        }
    }
}

// ---------------- mean cosine ----------------
__global__ __launch_bounds__(256)
void cos_kernel(const float* __restrict__ out, const float* __restrict__ tgt,
                float* __restrict__ acc)
{
    int row = blockIdx.x * 4 + (threadIdx.x >> 6);
    int lane = threadIdx.x & 63;
    const float* a = out + (long)row * ND;
    const float* tg = tgt + (long)row * ND;
    float sd = 0.f, sa = 0.f, st = 0.f;
    for (int i = lane; i < ND; i += 64) {
        float av = a[i], tv = tg[i];
        sd += av * tv; sa += av * av; st += tv * tv;
    }
#pragma unroll
    for (int off = 32; off > 0; off >>= 1) {
        sd += __shfl_down(sd, off); sa += __shfl_down(sa, off); st += __shfl_down(st, off);
    }
    __shared__ float part[4];
    if (lane == 0) part[threadIdx.x >> 6] = sd / (sqrtf(sa) * sqrtf(st) + 1e-8f);
    __syncthreads();
    if (threadIdx.x == 0) atomicAdd(acc, part[0] + part[1] + part[2] + part[3]);
}

__global__ void finalize_kernel(const float* __restrict__ acc, float* __restrict__ out)
{
    out[0] = acc[0] / 32768.0f;
}

// ---------------- host ----------------
static inline void launch_gd(int TA,
    const float* A1p, const float* B1p, float* C1p, int mode1, const float* sc1, int tm1,
    const float* A2p, const float* B2p, float* C2p, int mode2, const float* sc2, int tm2,
    int nbat, int M, int N, int K, long sA, long sB, long sC,
    int lda, int ldb, int ldc, int sym, hipStream_t stream)
{
    int tiles;
    if (sym) { int tn = N >> 7; tiles = tn * (tn + 1) / 2; }
    else tiles = (M / 128) * (N / 128);
    dim3 grid(tiles, nbat);
    if (TA)
        gemm_kernel<1><<<grid, dim3(256), 0, stream>>>(A1p, B1p, C1p, A2p, B2p, C2p,
            M, N, K, sA, sB, sC, lda, ldb, ldc, mode1, sc1, mode2, sc2, sym, tm1, tm2);
    else
        gemm_kernel<0><<<grid, dim3(256), 0, stream>>>(A1p, B1p, C1p, A2p, B2p, C2p,
            M, N, K, sA, sB, sC, lda, ldb, ldc, mode1, sc1, mode2, sc2, sym, tm1, tm2);
}

static inline void launch_g1(int TA, const float* Ap, const float* Bp, float* Cp,
    int mode, const float* sc, int tm,
    int M, int N, int K, long sA, long sB, long sC,
    int lda, int ldb, int ldc, int sym, hipStream_t stream)
{
    launch_gd(TA, Ap, Bp, Cp, mode, sc, tm, Ap, Bp, Cp, mode, sc, tm,
              BATCH, M, N, K, sA, sB, sC, lda, ldb, ldc, sym, stream);
}

extern "C" void kernel_launch(void* const* d_in, const int* in_sizes, int n_in,
                              void* d_out, int out_size, void* d_ws, size_t ws_size,
                              hipStream_t stream)
{
    const float* src = (const float*)d_in[0];
    const float* tgt = (const float*)d_in[1];
    float* out = (float*)d_out;
    float* ws = (float*)d_ws;

    float* A0 = ws;
    float* A3 = ws + 3 * SZC;
    float* A4 = ws + 4 * SZC;
    float* S5 = ws + 5 * SZC;
    float* nrm_s = S5;                     // nrm_t = nrm_s + 64 (contiguous for dual frob)
    float* nrm_t = S5 + 64;
    float* dd = S5 + 128;
    float* ee = dd + BATCH * ND;
    float* tt = ee + BATCH * ND;
    float* lam = tt + BATCH * ND;
    float* accp = lam + BATCH * RK;

    float* Tm = out;                       // square scratch in d_out
    float* SW = A0;                        // [0, 12.58M) rect
    float* TW = A0 + (long)BATCH * NR * ND;// [12.58M, 25.2M) rect
    float* C1 = TW;                        // square M_t buffer (dead before TW written)
    float* G  = A3;
    float* scr = A4;                       // 6 * 384 * 1536
    float* Qp  = A4 + 6L * ND * SSTR;
    float* Spp = Qp + (long)BATCH * ND * RK;
    float* Tpp = Spp + (long)BATCH * NR * RK;
    float* Rp  = Tpp + (long)BATCH * NR * RK;
    float* Wg  = Rp + (long)BATCH * RK * RK;           // PNB*ND per batch
    float* yarr = scr + 5L * ND * SSTR;

    const long sXin = (long)NR * ND;     // 196608
    const long sSq  = (long)ND * ND;     // 147456

    // ==== dual covariance: cov_s -> A3, cov_t -> C1 ====
    launch_gd(1, src, src, A3, MODE_COV, nullptr, 0,
                 tgt, tgt, C1, MODE_COV, nullptr, 0,
              128, ND, ND, NR, sXin, sXin, sSq, ND, ND, ND, 1, stream);
    frob_kernel<<<dim3(128), 256, 0, stream>>>(A3, C1, nrm_s);

    // ==== phase S (M-track rotation A3 -> A0 -> A4 -> A3 -> A0; U scratch Tm) ====
    initns_kernel<<<dim3(2048), 256, 0, stream>>>(A3, A4, nrm_s);   // M0=A3, Z1=A4
    // iter1: U0 -> Tm ; M1 -> A0
    launch_g1(0, A3, A3, Tm, MODE_PLAIN, nullptr, 3, ND, ND, ND, sSq, sSq, sSq, ND, ND, ND, 1, stream);
    launch_g1(0, A3, Tm, A0, MODE_PLAIN, nullptr, 0, ND, ND, ND, sSq, sSq, sSq, ND, ND, ND, 1, stream);
    // iter2: dual{Z2 = T(M1)*Z1 -> A3 ; U1 -> Tm} ; M2 -> A4
    launch_gd(0, A0, A4, A3, MODE_PLAIN, nullptr, 1,
                 A0, A0, Tm, MODE_PLAIN, nullptr, 3,
              128, ND, ND, ND, sSq, sSq, sSq, ND, ND, ND, 1, stream);
    launch_g1(0, A0, Tm, A4, MODE_PLAIN, nullptr, 0, ND, ND, ND, sSq, sSq, sSq, ND, ND, ND, 1, stream);
    // iter3: dual{Z3 -> A0 ; U2 -> Tm} ; M3 -> A3
    launch_gd(0, A4, A3, A0, MODE_PLAIN, nullptr, 1,
                 A4, A4, Tm, MODE_PLAIN, nullptr, 3,
              128, ND, ND, ND, sSq, sSq, sSq, ND, ND, ND, 1, stream);
    launch_g1(0, A4, Tm, A3, MODE_PLAIN, nullptr, 0, ND, ND, ND, sSq, sSq, sSq, ND, ND, ND, 1, stream);
    // iter4: dual{Z4 -> A4 ; U3 -> Tm} ; M4 -> A0
    launch_gd(0, A3, A0, A4, MODE_PLAIN, nullptr, 1,
                 A3, A3, Tm, MODE_PLAIN, nullptr, 3,
              128, ND, ND, ND, sSq, sSq, sSq, ND, ND, ND, 1, stream);
    launch_g1(0, A3, Tm, A0, MODE_PLAIN, nullptr, 0, ND, ND, ND, sSq, sSq, sSq, ND, ND, ND, 1, stream);
    // iter5: Z5_s = T(M4)*Z4 -> A3
    launch_g1(0, A0, A4, A3, MODE_PLAIN, nullptr, 1, ND, ND, ND, sSq, sSq, sSq, ND, ND, ND, 1, stream);

    // ==== phase T (M-track C1 -> A4 -> A0 -> C1 -> A4; Z-track A0/C1/A4; U scratch Tm) ====
    initns_kernel<<<dim3(2048), 256, 0, stream>>>(C1, A0, nrm_t);   // M0=C1, Z1=A0
    // iter1
    launch_g1(0, C1, C1, Tm, MODE_PLAIN, nullptr, 3, ND, ND, ND, sSq, sSq, sSq, ND, ND, ND, 1, stream);
    launch_g1(0, C1, Tm, A4, MODE_PLAIN, nullptr, 0, ND, ND, ND, sSq, sSq, sSq, ND, ND, ND, 1, stream);
    // iter2: dual{Z2 -> C1 ; U1 -> Tm} ; M2 -> A0
    launch_gd(0, A4, A0, C1, MODE_PLAIN, nullptr, 1,
                 A4, A4, Tm, MODE_PLAIN, nullptr, 3,
              128, ND, ND, ND, sSq, sSq, sSq, ND, ND, ND, 1, stream);
    launch_g1(0, A4, Tm, A0, MODE_PLAIN, nullptr, 0, ND, ND, ND, sSq, sSq, sSq, ND, ND, ND, 1, stream);
    // iter3: dual{Z3 -> A4 ; U2 -> Tm} ; M3 -> C1
    launch_gd(0, A0, C1, A4, MODE_PLAIN, nullptr, 1,
                 A0, A0, Tm, MODE_PLAIN, nullptr, 3,
              128, ND, ND, ND, sSq, sSq, sSq, ND, ND, ND, 1, stream);
    launch_g1(0, A0, Tm, C1, MODE_PLAIN, nullptr, 0, ND, ND, ND, sSq, sSq, sSq, ND, ND, ND, 1, stream);
    // iter4: dual{Z4 -> A0 ; U3 -> Tm} ; M4 -> A4
    launch_gd(0, C1, A4, A0, MODE_PLAIN, nullptr, 1,
                 C1, C1, Tm, MODE_PLAIN, nullptr, 3,
              128, ND, ND, ND, sSq, sSq, sSq, ND, ND, ND, 1, stream);
    launch_g1(0, C1, Tm, A4, MODE_PLAIN, nullptr, 0, ND, ND, ND, sSq, sSq, sSq, ND, ND, ND, 1, stream);
    // iter5: Z5_t = T(M4)*Z4 -> Tm   (survives into whiten; C1 region now dead)
    launch_g1(0, A4, A0, Tm, MODE_PLAIN, nullptr, 1, ND, ND, ND, sSq, sSq, sSq, ND, ND, ND, 1, stream);

    // ==== dual whiten: SW = src*Z5_s/sqrt(nrm_s), TW = tgt*Z5_t/sqrt(nrm_t) ====
    launch_gd(0, src, A3, SW, MODE_SCALE, nrm_s, 0,
                 tgt, Tm, TW, MODE_SCALE, nrm_t, 0,
              128, NR, ND, ND, sXin, sSq, sXin, ND, ND, ND, 0, stream);

    // ---- G = S_w^T S_w + T_w^T T_w ----
    launch_g1(1, SW, SW, G, MODE_PLAIN, nullptr, 0, ND, ND, NR, sXin, sXin, sSq, ND, ND, ND, 1, stream);
    launch_g1(1, TW, TW, G, MODE_ACC,   nullptr, 0, ND, ND, NR, sXin, sXin, sSq, ND, ND, ND, 1, stream);

    // ---- blocked tridiagonalization: panels + full-device trailing updates ----
    // p=0,1: split into two 32-batch halves -> 4 blocks/XCD, trailing block fits
    // per-XCD L2 (2.2 MB < 4 MB) -> matvec streams from L2 instead of HBM.
    for (int p = 0; p < ND / PNB; p++) {
        int k0 = p * PNB;
        if (p < 2) {
            tridiag_panel<<<dim3(32), 768, 0, stream>>>(G, dd, ee, tt, Wg, k0);
            tridiag_panel<<<dim3(32), 768, 0, stream>>>(G + 32L * sSq, dd + 32 * ND,
                ee + 32 * ND, tt + 32 * ND, Wg + 32L * PNB * ND, k0);
        } else {
            tridiag_panel<<<dim3(BATCH), 768, 0, stream>>>(G, dd, ee, tt, Wg, k0);
        }
        int k1 = (p + 1) * PNB;
        if (k1 < ND - 2) {
            int tiles = (ND - k1) >> 5;
            syr2k_update<<<dim3(tiles * tiles, BATCH), 256, 0, stream>>>(G, Wg, k0);
        }
    }
    eigvals_kernel<<<BATCH, 64, 0, stream>>>(dd, ee, lam);
    invit_kernel<<<BATCH, 64, 0, stream>>>(dd, ee, lam, scr);
    orthbt_kernel<<<BATCH, 384, 0, stream>>>(yarr, G, tt, Qp);
    // ---- projections, Procrustes, output ----
    proj_kernel<<<dim3(2, BATCH), 256, 0, stream>>>(SW, Qp, Spp);
    proj_kernel<<<dim3(2, BATCH), 256, 0, stream>>>(TW, Qp, Tpp);
    polar_kernel<<<BATCH, 256, 0, stream>>>(Spp, Tpp, Rp);
    align_kernel<<<dim3(8, BATCH), 256, 0, stream>>>(SW, Spp, Rp, Qp, out);
    hipMemsetAsync((void*)accp, 0, 4, stream);
    cos_kernel<<<dim3(8192), 256, 0, stream>>>(out, tgt, accp);
    finalize_kernel<<<1, 1, 0, stream>>>(accp, out + (long)BATCH * NR * ND);
    (void)in_sizes; (void)n_in; (void)out_size; (void)ws_size;
}

// Round 7
// 5356.437 us; speedup vs baseline: 1.2372x; 1.0430x over previous
//
#include <hip/hip_runtime.h>
#include <math.h>

static constexpr int BATCH = 64;
static constexpr int NR  = 512;    // rows per matrix (n)
static constexpr int ND  = 384;    // feature dim (N)
static constexpr int RK  = 24;     // rank
static constexpr int POLAR_ITERS = 36;
static constexpr int PNB = 32;     // tridiag panel width (U+W panels live in LDS)
static constexpr long SZC = (long)BATCH * ND * ND;      // 9,437,184 floats
static constexpr int SSTR = BATCH * RK;                 // 1536 (inverse-iter solve stride)

#define MODE_PLAIN 0
#define MODE_COV   1
#define MODE_SCALE 3
#define MODE_ACC   4

typedef _Float16 half8 __attribute__((ext_vector_type(8)));
typedef _Float16 half4 __attribute__((ext_vector_type(4)));
typedef float floatx4 __attribute__((ext_vector_type(4)));

// ---------------- batched split-fp16 MFMA GEMM (128x128 tile, 4 waves) ----------
// C = A*B (TA=0, A row-major MxK) or C = A^T*B (TA=1, A stored KxM row-major).
// fp32 emulated via 2-term fp16 split, 3 MFMA passes.
// sym=1: upper-triangle tiles only, epilogue mirrors (square M=N).
// tmask bit0/bit1: operand transform v -> 1.5*delta - 0.5*v (NS T on the fly).
// DUAL: grid.y up to 128; batches >= 64 use the second pointer/mode set.
// PIPELINE: next k-tile prefetched into registers during the MFMA phase.
template<int TA>
__global__ __launch_bounds__(256)
void gemm_kernel(const float* __restrict__ Ag, const float* __restrict__ Bg,
                 float* __restrict__ Cg,
                 const float* __restrict__ Ag2, const float* __restrict__ Bg2,
                 float* __restrict__ Cg2,
                 int M, int N, int K,
                 long sA, long sB, long sC, int lda, int ldb, int ldc,
                 int mode, const float* __restrict__ scale,
                 int mode2, const float* __restrict__ scale2,
                 int sym, int tmask, int tmask2)
{
    const int by = blockIdx.y;
    int bloc;
    const float* A; const float* Bm; float* C;
    if (by < BATCH) {
        bloc = by;
        A = Ag + (long)bloc * sA; Bm = Bg + (long)bloc * sB; C = Cg + (long)bloc * sC;
    } else {
        bloc = by - BATCH;
        A = Ag2 + (long)bloc * sA; Bm = Bg2 + (long)bloc * sB; C = Cg2 + (long)bloc * sC;
        mode = mode2; scale = scale2; tmask = tmask2;
    }
    const int tilesN = N >> 7;            // N/128
    int ti, tj;
    if (sym) {
        int idx = blockIdx.x;
        ti = 0; int rem = tilesN;
        while (idx >= rem) { idx -= rem; ti++; rem--; }
        tj = ti + idx;
    } else {
        tj = blockIdx.x % tilesN;
        ti = blockIdx.x / tilesN;
    }
    const int n0 = tj * 128, m0 = ti * 128;

    __shared__ _Float16 Ah[128][40], Al[128][40];
    __shared__ _Float16 Bh[128][40], Bl[128][40];

    const int tid = threadIdx.x;
    const int wave = tid >> 6, lane = tid & 63;
    const int wm0 = (wave >> 1) * 64, wn0 = (wave & 1) * 64;
    const int fm = lane & 15;       // frag row (A) / col (B,D)
    const int fq = lane >> 4;       // quad

    floatx4 acc[4][4];
#pragma unroll
    for (int i = 0; i < 4; i++)
#pragma unroll
        for (int j = 0; j < 4; j++) acc[i][j] = (floatx4){0.f, 0.f, 0.f, 0.f};

    // ---- prefetch registers ----
    float4 pA4[4];
    float  pAs[16];
    float  pBs[16];

    // initial load (k-tile 0)
    if (TA == 0) {
#pragma unroll
        for (int q = 0; q < 4; q++) {
            int idx = tid + q * 256;
            int row = idx >> 3, kq = (idx & 7) * 4;
            pA4[q] = *(const float4*)&A[(long)(m0 + row) * lda + kq];
        }
    } else {
        int m = tid & 127, kb = (tid >> 7) * 16;
#pragma unroll
        for (int i = 0; i < 16; i++)
            pAs[i] = A[(long)(kb + i) * lda + m0 + m];
    }
    {
        int n = tid & 127, kb = (tid >> 7) * 16;
#pragma unroll
        for (int i = 0; i < 16; i++)
            pBs[i] = Bm[(long)(kb + i) * ldb + n0 + n];
    }

    for (int k0 = 0; k0 < K; k0 += 32) {
        // ---- stage prefetched regs -> LDS (identical arithmetic to unpipelined) ----
        if (TA == 0) {
#pragma unroll
            for (int q = 0; q < 4; q++) {
                int idx = tid + q * 256;          // 1024 float4 = 128x32
                int row = idx >> 3, kq = (idx & 7) * 4;
                float4 v = pA4[q];
                if (tmask & 1) {
                    int gr = m0 + row, gc = k0 + kq;
                    v.x = ((gr == gc    ) ? 1.5f : 0.f) - 0.5f * v.x;
                    v.y = ((gr == gc + 1) ? 1.5f : 0.f) - 0.5f * v.y;
                    v.z = ((gr == gc + 2) ? 1.5f : 0.f) - 0.5f * v.z;
                    v.w = ((gr == gc + 3) ? 1.5f : 0.f) - 0.5f * v.w;
                }
                _Float16 h0 = (_Float16)v.x; _Float16 l0 = (_Float16)(v.x - (float)h0);
                _Float16 h1 = (_Float16)v.y; _Float16 l1 = (_Float16)(v.y - (float)h1);
                _Float16 h2 = (_Float16)v.z; _Float16 l2 = (_Float16)(v.z - (float)h2);
                _Float16 h3 = (_Float16)v.w; _Float16 l3 = (_Float16)(v.w - (float)h3);
                half4 hv, lv;
                hv[0] = h0; hv[1] = h1; hv[2] = h2; hv[3] = h3;
                lv[0] = l0; lv[1] = l1; lv[2] = l2; lv[3] = l3;
                *(half4*)&Ah[row][kq] = hv;
                *(half4*)&Al[row][kq] = lv;
            }
        } else {
            int m = tid & 127, kb = (tid >> 7) * 16;
#pragma unroll
            for (int i = 0; i < 16; i += 4) {
                half4 hv, lv;
#pragma unroll
                for (int jj = 0; jj < 4; jj++) {
                    float v = pAs[i + jj];
                    _Float16 hh = (_Float16)v;
                    hv[jj] = hh; lv[jj] = (_Float16)(v - (float)hh);
                }
                *(half4*)&Ah[m][kb + i] = hv;
                *(half4*)&Al[m][kb + i] = lv;
            }
        }
        {
            int n = tid & 127, kb = (tid >> 7) * 16;
#pragma unroll
            for (int i = 0; i < 16; i += 4) {
                half4 hv, lv;
#pragma unroll
                for (int jj = 0; jj < 4; jj++) {
                    float v = pBs[i + jj];
                    if (tmask & 2) v = (((k0 + kb + i + jj) == (n0 + n)) ? 1.5f : 0.f) - 0.5f * v;
                    _Float16 hh = (_Float16)v;
                    hv[jj] = hh; lv[jj] = (_Float16)(v - (float)hh);
                }
                *(half4*)&Bh[n][kb + i] = hv;
                *(half4*)&Bl[n][kb + i] = lv;
            }
        }
        __syncthreads();

        half8 ah[4], alv[4], bh[4], blv[4];
#pragma unroll
        for (int mt = 0; mt < 4; mt++) {
            ah[mt]  = *(const half8*)&Ah[wm0 + mt * 16 + fm][fq * 8];
            alv[mt] = *(const half8*)&Al[wm0 + mt * 16 + fm][fq * 8];
        }
#pragma unroll
        for (int nt = 0; nt < 4; nt++) {
            bh[nt]  = *(const half8*)&Bh[wn0 + nt * 16 + fm][fq * 8];
            blv[nt] = *(const half8*)&Bl[wn0 + nt * 16 + fm][fq * 8];
        }

        // ---- prefetch next k-tile (flies during MFMA + barrier + next stage) ----
        if (k0 + 32 < K) {
            const int kn = k0 + 32;
            if (TA == 0) {
#pragma unroll
                for (int q = 0; q < 4; q++) {
                    int idx = tid + q * 256;
                    int row = idx >> 3, kq = (idx & 7) * 4;
                    pA4[q] = *(const float4*)&A[(long)(m0 + row) * lda + kn + kq];
                }
            } else {
                int m = tid & 127, kb = (tid >> 7) * 16;
#pragma unroll
                for (int i = 0; i < 16; i++)
                    pAs[i] = A[(long)(kn + kb + i) * lda + m0 + m];
            }
            {
                int n = tid & 127, kb = (tid >> 7) * 16;
#pragma unroll
                for (int i = 0; i < 16; i++)
                    pBs[i] = Bm[(long)(kn + kb + i) * ldb + n0 + n];
            }
        }

#pragma unroll
        for (int mt = 0; mt < 4; mt++) {
#pragma unroll
            for (int nt = 0; nt < 4; nt++) {
                floatx4 a = acc[mt][nt];
                a = __builtin_amdgcn_mfma_f32_16x16x32_f16(alv[mt], bh[nt], a, 0, 0, 0);
                a = __builtin_amdgcn_mfma_f32_16x16x32_f16(ah[mt], blv[nt], a, 0, 0, 0);
                a = __builtin_amdgcn_mfma_f32_16x16x32_f16(ah[mt], bh[nt], a, 0, 0, 0);
                acc[mt][nt] = a;
            }
        }
        __syncthreads();
    }

    float scl = 1.f;
    if (mode == MODE_SCALE) scl = 1.0f / sqrtf(scale[bloc]);

#pragma unroll
    for (int mt = 0; mt < 4; mt++) {
#pragma unroll
        for (int nt = 0; nt < 4; nt++) {
            int gn = n0 + wn0 + nt * 16 + fm;
#pragma unroll
            for (int r = 0; r < 4; r++) {
                int gm = m0 + wm0 + mt * 16 + fq * 4 + r;
                float a = acc[mt][nt][r];
                float* cp = C + (long)gm * ldc + gn;
                float v = a;
                if (mode == MODE_COV)      v = a * (1.0f / 512.0f) + ((gm == gn) ? 1e-5f : 0.f);
                else if (mode == MODE_SCALE) v = a * scl;
                else if (mode == MODE_ACC) v = a + *cp;
                *cp = v;
                if (sym && ti != tj) {
                    float* cq = C + (long)gn * ldc + gm;
                    float vq = v;
                    if (mode == MODE_ACC) vq = a + *cq;
                    *cq = vq;
                }
            }
        }
    }
}

// ---------------- Frobenius norm per batch (dual: 128 blocks, 2 sources) ----------
__global__ __launch_bounds__(256)
void frob_kernel(const float* __restrict__ Cm1, const float* __restrict__ Cm2,
                 float* __restrict__ nrm)
{
    int b = blockIdx.x;
    const float* p = (b < BATCH) ? (Cm1 + (long)b * ND * ND)
                                 : (Cm2 + (long)(b - BATCH) * ND * ND);
    float s = 0.f;
    for (int i = threadIdx.x; i < ND * ND; i += 256) { float v = p[i]; s += v * v; }
    __shared__ float red[256];
    red[threadIdx.x] = s; __syncthreads();
    for (int off = 128; off > 0; off >>= 1) {
        if (threadIdx.x < off) red[threadIdx.x] += red[threadIdx.x + off];
        __syncthreads();
    }
    if (threadIdx.x == 0) nrm[b] = sqrtf(red[0]);
}

// ---------------- M0 = C/normC (in place), Z1 = T0 = 1.5I - 0.5*M0 ----------------
__global__ __launch_bounds__(256)
void initns_kernel(float* __restrict__ Mb, float* __restrict__ Z, const float* __restrict__ nrm)
{
    const int total = BATCH * ND * ND;
    for (int idx = blockIdx.x * 256 + threadIdx.x; idx < total; idx += gridDim.x * 256) {
        int b = idx / (ND * ND);
        int rem = idx - b * (ND * ND);
        int r = rem / ND, c = rem - r * ND;
        float v = Mb[idx] / nrm[b];
        Mb[idx] = v;
        Z[idx] = ((r == c) ? 1.5f : 0.f) - 0.5f * v;
    }
}

// ---------------- block reduction over 768 threads ----------------
__device__ __forceinline__ float bred768(float v, float* red12, int t)
{
#pragma unroll
    for (int off = 32; off > 0; off >>= 1) v += __shfl_down(v, off);
    if ((t & 63) == 0) red12[t >> 6] = v;
    __syncthreads();
    float r = 0.f;
#pragma unroll
    for (int i = 0; i < 12; i++) r += red12[i];
    __syncthreads();
    return r;
}

// ---------------- Blocked Householder tridiagonalization: panel kernel ----------
// Round-4 version (full dwordx4 matvec). For the first two panels the host splits
// the launch into two 32-batch halves: 4 blocks/XCD x 539 KB = 2.2 MB fits the
// 4 MB per-XCD L2, so the per-step matvec streams from L2 instead of HBM.
__global__ __launch_bounds__(768)
void tridiag_panel(float* __restrict__ Gall, float* __restrict__ dA,
                   float* __restrict__ eA, float* __restrict__ tauA,
                   float* __restrict__ Wgall, int k0)
{
    int b = blockIdx.x;
    float* A = Gall + (long)b * ND * ND;
    float* Wg = Wgall + (long)b * (PNB * ND);
    float* d = dA + b * ND; float* e = eA + b * ND; float* tau = tauA + b * ND;
    const int t = threadIdx.x;
    const int h = (t >= ND) ? 1 : 0;
    const int c = t - h * ND;            // 0..383
    const int g = t % 96;                // column quad (4 cols)
    const int s = t / 96;                // row slice 0..7
    __shared__ float Ul[PNB][ND];        // 48 KiB  (u vectors, columns k+1..383)
    __shared__ float Wl[PNB][ND];        // 48 KiB  (w vectors, columns k+1..383)
    __shared__ float u_s[ND];
    __shared__ float pp4s[8][392];
    __shared__ float al[PNB], be[PNB];
    __shared__ float red12[12];
    __shared__ float s_tau;

    const int jcnt = min(PNB, ND - 2 - k0);

    for (int j = 0; j < jcnt; j++) {
        const int k = k0 + j;
        const int m = ND - 1 - k;
        float x = 0.f;
        if (!h && c < m) {
            const int kc = (k + 1) + c;
            x = A[(long)k * ND + kc];
#pragma unroll 4
            for (int l = 0; l < j; l++) {
                x -= Ul[l][k] * Wl[l][kc] + Wl[l][k] * Ul[l][kc];
            }
            u_s[c] = x;
        }
        float sigma = bred768(x * x, red12, t);
        if (t == 0) {
            float v0 = u_s[0];
            float normx = sqrtf(sigma);
            float alpha = (v0 >= 0.f) ? -normx : normx;
            float denom = sigma - alpha * v0;
            float tk = (denom > 1e-30f) ? 1.f / denom : 0.f;
            s_tau = tk;
            float diag = A[(long)k * ND + k];
            for (int l = 0; l < j; l++) diag -= 2.f * Ul[l][k] * Wl[l][k];
            e[k] = alpha; tau[k] = tk; d[k] = diag;
            u_s[0] = v0 - alpha;
        }
        __syncthreads();
        const float tk = s_tau;

        // ---- matvec over the clean trailing block: dwordx4, 8-way row split ----
        const int kk4 = (k + 1) & ~3;
        const int off = (k + 1) - kk4;
        const int ncol4 = 96 - (kk4 >> 2);
        if (g < ncol4) {
            const int ri0 = (m * s) >> 3;
            const int ri1 = (m * (s + 1)) >> 3;
            const float* base = A + (long)(k + 1) * ND + kk4 + 4 * g;
            floatx4 p4 = (floatx4){0.f, 0.f, 0.f, 0.f};
            int i = ri0;
            for (; i + 8 <= ri1; i += 8) {
                floatx4 a0 = *(const floatx4*)&base[(long)(i    ) * ND];
                floatx4 a1 = *(const floatx4*)&base[(long)(i + 1) * ND];
                floatx4 a2 = *(const floatx4*)&base[(long)(i + 2) * ND];
                floatx4 a3 = *(const floatx4*)&base[(long)(i + 3) * ND];
                floatx4 a4 = *(const floatx4*)&base[(long)(i + 4) * ND];
                floatx4 a5 = *(const floatx4*)&base[(long)(i + 5) * ND];
                floatx4 a6 = *(const floatx4*)&base[(long)(i + 6) * ND];
                floatx4 a7 = *(const floatx4*)&base[(long)(i + 7) * ND];
                p4 += a0 * u_s[i]     + a1 * u_s[i + 1] + a2 * u_s[i + 2] + a3 * u_s[i + 3]
                    + a4 * u_s[i + 4] + a5 * u_s[i + 5] + a6 * u_s[i + 6] + a7 * u_s[i + 7];
            }
            for (; i < ri1; i++) {
                floatx4 a0 = *(const floatx4*)&base[(long)i * ND];
                p4 += a0 * u_s[i];
            }
            *(floatx4*)&pp4s[s][4 * g] = p4;
        }
        // wave-parallel dots from LDS panels: al[l] = w_l . u, be[l] = u_l . u
        {
            int wv = t >> 6, ln = t & 63;
            for (int l = wv; l < j; l += 12) {
                float sa = 0.f, sb = 0.f;
                const float* wrow = &Wl[l][k + 1];
                const float* urow = &Ul[l][k + 1];
                for (int i = ln; i < m; i += 64) { sa += wrow[i] * u_s[i]; sb += urow[i] * u_s[i]; }
#pragma unroll
                for (int off2 = 32; off2 > 0; off2 >>= 1) {
                    sa += __shfl_down(sa, off2); sb += __shfl_down(sb, off2);
                }
                if (ln == 0) { al[l] = sa; be[l] = sb; }
            }
        }
        __syncthreads();
        float contrib = 0.f, pc = 0.f;
        if (!h && c < m) {
            int ca = c + off;
            pc = pp4s[0][ca] + pp4s[1][ca] + pp4s[2][ca] + pp4s[3][ca]
               + pp4s[4][ca] + pp4s[5][ca] + pp4s[6][ca] + pp4s[7][ca];
            const int kc = (k + 1) + c;
#pragma unroll 4
            for (int l = 0; l < j; l++) {
                pc -= al[l] * Ul[l][kc] + be[l] * Wl[l][kc];
            }
            pc *= tk;
            contrib = u_s[c] * pc;
        }
        float dotup = bred768(contrib, red12, t);
        float sc = 0.5f * tk * dotup;
        if (!h && c < m) {
            const int kc = (k + 1) + c;
            float uv = u_s[c];
            float w = pc - sc * uv;
            Wl[j][kc] = w;
            Ul[j][kc] = uv;
            Wg[j * ND + kc] = w;
            A[(long)k * ND + kc] = uv;
        }
        __syncthreads();
    }
    if (k0 + PNB >= ND - 2 && t == 0) {
        float d0 = A[(long)(ND - 2) * ND + (ND - 2)];
        float e0 = A[(long)(ND - 2) * ND + (ND - 1)];
        float d1 = A[(long)(ND - 1) * ND + (ND - 1)];
        for (int l = 0; l < jcnt; l++) {
            float u0 = A[(long)(k0 + l) * ND + (ND - 2)];
            float u1 = A[(long)(k0 + l) * ND + (ND - 1)];
            float w0 = Wg[l * ND + (ND - 2)];
            float w1 = Wg[l * ND + (ND - 1)];
            d0 -= 2.f * u0 * w0;
            e0 -= u0 * w1 + w0 * u1;
            d1 -= 2.f * u1 * w1;
        }
        d[ND - 2] = d0; d[ND - 1] = d1; e[ND - 2] = e0;
        e[ND - 1] = 0.f; tau[ND - 2] = 0.f; tau[ND - 1] = 0.f;
    }
}

// ---------------- trailing update: A -= U W^T + W U^T (full device, 32x32 tiles) ----
__global__ __launch_bounds__(256)
void syr2k_update(float* __restrict__ Gall, const float* __restrict__ Wgall, int k0)
{
    const int k1 = k0 + PNB;
    const int tiles = (ND - k1) >> 5;
    int b = blockIdx.y;
    int ti = blockIdx.x / tiles, tj = blockIdx.x % tiles;
    int i0 = k1 + ti * 32, c0 = k1 + tj * 32;
    float* A = Gall + (long)b * ND * ND;
    const float* Wg = Wgall + (long)b * (PNB * ND);

    __shared__ float Us[PNB][36], Ws[PNB][36], Uc[PNB][36], Wc[PNB][36];
    int t = threadIdx.x;
    for (int q = t; q < PNB * 8; q += 256) {
        int l = q >> 3, c4 = (q & 7) * 4;
        *(float4*)&Us[l][c4] = *(const float4*)&A[(long)(k0 + l) * ND + i0 + c4];
        *(float4*)&Ws[l][c4] = *(const float4*)&Wg[l * ND + i0 + c4];
        *(float4*)&Uc[l][c4] = *(const float4*)&A[(long)(k0 + l) * ND + c0 + c4];
        *(float4*)&Wc[l][c4] = *(const float4*)&Wg[l * ND + c0 + c4];
    }
    __syncthreads();
    int tr = t >> 4, tc = t & 15;
    float acc00 = 0.f, acc01 = 0.f, acc10 = 0.f, acc11 = 0.f;
#pragma unroll 4
    for (int l = 0; l < PNB; l++) {
        float ua0 = Us[l][tr * 2], ua1 = Us[l][tr * 2 + 1];
        float wa0 = Ws[l][tr * 2], wa1 = Ws[l][tr * 2 + 1];
        float ub0 = Uc[l][tc * 2], ub1 = Uc[l][tc * 2 + 1];
        float wb0 = Wc[l][tc * 2], wb1 = Wc[l][tc * 2 + 1];
        acc00 += ua0 * wb0 + wa0 * ub0;
        acc01 += ua0 * wb1 + wa0 * ub1;
        acc10 += ua1 * wb0 + wa1 * ub0;
        acc11 += ua1 * wb1 + wa1 * ub1;
    }
    {
        float* r0 = &A[(long)(i0 + tr * 2) * ND + c0 + tc * 2];
        float* r1 = r0 + ND;
        float2 o0 = *(const float2*)r0, o1 = *(const float2*)r1;
        o0.x -= acc00; o0.y -= acc01;
        o1.x -= acc10; o1.y -= acc11;
        *(float2*)r0 = o0; *(float2*)r1 = o1;
    }
}

// ---------------- Sturm 64-way multisection: top-24 eigenvalues ----------------
// One block per (batch, eigenvalue). All 64 lanes probe 64 interior points of the
// bracket simultaneously (interval /65 per iteration vs /2 for bisection); the
// crossing is located with one ballot. 8 iterations give 65^-8 ~ 2^-48 of the
// Gershgorin range -- tighter than the old 42-step bisection -- with 5.25x less
// serial Sturm work and 24x more blocks in flight.
__global__ __launch_bounds__(64)
void eigvals_kernel(const float* __restrict__ dA, const float* __restrict__ eA,
                    float* __restrict__ lamA)
{
    int blk = blockIdx.x;
    int b = blk / RK, eig = blk % RK;
    int t = threadIdx.x;   // 64 threads
    __shared__ float2 de[ND];
    __shared__ float d_s[ND], ea[ND], red[64];
    for (int i = t; i < ND; i += 64) {
        float dv = dA[b * ND + i];
        float ev = eA[b * ND + i];
        float ep = (i > 0) ? eA[b * ND + i - 1] : 0.f;
        d_s[i] = dv; ea[i] = fabsf(ev);
        de[i] = make_float2(dv, ep * ep + 1e-38f);
    }
    __syncthreads();
    float lo = 1e30f, hi = -1e30f;
    for (int i = t; i < ND; i += 64) {
        float r = ea[i] + ((i > 0) ? ea[i - 1] : 0.f);
        lo = fminf(lo, d_s[i] - r); hi = fmaxf(hi, d_s[i] + r);
    }
    red[t] = lo; __syncthreads();
    for (int off = 32; off > 0; off >>= 1) {
        if (t < off) red[t] = fminf(red[t], red[t + off]);
        __syncthreads();
    }
    lo = red[0]; __syncthreads();
    red[t] = hi; __syncthreads();
    for (int off = 32; off > 0; off >>= 1) {
        if (t < off) red[t] = fmaxf(red[t], red[t + off]);
        __syncthreads();
    }
    hi = red[0];
    __syncthreads();

    const int idx = ND - 1 - eig;      // ascending index (eig=0 -> largest)
    float a = lo, c = hi;
    for (int it = 0; it < 8; it++) {
        const float w = (c - a) * (1.f / 65.f);
        const float mid = a + w * (float)(t + 1);
        int cnt = 0;
        float qinv = 0.f;
        for (int i = 0; i < ND; i += 8) {
            float2 v0 = de[i    ], v1 = de[i + 1], v2 = de[i + 2], v3 = de[i + 3];
            float2 v4 = de[i + 4], v5 = de[i + 5], v6 = de[i + 6], v7 = de[i + 7];
            float q;
            q = (v0.x - mid) - v0.y * qinv; cnt += (q < 0.f); qinv = __builtin_amdgcn_rcpf(q);
            q = (v1.x - mid) - v1.y * qinv; cnt += (q < 0.f); qinv = __builtin_amdgcn_rcpf(q);
            q = (v2.x - mid) - v2.y * qinv; cnt += (q < 0.f); qinv = __builtin_amdgcn_rcpf(q);
            q = (v3.x - mid) - v3.y * qinv; cnt += (q < 0.f); qinv = __builtin_amdgcn_rcpf(q);
            q = (v4.x - mid) - v4.y * qinv; cnt += (q < 0.f); qinv = __builtin_amdgcn_rcpf(q);
            q = (v5.x - mid) - v5.y * qinv; cnt += (q < 0.f); qinv = __builtin_amdgcn_rcpf(q);
            q = (v6.x - mid) - v6.y * qinv; cnt += (q < 0.f); qinv = __builtin_amdgcn_rcpf(q);
            q = (v7.x - mid) - v7.y * qinv; cnt += (q < 0.f); qinv = __builtin_amdgcn_rcpf(q);
        }
        unsigned long long over = __ballot(cnt > idx);   // monotone in lane
        if (over == 0ULL) {
            a = a + w * 64.f;                            // eigenvalue in (mid_63, c]
        } else {
            int f = __ffsll((long long)over) - 1;        // first lane with cnt > idx
            float na = a + w * (float)f;                 // mid_{f-1} (f==0 -> a)
            float nc = a + w * (float)(f + 1);           // mid_f
            a = na; c = nc;
        }
    }
    if (t == 0) lamA[b * RK + eig] = 0.5f * (a + c);
}

// ---------------- tridiagonal inverse iteration (pivoted LU, all in LDS) ----------
__global__ __launch_bounds__(64)
void invit_kernel(const float* __restrict__ dA, const float* __restrict__ eA,
                  const float* __restrict__ lamA, float* __restrict__ scr)
{
    int b = blockIdx.x, t = threadIdx.x;
    __shared__ float d[ND], e[ND];
    __shared__ float ua[ND][RK], ub[ND][RK], uc[ND][RK];
    __shared__ float y[ND][RK];
    for (int i = t; i < ND; i += 64) { d[i] = dA[b * ND + i]; e[i] = eA[b * ND + i]; }
    __syncthreads();
    if (t >= RK) return;
    const int s = b * RK + t;
    float* yout = scr + 5L * ND * SSTR;
    const float lam = lamA[s];

    for (int pass = 0; pass < 2; pass++) {
        if (pass == 0) {
            for (int i = 0; i < ND; i++) {
                unsigned h = ((unsigned)i * 1103515245u) ^ ((unsigned)s * 747796405u);
                h *= 2654435769u; h ^= h >> 16;
                y[i][t] = ((float)(h & 0xFFFFu) * (1.f / 65536.f)) - 0.5f;
            }
        }
        float ai = d[0] - lam;
        float bc = e[0];
        float ycur = y[0][t];
        for (int i = 0; i < ND - 1; i++) {
            float sub = e[i];
            float dn = d[i + 1] - lam;
            float en = (i + 1 < ND - 1) ? e[i + 1] : 0.f;
            float ynext = y[i + 1][t];
            if (fabsf(ai) >= fabsf(sub)) {
                float aa = (ai == 0.f) ? 1e-20f : ai;
                float mlt = sub / aa;
                ua[i][t] = aa; ub[i][t] = bc; uc[i][t] = 0.f;
                y[i][t] = ycur;
                ycur = ynext - mlt * ycur;
                ai = dn - mlt * bc;
                bc = en;
            } else {
                float mlt = ai / sub;
                ua[i][t] = sub; ub[i][t] = dn; uc[i][t] = en;
                y[i][t] = ynext;
                ycur = ycur - mlt * ynext;
                ai = bc - mlt * dn;
                bc = -mlt * en;
            }
        }
        float uaN = (ai == 0.f) ? 1e-20f : ai;
        float x1 = ycur / uaN;           // x[ND-1]
        y[ND - 1][t] = x1;
        float x2 = x1;
        {
            float xm = (y[ND - 2][t] - ub[ND - 2][t] * x1) / ua[ND - 2][t];
            y[ND - 2][t] = xm; x2 = x1; x1 = xm;
        }
        for (int i = ND - 3; i >= 0; i--) {
            float xi = (y[i][t] - ub[i][t] * x1 - uc[i][t] * x2) / ua[i][t];
            y[i][t] = xi; x2 = x1; x1 = xi;
        }
        float nn = 0.f;
        for (int i = 0; i < ND; i++) { float v = y[i][t]; nn += v * v; }
        float inv = (nn > 0.f) ? 1.f / sqrtf(nn) : 0.f;
        for (int i = 0; i < ND; i++) y[i][t] *= inv;
    }
    for (int i = 0; i < ND; i++) yout[(long)i * SSTR + s] = y[i][t];
}

// ---------------- fast MGS + register-pipelined Householder back-transform ------
__global__ __launch_bounds__(384)
void orthbt_kernel(const float* __restrict__ xx, const float* __restrict__ Gall,
                   const float* __restrict__ tauA, float* __restrict__ Qout)
{
    int b = blockIdx.x, t = threadIdx.x;   // 384 threads
    __shared__ float Y[ND][RK + 1];
    __shared__ float red[ND];
    __shared__ float dts[RK];
    __shared__ float tls[ND];

    for (int j = 0; j < RK; j++) Y[t][j] = xx[(long)t * SSTR + b * RK + j];
    tls[t] = tauA[b * ND + t];
    __syncthreads();

    const int mcol = t % RK;      // 0..23
    const int msl  = t / RK;      // 0..15 (24-row slices)
    const int r0m  = msl * 24;
    for (int j = 0; j < RK; j++) {
        float pp = 0.f;
        for (int i = 0; i < 24; i++) {
            pp += Y[r0m + i][j] * Y[r0m + i][mcol];
        }
        red[mcol * 16 + msl] = pp;
        __syncthreads();
        if (t < RK) {
            float ssum = 0.f;
            for (int q = 0; q < 16; q++) ssum += red[t * 16 + q];
            dts[t] = ssum;
        }
        __syncthreads();
        float nv = dts[j];
        float inv = (nv > 1e-30f) ? (1.f / sqrtf(nv)) : 0.f;
        if (mcol > j) {
            float coef = dts[mcol] * inv * inv;
            for (int i = 0; i < 24; i++) Y[r0m + i][mcol] -= coef * Y[r0m + i][j];
        } else if (mcol == j) {
            for (int i = 0; i < 24; i++) Y[r0m + i][j] *= inv;
        }
        __syncthreads();
    }

    const int wv = t >> 6, ln = t & 63;
    float yr[4][6];
#pragma unroll
    for (int cc = 0; cc < 4; cc++)
#pragma unroll
        for (int q = 0; q < 6; q++)
            yr[cc][q] = Y[ln + 64 * q][4 * wv + cc];
    __syncthreads();

    const float* A = Gall + (long)b * ND * ND;
    float un[6];
    {
        const int k = ND - 3;
#pragma unroll
        for (int q = 0; q < 6; q++) un[q] = A[(long)k * ND + ln + 64 * q];
    }
    for (int k = ND - 3; k >= 0; k--) {
        float cu[6];
#pragma unroll
        for (int q = 0; q < 6; q++) {
            int r = ln + 64 * q;
            cu[q] = (r > k) ? un[q] : 0.f;
        }
        if (k > 0) {
#pragma unroll
            for (int q = 0; q < 6; q++) un[q] = A[(long)(k - 1) * ND + ln + 64 * q];
        }
        const float tk = tls[k];
#pragma unroll
        for (int cc = 0; cc < 4; cc++) {
            float p = 0.f;
#pragma unroll
            for (int q = 0; q < 6; q++) p += cu[q] * yr[cc][q];
#pragma unroll
            for (int off = 32; off > 0; off >>= 1) p += __shfl_xor(p, off);
            float sv = tk * p;
#pragma unroll
            for (int q = 0; q < 6; q++) yr[cc][q] -= sv * cu[q];
        }
    }

#pragma unroll
    for (int cc = 0; cc < 4; cc++)
#pragma unroll
        for (int q = 0; q < 6; q++)
            Y[ln + 64 * q][4 * wv + cc] = yr[cc][q];
    __syncthreads();
    for (int l = t; l < ND * RK; l += 384) {
        int i = l / RK, j = l - i * RK;
        Qout[(long)b * ND * RK + l] = Y[i][j];
    }
}

// ---------------- Sp = X_w @ Q ----------------
__global__ __launch_bounds__(256)
void proj_kernel(const float* __restrict__ Xw, const float* __restrict__ Qall,
                 float* __restrict__ P)
{
    int b = blockIdx.y;
    int r0 = blockIdx.x * 256;
    __shared__ float Qs[ND][RK + 1];
    const float* Q = Qall + (long)b * ND * RK;
    for (int l = threadIdx.x; l < ND * RK; l += 256) {
        int i = l / RK, j = l - i * RK;
        Qs[i][j] = Q[l];
    }
    __syncthreads();
    int r = r0 + threadIdx.x;
    const float* X = Xw + (long)b * NR * ND + (long)r * ND;
    float acc[RK];
#pragma unroll
    for (int j = 0; j < RK; j++) acc[j] = 0.f;
    for (int k = 0; k < ND; k++) {
        float xv = X[k];
#pragma unroll
        for (int j = 0; j < RK; j++) acc[j] += xv * Qs[k][j];
    }
    float* Pr = P + (long)b * NR * RK + (long)r * RK;
#pragma unroll
    for (int j = 0; j < RK; j++) Pr[j] = acc[j];
}

// ---------------- M = Sp^T Tp ; R = polar(M) via Newton-Schulz ; write R - I ----------------
__global__ __launch_bounds__(256)
void polar_kernel(const float* __restrict__ Sp, const float* __restrict__ Tp,
                  float* __restrict__ RmI)
{
    int b = blockIdx.x, t = threadIdx.x;
    __shared__ float Sb[128][RK + 1], Tb[128][RK + 1];
    __shared__ float Xm[RK][RK + 1], Bm[RK][RK + 1], Mm[RK][RK + 1];
    __shared__ float red[256];

    float accM[3] = {0.f, 0.f, 0.f};
    for (int c = 0; c < 4; c++) {
        for (int l = t; l < 128 * RK; l += 256) {
            int row = l / RK, colj = l - row * RK;
            Sb[row][colj] = Sp[(long)b * NR * RK + (long)(c * 128 + row) * RK + colj];
            Tb[row][colj] = Tp[(long)b * NR * RK + (long)(c * 128 + row) * RK + colj];
        }
        __syncthreads();
        for (int q = 0; q < 3; q++) {
            int e = t + q * 256;
            if (e < RK * RK) {
                int r = e / RK, s2 = e - r * RK;
                float a = 0.f;
                for (int n = 0; n < 128; n++) a += Sb[n][r] * Tb[n][s2];
                accM[q] += a;
            }
        }
        __syncthreads();
    }
    float ss = 0.f;
    for (int q = 0; q < 3; q++) {
        int e = t + q * 256;
        if (e < RK * RK) {
            int r = e / RK, s2 = e - r * RK;
            Mm[r][s2] = accM[q];
            ss += accM[q] * accM[q];
        }
    }
    red[t] = ss; __syncthreads();
    for (int off = 128; off > 0; off >>= 1) {
        if (t < off) red[t] += red[t + off];
        __syncthreads();
    }
    float fro = sqrtf(red[0]);
    float inv = (fro > 1e-30f) ? 1.f / fro : 0.f;
    for (int q = 0; q < 3; q++) {
        int e = t + q * 256;
        if (e < RK * RK) { int r = e / RK, s2 = e - r * RK; Xm[r][s2] = Mm[r][s2] * inv; }
    }
    __syncthreads();
    for (int it = 0; it < POLAR_ITERS; it++) {
        for (int q = 0; q < 3; q++) {
            int e = t + q * 256;
            if (e < RK * RK) {
                int r = e / RK, s2 = e - r * RK;
                float a = 0.f;
                for (int k = 0; k < RK; k++) a += Xm[k][r] * Xm[k][s2];
                Bm[r][s2] = a;
            }
        }
        __syncthreads();
        for (int q = 0; q < 3; q++) {
            int e = t + q * 256;
            if (e < RK * RK) {
                int r = e / RK, s2 = e - r * RK;
                float a = 0.f;
                for (int k = 0; k < RK; k++) a += Xm[r][k] * Bm[k][s2];
                Mm[r][s2] = 1.5f * Xm[r][s2] - 0.5f * a;
            }
        }
        __syncthreads();
        for (int q = 0; q < 3; q++) {
            int e = t + q * 256;
            if (e < RK * RK) { int r = e / RK, s2 = e - r * RK; Xm[r][s2] = Mm[r][s2]; }
        }
        __syncthreads();
    }
    for (int q = 0; q < 3; q++) {
        int e = t + q * 256;
        if (e < RK * RK) {
            int r = e / RK, s2 = e - r * RK;
            RmI[(long)b * RK * RK + e] = Xm[r][s2] - ((r == s2) ? 1.f : 0.f);
        }
    }
}

// ---------------- aligned = S_w + Sp (R-I) Q^T  (writes d_out) ----------------
__global__ __launch_bounds__(256)
void align_kernel(const float* __restrict__ Sw, const float* __restrict__ Sp,
                  const float* __restrict__ RmI, const float* __restrict__ Qall,
                  float* __restrict__ out)
{
    int b = blockIdx.y;
    int r0 = blockIdx.x * 64;
    int t = threadIdx.x;
    __shared__ float Qs[ND][RK + 1];
    __shared__ float Rm[RK][RK + 1];
    __shared__ float Ss[64][RK + 1];
    __shared__ float W[64][RK + 1];

    for (int l = t; l < ND * RK; l += 256) {
        int i = l / RK, j = l - i * RK;
        Qs[i][j] = Qall[(long)b * ND * RK + l];
    }
    for (int l = t; l < RK * RK; l += 256) {
        int i = l / RK, j = l - i * RK;
        Rm[i][j] = RmI[(long)b * RK * RK + l];
    }
    for (int l = t; l < 64 * RK; l += 256) {
        int i = l / RK, j = l - i * RK;
        Ss[i][j] = Sp[(long)b * NR * RK + (long)(r0 + i) * RK + j];
    }
    __syncthreads();
    for (int l = t; l < 64 * RK; l += 256) {
        int r = l / RK, j = l - r * RK;
        float a = 0.f;
        for (int k = 0; k < RK; k++) a += Ss[r][k] * Rm[k][j];
        W[r][j] = a;
    }
    __syncthreads();
    for (int r = 0; r < 64; r++) {
        for (int c = t; c < ND; c += 256) {
            float a = Sw[(long)b * NR * ND + (long)(r0 + r) * ND + c];
            float s2 = 0.f;
#pragma unroll
            for (int j = 0; j < RK; j++) s2 += W[r][j] * Qs[c][j];
            out[(long)b * NR * ND + (long)(r0 + r) * ND + c] = a + s2;
        }
    }
}

// ---------------- mean cosine ----------------
__global__ __launch_bounds__(256)
void cos_kernel(const float* __restrict__ out, const float* __restrict__ tgt,
                float* __restrict__ acc)
{
    int row = blockIdx.x * 4 + (threadIdx.x >> 6);
    int lane = threadIdx.x & 63;
    const float* a = out + (long)row * ND;
    const float* tg = tgt + (long)row * ND;
    float sd = 0.f, sa = 0.f, st = 0.f;
    for (int i = lane; i < ND; i += 64) {
        float av = a[i], tv = tg[i];
        sd += av * tv; sa += av * av; st += tv * tv;
    }
#pragma unroll
    for (int off = 32; off > 0; off >>= 1) {
        sd += __shfl_down(sd, off); sa += __shfl_down(sa, off); st += __shfl_down(st, off);
    }
    __shared__ float part[4];
    if (lane == 0) part[threadIdx.x >> 6] = sd / (sqrtf(sa) * sqrtf(st) + 1e-8f);
    __syncthreads();
    if (threadIdx.x == 0) atomicAdd(acc, part[0] + part[1] + part[2] + part[3]);
}

__global__ void finalize_kernel(const float* __restrict__ acc, float* __restrict__ out)
{
    out[0] = acc[0] / 32768.0f;
}

// ---------------- host ----------------
static inline void launch_gd(int TA,
    const float* A1p, const float* B1p, float* C1p, int mode1, const float* sc1, int tm1,
    const float* A2p, const float* B2p, float* C2p, int mode2, const float* sc2, int tm2,
    int nbat, int M, int N, int K, long sA, long sB, long sC,
    int lda, int ldb, int ldc, int sym, hipStream_t stream)
{
    int tiles;
    if (sym) { int tn = N >> 7; tiles = tn * (tn + 1) / 2; }
    else tiles = (M / 128) * (N / 128);
    dim3 grid(tiles, nbat);
    if (TA)
        gemm_kernel<1><<<grid, dim3(256), 0, stream>>>(A1p, B1p, C1p, A2p, B2p, C2p,
            M, N, K, sA, sB, sC, lda, ldb, ldc, mode1, sc1, mode2, sc2, sym, tm1, tm2);
    else
        gemm_kernel<0><<<grid, dim3(256), 0, stream>>>(A1p, B1p, C1p, A2p, B2p, C2p,
            M, N, K, sA, sB, sC, lda, ldb, ldc, mode1, sc1, mode2, sc2, sym, tm1, tm2);
}

static inline void launch_g1(int TA, const float* Ap, const float* Bp, float* Cp,
    int mode, const float* sc, int tm,
    int M, int N, int K, long sA, long sB, long sC,
    int lda, int ldb, int ldc, int sym, hipStream_t stream)
{
    launch_gd(TA, Ap, Bp, Cp, mode, sc, tm, Ap, Bp, Cp, mode, sc, tm,
              BATCH, M, N, K, sA, sB, sC, lda, ldb, ldc, sym, stream);
}

extern "C" void kernel_launch(void* const* d_in, const int* in_sizes, int n_in,
                              void* d_out, int out_size, void* d_ws, size_t ws_size,
                              hipStream_t stream)
{
    const float* src = (const float*)d_in[0];
    const float* tgt = (const float*)d_in[1];
    float* out = (float*)d_out;
    float* ws = (float*)d_ws;

    float* A0 = ws;
    float* A3 = ws + 3 * SZC;
    float* A4 = ws + 4 * SZC;
    float* S5 = ws + 5 * SZC;
    float* nrm_s = S5;                     // nrm_t = nrm_s + 64 (contiguous for dual frob)
    float* nrm_t = S5 + 64;
    float* dd = S5 + 128;
    float* ee = dd + BATCH * ND;
    float* tt = ee + BATCH * ND;
    float* lam = tt + BATCH * ND;
    float* accp = lam + BATCH * RK;

    float* Tm = out;                       // square scratch in d_out
    float* SW = A0;                        // [0, 12.58M) rect
    float* TW = A0 + (long)BATCH * NR * ND;// [12.58M, 25.2M) rect
    float* C1 = TW;                        // square M_t buffer (dead before TW written)
    float* G  = A3;
    float* scr = A4;                       // 6 * 384 * 1536
    float* Qp  = A4 + 6L * ND * SSTR;
    float* Spp = Qp + (long)BATCH * ND * RK;
    float* Tpp = Spp + (long)BATCH * NR * RK;
    float* Rp  = Tpp + (long)BATCH * NR * RK;
    float* Wg  = Rp + (long)BATCH * RK * RK;           // PNB*ND per batch
    float* yarr = scr + 5L * ND * SSTR;

    const long sXin = (long)NR * ND;     // 196608
    const long sSq  = (long)ND * ND;     // 147456

    // ==== dual covariance: cov_s -> A3, cov_t -> C1 ====
    launch_gd(1, src, src, A3, MODE_COV, nullptr, 0,
                 tgt, tgt, C1, MODE_COV, nullptr, 0,
              128, ND, ND, NR, sXin, sXin, sSq, ND, ND, ND, 1, stream);
    frob_kernel<<<dim3(128), 256, 0, stream>>>(A3, C1, nrm_s);

    // ==== phase S (M-track rotation A3 -> A0 -> A4 -> A3 -> A0; U scratch Tm) ====
    initns_kernel<<<dim3(2048), 256, 0, stream>>>(A3, A4, nrm_s);   // M0=A3, Z1=A4
    launch_g1(0, A3, A3, Tm, MODE_PLAIN, nullptr, 3, ND, ND, ND, sSq, sSq, sSq, ND, ND, ND, 1, stream);
    launch_g1(0, A3, Tm, A0, MODE_PLAIN, nullptr, 0, ND, ND, ND, sSq, sSq, sSq, ND, ND, ND, 1, stream);
    launch_gd(0, A0, A4, A3, MODE_PLAIN, nullptr, 1,
                 A0, A0, Tm, MODE_PLAIN, nullptr, 3,
              128, ND, ND, ND, sSq, sSq, sSq, ND, ND, ND, 1, stream);
    launch_g1(0, A0, Tm, A4, MODE_PLAIN, nullptr, 0, ND, ND, ND, sSq, sSq, sSq, ND, ND, ND, 1, stream);
    launch_gd(0, A4, A3, A0, MODE_PLAIN, nullptr, 1,
                 A4, A4, Tm, MODE_PLAIN, nullptr, 3,
              128, ND, ND, ND, sSq, sSq, sSq, ND, ND, ND, 1, stream);
    launch_g1(0, A4, Tm, A3, MODE_PLAIN, nullptr, 0, ND, ND, ND, sSq, sSq, sSq, ND, ND, ND, 1, stream);
    launch_gd(0, A3, A0, A4, MODE_PLAIN, nullptr, 1,
                 A3, A3, Tm, MODE_PLAIN, nullptr, 3,
              128, ND, ND, ND, sSq, sSq, sSq, ND, ND, ND, 1, stream);
    launch_g1(0, A3, Tm, A0, MODE_PLAIN, nullptr, 0, ND, ND, ND, sSq, sSq, sSq, ND, ND, ND, 1, stream);
    launch_g1(0, A0, A4, A3, MODE_PLAIN, nullptr, 1, ND, ND, ND, sSq, sSq, sSq, ND, ND, ND, 1, stream);

    // ==== phase T (M-track C1 -> A4 -> A0 -> C1 -> A4; Z-track A0/C1/A4; U scratch Tm) ====
    initns_kernel<<<dim3(2048), 256, 0, stream>>>(C1, A0, nrm_t);   // M0=C1, Z1=A0
    launch_g1(0, C1, C1, Tm, MODE_PLAIN, nullptr, 3, ND, ND, ND, sSq, sSq, sSq, ND, ND, ND, 1, stream);
    launch_g1(0, C1, Tm, A4, MODE_PLAIN, nullptr, 0, ND, ND, ND, sSq, sSq, sSq, ND, ND, ND, 1, stream);
    launch_gd(0, A4, A0, C1, MODE_PLAIN, nullptr, 1,
                 A4, A4, Tm, MODE_PLAIN, nullptr, 3,
              128, ND, ND, ND, sSq, sSq, sSq, ND, ND, ND, 1, stream);
    launch_g1(0, A4, Tm, A0, MODE_PLAIN, nullptr, 0, ND, ND, ND, sSq, sSq, sSq, ND, ND, ND, 1, stream);
    launch_gd(0, A0, C1, A4, MODE_PLAIN, nullptr, 1,
                 A0, A0, Tm, MODE_PLAIN, nullptr, 3,
              128, ND, ND, ND, sSq, sSq, sSq, ND, ND, ND, 1, stream);
    launch_g1(0, A0, Tm, C1, MODE_PLAIN, nullptr, 0, ND, ND, ND, sSq, sSq, sSq, ND, ND, ND, 1, stream);
    launch_gd(0, C1, A4, A0, MODE_PLAIN, nullptr, 1,
                 C1, C1, Tm, MODE_PLAIN, nullptr, 3,
              128, ND, ND, ND, sSq, sSq, sSq, ND, ND, ND, 1, stream);
    launch_g1(0, C1, Tm, A4, MODE_PLAIN, nullptr, 0, ND, ND, ND, sSq, sSq, sSq, ND, ND, ND, 1, stream);
    launch_g1(0, A4, A0, Tm, MODE_PLAIN, nullptr, 1, ND, ND, ND, sSq, sSq, sSq, ND, ND, ND, 1, stream);

    // ==== dual whiten: SW = src*Z5_s/sqrt(nrm_s), TW = tgt*Z5_t/sqrt(nrm_t) ====
    launch_gd(0, src, A3, SW, MODE_SCALE, nrm_s, 0,
                 tgt, Tm, TW, MODE_SCALE, nrm_t, 0,
              128, NR, ND, ND, sXin, sSq, sXin, ND, ND, ND, 0, stream);

    // ---- G = S_w^T S_w + T_w^T T_w ----
    launch_g1(1, SW, SW, G, MODE_PLAIN, nullptr, 0, ND, ND, NR, sXin, sXin, sSq, ND, ND, ND, 1, stream);
    launch_g1(1, TW, TW, G, MODE_ACC,   nullptr, 0, ND, ND, NR, sXin, sXin, sSq, ND, ND, ND, 1, stream);

    // ---- blocked tridiagonalization: panels + full-device trailing updates ----
    for (int p = 0; p < ND / PNB; p++) {
        int k0 = p * PNB;
        if (p < 2) {
            tridiag_panel<<<dim3(32), 768, 0, stream>>>(G, dd, ee, tt, Wg, k0);
            tridiag_panel<<<dim3(32), 768, 0, stream>>>(G + 32L * sSq, dd + 32 * ND,
                ee + 32 * ND, tt + 32 * ND, Wg + 32L * PNB * ND, k0);
        } else {
            tridiag_panel<<<dim3(BATCH), 768, 0, stream>>>(G, dd, ee, tt, Wg, k0);
        }
        int k1 = (p + 1) * PNB;
        if (k1 < ND - 2) {
            int tiles = (ND - k1) >> 5;
            syr2k_update<<<dim3(tiles * tiles, BATCH), 256, 0, stream>>>(G, Wg, k0);
        }
    }
    eigvals_kernel<<<dim3(BATCH * RK), 64, 0, stream>>>(dd, ee, lam);
    invit_kernel<<<BATCH, 64, 0, stream>>>(dd, ee, lam, scr);
    orthbt_kernel<<<BATCH, 384, 0, stream>>>(yarr, G, tt, Qp);
    // ---- projections, Procrustes, output ----
    proj_kernel<<<dim3(2, BATCH), 256, 0, stream>>>(SW, Qp, Spp);
    proj_kernel<<<dim3(2, BATCH), 256, 0, stream>>>(TW, Qp, Tpp);
    polar_kernel<<<BATCH, 256, 0, stream>>>(Spp, Tpp, Rp);
    align_kernel<<<dim3(8, BATCH), 256, 0, stream>>>(SW, Spp, Rp, Qp, out);
    hipMemsetAsync((void*)accp, 0, 4, stream);
    cos_kernel<<<dim3(8192), 256, 0, stream>>>(out, tgt, accp);
    finalize_kernel<<<1, 1, 0, stream>>>(accp, out + (long)BATCH * NR * ND);
    (void)in_sizes; (void)n_in; (void)out_size; (void)ws_size;
}

// Round 8
// 4920.950 us; speedup vs baseline: 1.3467x; 1.0885x over previous
//
#include <hip/hip_runtime.h>
#include <math.h>

static constexpr int BATCH = 64;
static constexpr int NR  = 512;    // rows per matrix (n)
static constexpr int ND  = 384;    // feature dim (N)
static constexpr int RK  = 24;     // rank
static constexpr int POLAR_ITERS = 36;
static constexpr int PNB = 32;     // tridiag panel width (U+W panels live in LDS)
static constexpr long SZC = (long)BATCH * ND * ND;      // 9,437,184 floats
static constexpr int SSTR = BATCH * RK;                 // 1536 (inverse-iter solve stride)

#define MODE_PLAIN 0
#define MODE_COV   1
#define MODE_SCALE 3
#define MODE_ACC   4

typedef _Float16 half8 __attribute__((ext_vector_type(8)));
typedef _Float16 half4 __attribute__((ext_vector_type(4)));
typedef float floatx4 __attribute__((ext_vector_type(4)));

// ---------------- batched split-fp16 MFMA GEMM (128x128 tile, 4 waves) ----------
// C = A*B (TA=0, A row-major MxK) or C = A^T*B (TA=1, A stored KxM row-major).
// fp32 emulated via 2-term fp16 split, 3 MFMA passes.
// sym=1: upper-triangle tiles only, epilogue mirrors (square M=N).
// tmask bit0/bit1: operand transform v -> 1.5*delta - 0.5*v (NS T on the fly).
// DUAL: grid.y up to 128; batches >= 64 use the second pointer/mode set.
// PIPELINE: next k-tile prefetched into registers during the MFMA phase.
template<int TA>
__global__ __launch_bounds__(256)
void gemm_kernel(const float* __restrict__ Ag, const float* __restrict__ Bg,
                 float* __restrict__ Cg,
                 const float* __restrict__ Ag2, const float* __restrict__ Bg2,
                 float* __restrict__ Cg2,
                 int M, int N, int K,
                 long sA, long sB, long sC, int lda, int ldb, int ldc,
                 int mode, const float* __restrict__ scale,
                 int mode2, const float* __restrict__ scale2,
                 int sym, int tmask, int tmask2)
{
    const int by = blockIdx.y;
    int bloc;
    const float* A; const float* Bm; float* C;
    if (by < BATCH) {
        bloc = by;
        A = Ag + (long)bloc * sA; Bm = Bg + (long)bloc * sB; C = Cg + (long)bloc * sC;
    } else {
        bloc = by - BATCH;
        A = Ag2 + (long)bloc * sA; Bm = Bg2 + (long)bloc * sB; C = Cg2 + (long)bloc * sC;
        mode = mode2; scale = scale2; tmask = tmask2;
    }
    const int tilesN = N >> 7;            // N/128
    int ti, tj;
    if (sym) {
        int idx = blockIdx.x;
        ti = 0; int rem = tilesN;
        while (idx >= rem) { idx -= rem; ti++; rem--; }
        tj = ti + idx;
    } else {
        tj = blockIdx.x % tilesN;
        ti = blockIdx.x / tilesN;
    }
    const int n0 = tj * 128, m0 = ti * 128;

    __shared__ _Float16 Ah[128][40], Al[128][40];
    __shared__ _Float16 Bh[128][40], Bl[128][40];

    const int tid = threadIdx.x;
    const int wave = tid >> 6, lane = tid & 63;
    const int wm0 = (wave >> 1) * 64, wn0 = (wave & 1) * 64;
    const int fm = lane & 15;       // frag row (A) / col (B,D)
    const int fq = lane >> 4;       // quad

    floatx4 acc[4][4];
#pragma unroll
    for (int i = 0; i < 4; i++)
#pragma unroll
        for (int j = 0; j < 4; j++) acc[i][j] = (floatx4){0.f, 0.f, 0.f, 0.f};

    // ---- prefetch registers ----
    float4 pA4[4];
    float  pAs[16];
    float  pBs[16];

    // initial load (k-tile 0)
    if (TA == 0) {
#pragma unroll
        for (int q = 0; q < 4; q++) {
            int idx = tid + q * 256;
            int row = idx >> 3, kq = (idx & 7) * 4;
            pA4[q] = *(const float4*)&A[(long)(m0 + row) * lda + kq];
        }
    } else {
        int m = tid & 127, kb = (tid >> 7) * 16;
#pragma unroll
        for (int i = 0; i < 16; i++)
            pAs[i] = A[(long)(kb + i) * lda + m0 + m];
    }
    {
        int n = tid & 127, kb = (tid >> 7) * 16;
#pragma unroll
        for (int i = 0; i < 16; i++)
            pBs[i] = Bm[(long)(kb + i) * ldb + n0 + n];
    }

    for (int k0 = 0; k0 < K; k0 += 32) {
        // ---- stage prefetched regs -> LDS (identical arithmetic to unpipelined) ----
        if (TA == 0) {
#pragma unroll
            for (int q = 0; q < 4; q++) {
                int idx = tid + q * 256;          // 1024 float4 = 128x32
                int row = idx >> 3, kq = (idx & 7) * 4;
                float4 v = pA4[q];
                if (tmask & 1) {
                    int gr = m0 + row, gc = k0 + kq;
                    v.x = ((gr == gc    ) ? 1.5f : 0.f) - 0.5f * v.x;
                    v.y = ((gr == gc + 1) ? 1.5f : 0.f) - 0.5f * v.y;
                    v.z = ((gr == gc + 2) ? 1.5f : 0.f) - 0.5f * v.z;
                    v.w = ((gr == gc + 3) ? 1.5f : 0.f) - 0.5f * v.w;
                }
                _Float16 h0 = (_Float16)v.x; _Float16 l0 = (_Float16)(v.x - (float)h0);
                _Float16 h1 = (_Float16)v.y; _Float16 l1 = (_Float16)(v.y - (float)h1);
                _Float16 h2 = (_Float16)v.z; _Float16 l2 = (_Float16)(v.z - (float)h2);
                _Float16 h3 = (_Float16)v.w; _Float16 l3 = (_Float16)(v.w - (float)h3);
                half4 hv, lv;
                hv[0] = h0; hv[1] = h1; hv[2] = h2; hv[3] = h3;
                lv[0] = l0; lv[1] = l1; lv[2] = l2; lv[3] = l3;
                *(half4*)&Ah[row][kq] = hv;
                *(half4*)&Al[row][kq] = lv;
            }
        } else {
            int m = tid & 127, kb = (tid >> 7) * 16;
#pragma unroll
            for (int i = 0; i < 16; i += 4) {
                half4 hv, lv;
#pragma unroll
                for (int jj = 0; jj < 4; jj++) {
                    float v = pAs[i + jj];
                    _Float16 hh = (_Float16)v;
                    hv[jj] = hh; lv[jj] = (_Float16)(v - (float)hh);
                }
                *(half4*)&Ah[m][kb + i] = hv;
                *(half4*)&Al[m][kb + i] = lv;
            }
        }
        {
            int n = tid & 127, kb = (tid >> 7) * 16;
#pragma unroll
            for (int i = 0; i < 16; i += 4) {
                half4 hv, lv;
#pragma unroll
                for (int jj = 0; jj < 4; jj++) {
                    float v = pBs[i + jj];
                    if (tmask & 2) v = (((k0 + kb + i + jj) == (n0 + n)) ? 1.5f : 0.f) - 0.5f * v;
                    _Float16 hh = (_Float16)v;
                    hv[jj] = hh; lv[jj] = (_Float16)(v - (float)hh);
                }
                *(half4*)&Bh[n][kb + i] = hv;
                *(half4*)&Bl[n][kb + i] = lv;
            }
        }
        __syncthreads();

        half8 ah[4], alv[4], bh[4], blv[4];
#pragma unroll
        for (int mt = 0; mt < 4; mt++) {
            ah[mt]  = *(const half8*)&Ah[wm0 + mt * 16 + fm][fq * 8];
            alv[mt] = *(const half8*)&Al[wm0 + mt * 16 + fm][fq * 8];
        }
#pragma unroll
        for (int nt = 0; nt < 4; nt++) {
            bh[nt]  = *(const half8*)&Bh[wn0 + nt * 16 + fm][fq * 8];
            blv[nt] = *(const half8*)&Bl[wn0 + nt * 16 + fm][fq * 8];
        }

        // ---- prefetch next k-tile (flies during MFMA + barrier + next stage) ----
        if (k0 + 32 < K) {
            const int kn = k0 + 32;
            if (TA == 0) {
#pragma unroll
                for (int q = 0; q < 4; q++) {
                    int idx = tid + q * 256;
                    int row = idx >> 3, kq = (idx & 7) * 4;
                    pA4[q] = *(const float4*)&A[(long)(m0 + row) * lda + kn + kq];
                }
            } else {
                int m = tid & 127, kb = (tid >> 7) * 16;
#pragma unroll
                for (int i = 0; i < 16; i++)
                    pAs[i] = A[(long)(kn + kb + i) * lda + m0 + m];
            }
            {
                int n = tid & 127, kb = (tid >> 7) * 16;
#pragma unroll
                for (int i = 0; i < 16; i++)
                    pBs[i] = Bm[(long)(kn + kb + i) * ldb + n0 + n];
            }
        }

#pragma unroll
        for (int mt = 0; mt < 4; mt++) {
#pragma unroll
            for (int nt = 0; nt < 4; nt++) {
                floatx4 a = acc[mt][nt];
                a = __builtin_amdgcn_mfma_f32_16x16x32_f16(alv[mt], bh[nt], a, 0, 0, 0);
                a = __builtin_amdgcn_mfma_f32_16x16x32_f16(ah[mt], blv[nt], a, 0, 0, 0);
                a = __builtin_amdgcn_mfma_f32_16x16x32_f16(ah[mt], bh[nt], a, 0, 0, 0);
                acc[mt][nt] = a;
            }
        }
        __syncthreads();
    }

    float scl = 1.f;
    if (mode == MODE_SCALE) scl = 1.0f / sqrtf(scale[bloc]);

#pragma unroll
    for (int mt = 0; mt < 4; mt++) {
#pragma unroll
        for (int nt = 0; nt < 4; nt++) {
            int gn = n0 + wn0 + nt * 16 + fm;
#pragma unroll
            for (int r = 0; r < 4; r++) {
                int gm = m0 + wm0 + mt * 16 + fq * 4 + r;
                float a = acc[mt][nt][r];
                float* cp = C + (long)gm * ldc + gn;
                float v = a;
                if (mode == MODE_COV)      v = a * (1.0f / 512.0f) + ((gm == gn) ? 1e-5f : 0.f);
                else if (mode == MODE_SCALE) v = a * scl;
                else if (mode == MODE_ACC) v = a + *cp;
                *cp = v;
                if (sym && ti != tj) {
                    float* cq = C + (long)gn * ldc + gm;
                    float vq = v;
                    if (mode == MODE_ACC) vq = a + *cq;
                    *cq = vq;
                }
            }
        }
    }
}

// ---------------- Frobenius norm per batch (dual: 128 blocks, 2 sources) ----------
__global__ __launch_bounds__(256)
void frob_kernel(const float* __restrict__ Cm1, const float* __restrict__ Cm2,
                 float* __restrict__ nrm)
{
    int b = blockIdx.x;
    const float* p = (b < BATCH) ? (Cm1 + (long)b * ND * ND)
                                 : (Cm2 + (long)(b - BATCH) * ND * ND);
    float s = 0.f;
    for (int i = threadIdx.x; i < ND * ND; i += 256) { float v = p[i]; s += v * v; }
    __shared__ float red[256];
    red[threadIdx.x] = s; __syncthreads();
    for (int off = 128; off > 0; off >>= 1) {
        if (threadIdx.x < off) red[threadIdx.x] += red[threadIdx.x + off];
        __syncthreads();
    }
    if (threadIdx.x == 0) nrm[b] = sqrtf(red[0]);
}

// ---------------- M0 = C/normC (in place), Z1 = T0 = 1.5I - 0.5*M0 ----------------
__global__ __launch_bounds__(256)
void initns_kernel(float* __restrict__ Mb, float* __restrict__ Z, const float* __restrict__ nrm)
{
    const int total = BATCH * ND * ND;
    for (int idx = blockIdx.x * 256 + threadIdx.x; idx < total; idx += gridDim.x * 256) {
        int b = idx / (ND * ND);
        int rem = idx - b * (ND * ND);
        int r = rem / ND, c = rem - r * ND;
        float v = Mb[idx] / nrm[b];
        Mb[idx] = v;
        Z[idx] = ((r == c) ? 1.5f : 0.f) - 0.5f * v;
    }
}

// ---------------- G += Gt (vectorized elementwise add) ----------------
__global__ __launch_bounds__(256)
void addg_kernel(float* __restrict__ G, const float* __restrict__ Gt)
{
    const long total4 = (long)BATCH * ND * ND / 4;
    for (long idx = (long)blockIdx.x * 256 + threadIdx.x; idx < total4;
         idx += (long)gridDim.x * 256) {
        floatx4 a = *((const floatx4*)G + idx);
        floatx4 b = *((const floatx4*)Gt + idx);
        a += b;
        *((floatx4*)G + idx) = a;
    }
}

// ---------------- block reduction over 768 threads ----------------
__device__ __forceinline__ float bred768(float v, float* red12, int t)
{
#pragma unroll
    for (int off = 32; off > 0; off >>= 1) v += __shfl_down(v, off);
    if ((t & 63) == 0) red12[t >> 6] = v;
    __syncthreads();
    float r = 0.f;
#pragma unroll
    for (int i = 0; i < 12; i++) r += red12[i];
    __syncthreads();
    return r;
}

// ---------------- Blocked Householder tridiagonalization: panel kernel ----------
// Full 64-batch launch (the 32-batch L2-split was a measured regression: it cut
// FETCH 330->9 MB but halved active CUs -> 2x255us > 1x343us). The matvec keeps
// 16 rows of dwordx4 loads in flight per thread (two back-to-back 8-row FMA
// statements, bit-identical accumulation) to push the 64-CU HBM/L2 pull rate.
__global__ __launch_bounds__(768)
void tridiag_panel(float* __restrict__ Gall, float* __restrict__ dA,
                   float* __restrict__ eA, float* __restrict__ tauA,
                   float* __restrict__ Wgall, int k0)
{
    int b = blockIdx.x;
    float* A = Gall + (long)b * ND * ND;
    float* Wg = Wgall + (long)b * (PNB * ND);
    float* d = dA + b * ND; float* e = eA + b * ND; float* tau = tauA + b * ND;
    const int t = threadIdx.x;
    const int h = (t >= ND) ? 1 : 0;
    const int c = t - h * ND;            // 0..383
    const int g = t % 96;                // column quad (4 cols)
    const int s = t / 96;                // row slice 0..7
    __shared__ float Ul[PNB][ND];        // 48 KiB  (u vectors, columns k+1..383)
    __shared__ float Wl[PNB][ND];        // 48 KiB  (w vectors, columns k+1..383)
    __shared__ float u_s[ND];
    __shared__ float pp4s[8][392];
    __shared__ float al[PNB], be[PNB];
    __shared__ float red12[12];
    __shared__ float s_tau;

    const int jcnt = min(PNB, ND - 2 - k0);

    for (int j = 0; j < jcnt; j++) {
        const int k = k0 + j;
        const int m = ND - 1 - k;
        float x = 0.f;
        if (!h && c < m) {
            const int kc = (k + 1) + c;
            x = A[(long)k * ND + kc];
#pragma unroll 4
            for (int l = 0; l < j; l++) {
                x -= Ul[l][k] * Wl[l][kc] + Wl[l][k] * Ul[l][kc];
            }
            u_s[c] = x;
        }
        float sigma = bred768(x * x, red12, t);
        if (t == 0) {
            float v0 = u_s[0];
            float normx = sqrtf(sigma);
            float alpha = (v0 >= 0.f) ? -normx : normx;
            float denom = sigma - alpha * v0;
            float tk = (denom > 1e-30f) ? 1.f / denom : 0.f;
            s_tau = tk;
            float diag = A[(long)k * ND + k];
            for (int l = 0; l < j; l++) diag -= 2.f * Ul[l][k] * Wl[l][k];
            e[k] = alpha; tau[k] = tk; d[k] = diag;
            u_s[0] = v0 - alpha;
        }
        __syncthreads();
        const float tk = s_tau;

        // ---- matvec over the clean trailing block: dwordx4, 8-way row split,
        //      16 rows in flight per thread ----
        const int kk4 = (k + 1) & ~3;
        const int off = (k + 1) - kk4;
        const int ncol4 = 96 - (kk4 >> 2);
        if (g < ncol4) {
            const int ri0 = (m * s) >> 3;
            const int ri1 = (m * (s + 1)) >> 3;
            const float* base = A + (long)(k + 1) * ND + kk4 + 4 * g;
            floatx4 p4 = (floatx4){0.f, 0.f, 0.f, 0.f};
            int i = ri0;
            for (; i + 16 <= ri1; i += 16) {
                floatx4 a0 = *(const floatx4*)&base[(long)(i    ) * ND];
                floatx4 a1 = *(const floatx4*)&base[(long)(i + 1) * ND];
                floatx4 a2 = *(const floatx4*)&base[(long)(i + 2) * ND];
                floatx4 a3 = *(const floatx4*)&base[(long)(i + 3) * ND];
                floatx4 a4 = *(const floatx4*)&base[(long)(i + 4) * ND];
                floatx4 a5 = *(const floatx4*)&base[(long)(i + 5) * ND];
                floatx4 a6 = *(const floatx4*)&base[(long)(i + 6) * ND];
                floatx4 a7 = *(const floatx4*)&base[(long)(i + 7) * ND];
                floatx4 b0 = *(const floatx4*)&base[(long)(i + 8) * ND];
                floatx4 b1 = *(const floatx4*)&base[(long)(i + 9) * ND];
                floatx4 b2 = *(const floatx4*)&base[(long)(i + 10) * ND];
                floatx4 b3 = *(const floatx4*)&base[(long)(i + 11) * ND];
                floatx4 b4 = *(const floatx4*)&base[(long)(i + 12) * ND];
                floatx4 b5 = *(const floatx4*)&base[(long)(i + 13) * ND];
                floatx4 b6 = *(const floatx4*)&base[(long)(i + 14) * ND];
                floatx4 b7 = *(const floatx4*)&base[(long)(i + 15) * ND];
                p4 += a0 * u_s[i]     + a1 * u_s[i + 1] + a2 * u_s[i + 2] + a3 * u_s[i + 3]
                    + a4 * u_s[i + 4] + a5 * u_s[i + 5] + a6 * u_s[i + 6] + a7 * u_s[i + 7];
                p4 += b0 * u_s[i + 8] + b1 * u_s[i + 9] + b2 * u_s[i + 10] + b3 * u_s[i + 11]
                    + b4 * u_s[i + 12] + b5 * u_s[i + 13] + b6 * u_s[i + 14] + b7 * u_s[i + 15];
            }
            for (; i + 8 <= ri1; i += 8) {
                floatx4 a0 = *(const floatx4*)&base[(long)(i    ) * ND];
                floatx4 a1 = *(const floatx4*)&base[(long)(i + 1) * ND];
                floatx4 a2 = *(const floatx4*)&base[(long)(i + 2) * ND];
                floatx4 a3 = *(const floatx4*)&base[(long)(i + 3) * ND];
                floatx4 a4 = *(const floatx4*)&base[(long)(i + 4) * ND];
                floatx4 a5 = *(const floatx4*)&base[(long)(i + 5) * ND];
                floatx4 a6 = *(const floatx4*)&base[(long)(i + 6) * ND];
                floatx4 a7 = *(const floatx4*)&base[(long)(i + 7) * ND];
                p4 += a0 * u_s[i]     + a1 * u_s[i + 1] + a2 * u_s[i + 2] + a3 * u_s[i + 3]
                    + a4 * u_s[i + 4] + a5 * u_s[i + 5] + a6 * u_s[i + 6] + a7 * u_s[i + 7];
            }
            for (; i < ri1; i++) {
                floatx4 a0 = *(const floatx4*)&base[(long)i * ND];
                p4 += a0 * u_s[i];
            }
            *(floatx4*)&pp4s[s][4 * g] = p4;
        }
        // wave-parallel dots from LDS panels: al[l] = w_l . u, be[l] = u_l . u
        {
            int wv = t >> 6, ln = t & 63;
            for (int l = wv; l < j; l += 12) {
                float sa = 0.f, sb = 0.f;
                const float* wrow = &Wl[l][k + 1];
                const float* urow = &Ul[l][k + 1];
                for (int i = ln; i < m; i += 64) { sa += wrow[i] * u_s[i]; sb += urow[i] * u_s[i]; }
#pragma unroll
                for (int off2 = 32; off2 > 0; off2 >>= 1) {
                    sa += __shfl_down(sa, off2); sb += __shfl_down(sb, off2);
                }
                if (ln == 0) { al[l] = sa; be[l] = sb; }
            }
        }
        __syncthreads();
        float contrib = 0.f, pc = 0.f;
        if (!h && c < m) {
            int ca = c + off;
            pc = pp4s[0][ca] + pp4s[1][ca] + pp4s[2][ca] + pp4s[3][ca]
               + pp4s[4][ca] + pp4s[5][ca] + pp4s[6][ca] + pp4s[7][ca];
            const int kc = (k + 1) + c;
#pragma unroll 4
            for (int l = 0; l < j; l++) {
                pc -= al[l] * Ul[l][kc] + be[l] * Wl[l][kc];
            }
            pc *= tk;
            contrib = u_s[c] * pc;
        }
        float dotup = bred768(contrib, red12, t);
        float sc = 0.5f * tk * dotup;
        if (!h && c < m) {
            const int kc = (k + 1) + c;
            float uv = u_s[c];
            float w = pc - sc * uv;
            Wl[j][kc] = w;
            Ul[j][kc] = uv;
            Wg[j * ND + kc] = w;
            A[(long)k * ND + kc] = uv;
        }
        __syncthreads();
    }
    if (k0 + PNB >= ND - 2 && t == 0) {
        float d0 = A[(long)(ND - 2) * ND + (ND - 2)];
        float e0 = A[(long)(ND - 2) * ND + (ND - 1)];
        float d1 = A[(long)(ND - 1) * ND + (ND - 1)];
        for (int l = 0; l < jcnt; l++) {
            float u0 = A[(long)(k0 + l) * ND + (ND - 2)];
            float u1 = A[(long)(k0 + l) * ND + (ND - 1)];
            float w0 = Wg[l * ND + (ND - 2)];
            float w1 = Wg[l * ND + (ND - 1)];
            d0 -= 2.f * u0 * w0;
            e0 -= u0 * w1 + w0 * u1;
            d1 -= 2.f * u1 * w1;
        }
        d[ND - 2] = d0; d[ND - 1] = d1; e[ND - 2] = e0;
        e[ND - 1] = 0.f; tau[ND - 2] = 0.f; tau[ND - 1] = 0.f;
    }
}

// ---------------- trailing update: A -= U W^T + W U^T (full device, 32x32 tiles) ----
__global__ __launch_bounds__(256)
void syr2k_update(float* __restrict__ Gall, const float* __restrict__ Wgall, int k0)
{
    const int k1 = k0 + PNB;
    const int tiles = (ND - k1) >> 5;
    int b = blockIdx.y;
    int ti = blockIdx.x / tiles, tj = blockIdx.x % tiles;
    int i0 = k1 + ti * 32, c0 = k1 + tj * 32;
    float* A = Gall + (long)b * ND * ND;
    const float* Wg = Wgall + (long)b * (PNB * ND);

    __shared__ float Us[PNB][36], Ws[PNB][36], Uc[PNB][36], Wc[PNB][36];
    int t = threadIdx.x;
    for (int q = t; q < PNB * 8; q += 256) {
        int l = q >> 3, c4 = (q & 7) * 4;
        *(float4*)&Us[l][c4] = *(const float4*)&A[(long)(k0 + l) * ND + i0 + c4];
        *(float4*)&Ws[l][c4] = *(const float4*)&Wg[l * ND + i0 + c4];
        *(float4*)&Uc[l][c4] = *(const float4*)&A[(long)(k0 + l) * ND + c0 + c4];
        *(float4*)&Wc[l][c4] = *(const float4*)&Wg[l * ND + c0 + c4];
    }
    __syncthreads();
    int tr = t >> 4, tc = t & 15;
    float acc00 = 0.f, acc01 = 0.f, acc10 = 0.f, acc11 = 0.f;
#pragma unroll 4
    for (int l = 0; l < PNB; l++) {
        float ua0 = Us[l][tr * 2], ua1 = Us[l][tr * 2 + 1];
        float wa0 = Ws[l][tr * 2], wa1 = Ws[l][tr * 2 + 1];
        float ub0 = Uc[l][tc * 2], ub1 = Uc[l][tc * 2 + 1];
        float wb0 = Wc[l][tc * 2], wb1 = Wc[l][tc * 2 + 1];
        acc00 += ua0 * wb0 + wa0 * ub0;
        acc01 += ua0 * wb1 + wa0 * ub1;
        acc10 += ua1 * wb0 + wa1 * ub0;
        acc11 += ua1 * wb1 + wa1 * ub1;
    }
    {
        float* r0 = &A[(long)(i0 + tr * 2) * ND + c0 + tc * 2];
        float* r1 = r0 + ND;
        float2 o0 = *(const float2*)r0, o1 = *(const float2*)r1;
        o0.x -= acc00; o0.y -= acc01;
        o1.x -= acc10; o1.y -= acc11;
        *(float2*)r0 = o0; *(float2*)r1 = o1;
    }
}

// ---------------- Sturm 64-way multisection: top-24 eigenvalues ----------------
__global__ __launch_bounds__(64)
void eigvals_kernel(const float* __restrict__ dA, const float* __restrict__ eA,
                    float* __restrict__ lamA)
{
    int blk = blockIdx.x;
    int b = blk / RK, eig = blk % RK;
    int t = threadIdx.x;   // 64 threads
    __shared__ float2 de[ND];
    __shared__ float d_s[ND], ea[ND], red[64];
    for (int i = t; i < ND; i += 64) {
        float dv = dA[b * ND + i];
        float ev = eA[b * ND + i];
        float ep = (i > 0) ? eA[b * ND + i - 1] : 0.f;
        d_s[i] = dv; ea[i] = fabsf(ev);
        de[i] = make_float2(dv, ep * ep + 1e-38f);
    }
    __syncthreads();
    float lo = 1e30f, hi = -1e30f;
    for (int i = t; i < ND; i += 64) {
        float r = ea[i] + ((i > 0) ? ea[i - 1] : 0.f);
        lo = fminf(lo, d_s[i] - r); hi = fmaxf(hi, d_s[i] + r);
    }
    red[t] = lo; __syncthreads();
    for (int off = 32; off > 0; off >>= 1) {
        if (t < off) red[t] = fminf(red[t], red[t + off]);
        __syncthreads();
    }
    lo = red[0]; __syncthreads();
    red[t] = hi; __syncthreads();
    for (int off = 32; off > 0; off >>= 1) {
        if (t < off) red[t] = fmaxf(red[t], red[t + off]);
        __syncthreads();
    }
    hi = red[0];
    __syncthreads();

    const int idx = ND - 1 - eig;      // ascending index (eig=0 -> largest)
    float a = lo, c = hi;
    for (int it = 0; it < 8; it++) {
        const float w = (c - a) * (1.f / 65.f);
        const float mid = a + w * (float)(t + 1);
        int cnt = 0;
        float qinv = 0.f;
        for (int i = 0; i < ND; i += 8) {
            float2 v0 = de[i    ], v1 = de[i + 1], v2 = de[i + 2], v3 = de[i + 3];
            float2 v4 = de[i + 4], v5 = de[i + 5], v6 = de[i + 6], v7 = de[i + 7];
            float q;
            q = (v0.x - mid) - v0.y * qinv; cnt += (q < 0.f); qinv = __builtin_amdgcn_rcpf(q);
            q = (v1.x - mid) - v1.y * qinv; cnt += (q < 0.f); qinv = __builtin_amdgcn_rcpf(q);
            q = (v2.x - mid) - v2.y * qinv; cnt += (q < 0.f); qinv = __builtin_amdgcn_rcpf(q);
            q = (v3.x - mid) - v3.y * qinv; cnt += (q < 0.f); qinv = __builtin_amdgcn_rcpf(q);
            q = (v4.x - mid) - v4.y * qinv; cnt += (q < 0.f); qinv = __builtin_amdgcn_rcpf(q);
            q = (v5.x - mid) - v5.y * qinv; cnt += (q < 0.f); qinv = __builtin_amdgcn_rcpf(q);
            q = (v6.x - mid) - v6.y * qinv; cnt += (q < 0.f); qinv = __builtin_amdgcn_rcpf(q);
            q = (v7.x - mid) - v7.y * qinv; cnt += (q < 0.f); qinv = __builtin_amdgcn_rcpf(q);
        }
        unsigned long long over = __ballot(cnt > idx);   // monotone in lane
        if (over == 0ULL) {
            a = a + w * 64.f;                            // eigenvalue in (mid_63, c]
        } else {
            int f = __ffsll((long long)over) - 1;        // first lane with cnt > idx
            float na = a + w * (float)f;                 // mid_{f-1} (f==0 -> a)
            float nc = a + w * (float)(f + 1);           // mid_f
            a = na; c = nc;
        }
    }
    if (t == 0) lamA[b * RK + eig] = 0.5f * (a + c);
}

// ---------------- tridiagonal inverse iteration (pivoted LU, all in LDS) ----------
__global__ __launch_bounds__(64)
void invit_kernel(const float* __restrict__ dA, const float* __restrict__ eA,
                  const float* __restrict__ lamA, float* __restrict__ scr)
{
    int b = blockIdx.x, t = threadIdx.x;
    __shared__ float d[ND], e[ND];
    __shared__ float ua[ND][RK], ub[ND][RK], uc[ND][RK];
    __shared__ float y[ND][RK];
    for (int i = t; i < ND; i += 64) { d[i] = dA[b * ND + i]; e[i] = eA[b * ND + i]; }
    __syncthreads();
    if (t >= RK) return;
    const int s = b * RK + t;
    float* yout = scr + 5L * ND * SSTR;
    const float lam = lamA[s];

    for (int pass = 0; pass < 2; pass++) {
        if (pass == 0) {
            for (int i = 0; i < ND; i++) {
                unsigned h = ((unsigned)i * 1103515245u) ^ ((unsigned)s * 747796405u);
                h *= 2654435769u; h ^= h >> 16;
                y[i][t] = ((float)(h & 0xFFFFu) * (1.f / 65536.f)) - 0.5f;
            }
        }
        float ai = d[0] - lam;
        float bc = e[0];
        float ycur = y[0][t];
        for (int i = 0; i < ND - 1; i++) {
            float sub = e[i];
            float dn = d[i + 1] - lam;
            float en = (i + 1 < ND - 1) ? e[i + 1] : 0.f;
            float ynext = y[i + 1][t];
            if (fabsf(ai) >= fabsf(sub)) {
                float aa = (ai == 0.f) ? 1e-20f : ai;
                float mlt = sub / aa;
                ua[i][t] = aa; ub[i][t] = bc; uc[i][t] = 0.f;
                y[i][t] = ycur;
                ycur = ynext - mlt * ycur;
                ai = dn - mlt * bc;
                bc = en;
            } else {
                float mlt = ai / sub;
                ua[i][t] = sub; ub[i][t] = dn; uc[i][t] = en;
                y[i][t] = ynext;
                ycur = ycur - mlt * ynext;
                ai = bc - mlt * dn;
                bc = -mlt * en;
            }
        }
        float uaN = (ai == 0.f) ? 1e-20f : ai;
        float x1 = ycur / uaN;           // x[ND-1]
        y[ND - 1][t] = x1;
        float x2 = x1;
        {
            float xm = (y[ND - 2][t] - ub[ND - 2][t] * x1) / ua[ND - 2][t];
            y[ND - 2][t] = xm; x2 = x1; x1 = xm;
        }
        for (int i = ND - 3; i >= 0; i--) {
            float xi = (y[i][t] - ub[i][t] * x1 - uc[i][t] * x2) / ua[i][t];
            y[i][t] = xi; x2 = x1; x1 = xi;
        }
        float nn = 0.f;
        for (int i = 0; i < ND; i++) { float v = y[i][t]; nn += v * v; }
        float inv = (nn > 0.f) ? 1.f / sqrtf(nn) : 0.f;
        for (int i = 0; i < ND; i++) y[i][t] *= inv;
    }
    for (int i = 0; i < ND; i++) yout[(long)i * SSTR + s] = y[i][t];
}

// ---------------- fast MGS + register-pipelined Householder back-transform ------
__global__ __launch_bounds__(384)
void orthbt_kernel(const float* __restrict__ xx, const float* __restrict__ Gall,
                   const float* __restrict__ tauA, float* __restrict__ Qout)
{
    int b = blockIdx.x, t = threadIdx.x;   // 384 threads
    __shared__ float Y[ND][RK + 1];
    __shared__ float red[ND];
    __shared__ float dts[RK];
    __shared__ float tls[ND];

    for (int j = 0; j < RK; j++) Y[t][j] = xx[(long)t * SSTR + b * RK + j];
    tls[t] = tauA[b * ND + t];
    __syncthreads();

    const int mcol = t % RK;      // 0..23
    const int msl  = t / RK;      // 0..15 (24-row slices)
    const int r0m  = msl * 24;
    for (int j = 0; j < RK; j++) {
        float pp = 0.f;
        for (int i = 0; i < 24; i++) {
            pp += Y[r0m + i][j] * Y[r0m + i][mcol];
        }
        red[mcol * 16 + msl] = pp;
        __syncthreads();
        if (t < RK) {
            float ssum = 0.f;
            for (int q = 0; q < 16; q++) ssum += red[t * 16 + q];
            dts[t] = ssum;
        }
        __syncthreads();
        float nv = dts[j];
        float inv = (nv > 1e-30f) ? (1.f / sqrtf(nv)) : 0.f;
        if (mcol > j) {
            float coef = dts[mcol] * inv * inv;
            for (int i = 0; i < 24; i++) Y[r0m + i][mcol] -= coef * Y[r0m + i][j];
        } else if (mcol == j) {
            for (int i = 0; i < 24; i++) Y[r0m + i][j] *= inv;
        }
        __syncthreads();
    }

    const int wv = t >> 6, ln = t & 63;
    float yr[4][6];
#pragma unroll
    for (int cc = 0; cc < 4; cc++)
#pragma unroll
        for (int q = 0; q < 6; q++)
            yr[cc][q] = Y[ln + 64 * q][4 * wv + cc];
    __syncthreads();

    const float* A = Gall + (long)b * ND * ND;
    float un[6];
    {
        const int k = ND - 3;
#pragma unroll
        for (int q = 0; q < 6; q++) un[q] = A[(long)k * ND + ln + 64 * q];
    }
    for (int k = ND - 3; k >= 0; k--) {
        float cu[6];
#pragma unroll
        for (int q = 0; q < 6; q++) {
            int r = ln + 64 * q;
            cu[q] = (r > k) ? un[q] : 0.f;
        }
        if (k > 0) {
#pragma unroll
            for (int q = 0; q < 6; q++) un[q] = A[(long)(k - 1) * ND + ln + 64 * q];
        }
        const float tk = tls[k];
#pragma unroll
        for (int cc = 0; cc < 4; cc++) {
            float p = 0.f;
#pragma unroll
            for (int q = 0; q < 6; q++) p += cu[q] * yr[cc][q];
#pragma unroll
            for (int off = 32; off > 0; off >>= 1) p += __shfl_xor(p, off);
            float sv = tk * p;
#pragma unroll
            for (int q = 0; q < 6; q++) yr[cc][q] -= sv * cu[q];
        }
    }

#pragma unroll
    for (int cc = 0; cc < 4; cc++)
#pragma unroll
        for (int q = 0; q < 6; q++)
            Y[ln + 64 * q][4 * wv + cc] = yr[cc][q];
    __syncthreads();
    for (int l = t; l < ND * RK; l += 384) {
        int i = l / RK, j = l - i * RK;
        Qout[(long)b * ND * RK + l] = Y[i][j];
    }
}

// ---------------- Sp = X_w @ Q (dual: grid.y = 128, two source/dest sets) --------
__global__ __launch_bounds__(256)
void proj_kernel(const float* __restrict__ Xw1, const float* __restrict__ Q1,
                 float* __restrict__ P1,
                 const float* __restrict__ Xw2, const float* __restrict__ Q2,
                 float* __restrict__ P2)
{
    const int by = blockIdx.y;
    int b; const float* Xw; const float* Qall; float* P;
    if (by < BATCH) { b = by; Xw = Xw1; Qall = Q1; P = P1; }
    else            { b = by - BATCH; Xw = Xw2; Qall = Q2; P = P2; }
    int r0 = blockIdx.x * 256;
    __shared__ float Qs[ND][RK + 1];
    const float* Q = Qall + (long)b * ND * RK;
    for (int l = threadIdx.x; l < ND * RK; l += 256) {
        int i = l / RK, j = l - i * RK;
        Qs[i][j] = Q[l];
    }
    __syncthreads();
    int r = r0 + threadIdx.x;
    const float* X = Xw + (long)b * NR * ND + (long)r * ND;
    float acc[RK];
#pragma unroll
    for (int j = 0; j < RK; j++) acc[j] = 0.f;
    for (int k = 0; k < ND; k++) {
        float xv = X[k];
#pragma unroll
        for (int j = 0; j < RK; j++) acc[j] += xv * Qs[k][j];
    }
    float* Pr = P + (long)b * NR * RK + (long)r * RK;
#pragma unroll
    for (int j = 0; j < RK; j++) Pr[j] = acc[j];
}

// ---------------- M = Sp^T Tp ; R = polar(M) via Newton-Schulz ; write R - I ----------------
__global__ __launch_bounds__(256)
void polar_kernel(const float* __restrict__ Sp, const float* __restrict__ Tp,
                  float* __restrict__ RmI)
{
    int b = blockIdx.x, t = threadIdx.x;
    __shared__ float Sb[128][RK + 1], Tb[128][RK + 1];
    __shared__ float Xm[RK][RK + 1], Bm[RK][RK + 1], Mm[RK][RK + 1];
    __shared__ float red[256];

    float accM[3] = {0.f, 0.f, 0.f};
    for (int c = 0; c < 4; c++) {
        for (int l = t; l < 128 * RK; l += 256) {
            int row = l / RK, colj = l - row * RK;
            Sb[row][colj] = Sp[(long)b * NR * RK + (long)(c * 128 + row) * RK + colj];
            Tb[row][colj] = Tp[(long)b * NR * RK + (long)(c * 128 + row) * RK + colj];
        }
        __syncthreads();
        for (int q = 0; q < 3; q++) {
            int e = t + q * 256;
            if (e < RK * RK) {
                int r = e / RK, s2 = e - r * RK;
                float a = 0.f;
                for (int n = 0; n < 128; n++) a += Sb[n][r] * Tb[n][s2];
                accM[q] += a;
            }
        }
        __syncthreads();
    }
    float ss = 0.f;
    for (int q = 0; q < 3; q++) {
        int e = t + q * 256;
        if (e < RK * RK) {
            int r = e / RK, s2 = e - r * RK;
            Mm[r][s2] = accM[q];
            ss += accM[q] * accM[q];
        }
    }
    red[t] = ss; __syncthreads();
    for (int off = 128; off > 0; off >>= 1) {
        if (t < off) red[t] += red[t + off];
        __syncthreads();
    }
    float fro = sqrtf(red[0]);
    float inv = (fro > 1e-30f) ? 1.f / fro : 0.f;
    for (int q = 0; q < 3; q++) {
        int e = t + q * 256;
        if (e < RK * RK) { int r = e / RK, s2 = e - r * RK; Xm[r][s2] = Mm[r][s2] * inv; }
    }
    __syncthreads();
    for (int it = 0; it < POLAR_ITERS; it++) {
        for (int q = 0; q < 3; q++) {
            int e = t + q * 256;
            if (e < RK * RK) {
                int r = e / RK, s2 = e - r * RK;
                float a = 0.f;
                for (int k = 0; k < RK; k++) a += Xm[k][r] * Xm[k][s2];
                Bm[r][s2] = a;
            }
        }
        __syncthreads();
        for (int q = 0; q < 3; q++) {
            int e = t + q * 256;
            if (e < RK * RK) {
                int r = e / RK, s2 = e - r * RK;
                float a = 0.f;
                for (int k = 0; k < RK; k++) a += Xm[r][k] * Bm[k][s2];
                Mm[r][s2] = 1.5f * Xm[r][s2] - 0.5f * a;
            }
        }
        __syncthreads();
        for (int q = 0; q < 3; q++) {
            int e = t + q * 256;
            if (e < RK * RK) { int r = e / RK, s2 = e - r * RK; Xm[r][s2] = Mm[r][s2]; }
        }
        __syncthreads();
    }
    for (int q = 0; q < 3; q++) {
        int e = t + q * 256;
        if (e < RK * RK) {
            int r = e / RK, s2 = e - r * RK;
            RmI[(long)b * RK * RK + e] = Xm[r][s2] - ((r == s2) ? 1.f : 0.f);
        }
    }
}

// ---------------- aligned = S_w + Sp (R-I) Q^T  (writes d_out) ----------------
__global__ __launch_bounds__(256)
void align_kernel(const float* __restrict__ Sw, const float* __restrict__ Sp,
                  const float* __restrict__ RmI, const float* __restrict__ Qall,
                  float* __restrict__ out)
{
    int b = blockIdx.y;
    int r0 = blockIdx.x * 64;
    int t = threadIdx.x;
    __shared__ float Qs[ND][RK + 1];
    __shared__ float Rm[RK][RK + 1];
    __shared__ float Ss[64][RK + 1];
    __shared__ float W[64][RK + 1];

    for (int l = t; l < ND * RK; l += 256) {
        int i = l / RK, j = l - i * RK;
        Qs[i][j] = Qall[(long)b * ND * RK + l];
    }
    for (int l = t; l < RK * RK; l += 256) {
        int i = l / RK, j = l - i * RK;
        Rm[i][j] = RmI[(long)b * RK * RK + l];
    }
    for (int l = t; l < 64 * RK; l += 256) {
        int i = l / RK, j = l - i * RK;
        Ss[i][j] = Sp[(long)b * NR * RK + (long)(r0 + i) * RK + j];
    }
    __syncthreads();
    for (int l = t; l < 64 * RK; l += 256) {
        int r = l / RK, j = l - r * RK;
        float a = 0.f;
        for (int k = 0; k < RK; k++) a += Ss[r][k] * Rm[k][j];
        W[r][j] = a;
    }
    __syncthreads();
    for (int r = 0; r < 64; r++) {
        for (int c = t; c < ND; c += 256) {
            float a = Sw[(long)b * NR * ND + (long)(r0 + r) * ND + c];
            float s2 = 0.f;
#pragma unroll
            for (int j = 0; j < RK; j++) s2 += W[r][j] * Qs[c][j];
            out[(long)b * NR * ND + (long)(r0 + r) * ND + c] = a + s2;
        }
    }
}

// ---------------- mean cosine ----------------
__global__ __launch_bounds__(256)
void cos_kernel(const float* __restrict__ out, const float* __restrict__ tgt,
                float* __restrict__ acc)
{
    int row = blockIdx.x * 4 + (threadIdx.x >> 6);
    int lane = threadIdx.x & 63;
    const float* a = out + (long)row * ND;
    const float* tg = tgt + (long)row * ND;
    float sd = 0.f, sa = 0.f, st = 0.f;
    for (int i = lane; i < ND; i += 64) {
        float av = a[i], tv = tg[i];
        sd += av * tv; sa += av * av; st += tv * tv;
    }
#pragma unroll
    for (int off = 32; off > 0; off >>= 1) {
        sd += __shfl_down(sd, off); sa += __shfl_down(sa, off); st += __shfl_down(st, off);
    }
    __shared__ float part[4];
    if (lane == 0) part[threadIdx.x >> 6] = sd / (sqrtf(sa) * sqrtf(st) + 1e-8f);
    __syncthreads();
    if (threadIdx.x == 0) atomicAdd(acc, part[0] + part[1] + part[2] + part[3]);
}

__global__ void finalize_kernel(const float* __restrict__ acc, float* __restrict__ out)
{
    out[0] = acc[0] / 32768.0f;
}

// ---------------- host ----------------
static inline void launch_gd(int TA,
    const float* A1p, const float* B1p, float* C1p, int mode1, const float* sc1, int tm1,
    const float* A2p, const float* B2p, float* C2p, int mode2, const float* sc2, int tm2,
    int nbat, int M, int N, int K, long sA, long sB, long sC,
    int lda, int ldb, int ldc, int sym, hipStream_t stream)
{
    int tiles;
    if (sym) { int tn = N >> 7; tiles = tn * (tn + 1) / 2; }
    else tiles = (M / 128) * (N / 128);
    dim3 grid(tiles, nbat);
    if (TA)
        gemm_kernel<1><<<grid, dim3(256), 0, stream>>>(A1p, B1p, C1p, A2p, B2p, C2p,
            M, N, K, sA, sB, sC, lda, ldb, ldc, mode1, sc1, mode2, sc2, sym, tm1, tm2);
    else
        gemm_kernel<0><<<grid, dim3(256), 0, stream>>>(A1p, B1p, C1p, A2p, B2p, C2p,
            M, N, K, sA, sB, sC, lda, ldb, ldc, mode1, sc1, mode2, sc2, sym, tm1, tm2);
}

static inline void launch_g1(int TA, const float* Ap, const float* Bp, float* Cp,
    int mode, const float* sc, int tm,
    int M, int N, int K, long sA, long sB, long sC,
    int lda, int ldb, int ldc, int sym, hipStream_t stream)
{
    launch_gd(TA, Ap, Bp, Cp, mode, sc, tm, Ap, Bp, Cp, mode, sc, tm,
              BATCH, M, N, K, sA, sB, sC, lda, ldb, ldc, sym, stream);
}

extern "C" void kernel_launch(void* const* d_in, const int* in_sizes, int n_in,
                              void* d_out, int out_size, void* d_ws, size_t ws_size,
                              hipStream_t stream)
{
    const float* src = (const float*)d_in[0];
    const float* tgt = (const float*)d_in[1];
    float* out = (float*)d_out;
    float* ws = (float*)d_ws;

    float* A0 = ws;
    float* A3 = ws + 3 * SZC;
    float* A4 = ws + 4 * SZC;
    float* S5 = ws + 5 * SZC;
    float* nrm_s = S5;                     // nrm_t = nrm_s + 64 (contiguous for dual frob)
    float* nrm_t = S5 + 64;
    float* dd = S5 + 128;
    float* ee = dd + BATCH * ND;
    float* tt = ee + BATCH * ND;
    float* lam = tt + BATCH * ND;
    float* accp = lam + BATCH * RK;

    float* Tm = out;                       // square scratch in d_out
    float* SW = A0;                        // [0, 12.58M) rect
    float* TW = A0 + (long)BATCH * NR * ND;// [12.58M, 25.2M) rect
    float* C1 = TW;                        // square M_t buffer (dead before TW written)
    float* G  = A3;
    float* scr = A4;                       // 6 * 384 * 1536
    float* Qp  = A4 + 6L * ND * SSTR;
    float* Spp = Qp + (long)BATCH * ND * RK;
    float* Tpp = Spp + (long)BATCH * NR * RK;
    float* Rp  = Tpp + (long)BATCH * NR * RK;
    float* Wg  = Rp + (long)BATCH * RK * RK;           // PNB*ND per batch
    float* yarr = scr + 5L * ND * SSTR;

    const long sXin = (long)NR * ND;     // 196608
    const long sSq  = (long)ND * ND;     // 147456

    // ==== dual covariance: cov_s -> A3, cov_t -> C1 ====
    launch_gd(1, src, src, A3, MODE_COV, nullptr, 0,
                 tgt, tgt, C1, MODE_COV, nullptr, 0,
              128, ND, ND, NR, sXin, sXin, sSq, ND, ND, ND, 1, stream);
    frob_kernel<<<dim3(128), 256, 0, stream>>>(A3, C1, nrm_s);

    // ==== phase S (M-track rotation A3 -> A0 -> A4 -> A3 -> A0; U scratch Tm) ====
    initns_kernel<<<dim3(2048), 256, 0, stream>>>(A3, A4, nrm_s);   // M0=A3, Z1=A4
    launch_g1(0, A3, A3, Tm, MODE_PLAIN, nullptr, 3, ND, ND, ND, sSq, sSq, sSq, ND, ND, ND, 1, stream);
    launch_g1(0, A3, Tm, A0, MODE_PLAIN, nullptr, 0, ND, ND, ND, sSq, sSq, sSq, ND, ND, ND, 1, stream);
    launch_gd(0, A0, A4, A3, MODE_PLAIN, nullptr, 1,
                 A0, A0, Tm, MODE_PLAIN, nullptr, 3,
              128, ND, ND, ND, sSq, sSq, sSq, ND, ND, ND, 1, stream);
    launch_g1(0, A0, Tm, A4, MODE_PLAIN, nullptr, 0, ND, ND, ND, sSq, sSq, sSq, ND, ND, ND, 1, stream);
    launch_gd(0, A4, A3, A0, MODE_PLAIN, nullptr, 1,
                 A4, A4, Tm, MODE_PLAIN, nullptr, 3,
              128, ND, ND, ND, sSq, sSq, sSq, ND, ND, ND, 1, stream);
    launch_g1(0, A4, Tm, A3, MODE_PLAIN, nullptr, 0, ND, ND, ND, sSq, sSq, sSq, ND, ND, ND, 1, stream);
    launch_gd(0, A3, A0, A4, MODE_PLAIN, nullptr, 1,
                 A3, A3, Tm, MODE_PLAIN, nullptr, 3,
              128, ND, ND, ND, sSq, sSq, sSq, ND, ND, ND, 1, stream);
    launch_g1(0, A3, Tm, A0, MODE_PLAIN, nullptr, 0, ND, ND, ND, sSq, sSq, sSq, ND, ND, ND, 1, stream);
    launch_g1(0, A0, A4, A3, MODE_PLAIN, nullptr, 1, ND, ND, ND, sSq, sSq, sSq, ND, ND, ND, 1, stream);

    // ==== phase T (M-track C1 -> A4 -> A0 -> C1 -> A4; Z-track A0/C1/A4; U scratch Tm) ====
    initns_kernel<<<dim3(2048), 256, 0, stream>>>(C1, A0, nrm_t);   // M0=C1, Z1=A0
    launch_g1(0, C1, C1, Tm, MODE_PLAIN, nullptr, 3, ND, ND, ND, sSq, sSq, sSq, ND, ND, ND, 1, stream);
    launch_g1(0, C1, Tm, A4, MODE_PLAIN, nullptr, 0, ND, ND, ND, sSq, sSq, sSq, ND, ND, ND, 1, stream);
    launch_gd(0, A4, A0, C1, MODE_PLAIN, nullptr, 1,
                 A4, A4, Tm, MODE_PLAIN, nullptr, 3,
              128, ND, ND, ND, sSq, sSq, sSq, ND, ND, ND, 1, stream);
    launch_g1(0, A4, Tm, A0, MODE_PLAIN, nullptr, 0, ND, ND, ND, sSq, sSq, sSq, ND, ND, ND, 1, stream);
    launch_gd(0, A0, C1, A4, MODE_PLAIN, nullptr, 1,
                 A0, A0, Tm, MODE_PLAIN, nullptr, 3,
              128, ND, ND, ND, sSq, sSq, sSq, ND, ND, ND, 1, stream);
    launch_g1(0, A0, Tm, C1, MODE_PLAIN, nullptr, 0, ND, ND, ND, sSq, sSq, sSq, ND, ND, ND, 1, stream);
    launch_gd(0, C1, A4, A0, MODE_PLAIN, nullptr, 1,
                 C1, C1, Tm, MODE_PLAIN, nullptr, 3,
              128, ND, ND, ND, sSq, sSq, sSq, ND, ND, ND, 1, stream);
    launch_g1(0, C1, Tm, A4, MODE_PLAIN, nullptr, 0, ND, ND, ND, sSq, sSq, sSq, ND, ND, ND, 1, stream);
    launch_g1(0, A4, A0, Tm, MODE_PLAIN, nullptr, 1, ND, ND, ND, sSq, sSq, sSq, ND, ND, ND, 1, stream);

    // ==== dual whiten: SW = src*Z5_s/sqrt(nrm_s), TW = tgt*Z5_t/sqrt(nrm_t) ====
    launch_gd(0, src, A3, SW, MODE_SCALE, nrm_s, 0,
                 tgt, Tm, TW, MODE_SCALE, nrm_t, 0,
              128, NR, ND, ND, sXin, sSq, sXin, ND, ND, ND, 0, stream);

    // ---- dual G: G_s = SW^T SW -> A3, G_t = TW^T TW -> Tm(out); then G += G_t ----
    launch_gd(1, SW, SW, G,  MODE_PLAIN, nullptr, 0,
                 TW, TW, Tm, MODE_PLAIN, nullptr, 0,
              128, ND, ND, NR, sXin, sXin, sSq, ND, ND, ND, 1, stream);
    addg_kernel<<<dim3(2048), 256, 0, stream>>>(G, Tm);

    // ---- blocked tridiagonalization: panels + full-device trailing updates ----
    for (int p = 0; p < ND / PNB; p++) {
        int k0 = p * PNB;
        tridiag_panel<<<dim3(BATCH), 768, 0, stream>>>(G, dd, ee, tt, Wg, k0);
        int k1 = (p + 1) * PNB;
        if (k1 < ND - 2) {
            int tiles = (ND - k1) >> 5;
            syr2k_update<<<dim3(tiles * tiles, BATCH), 256, 0, stream>>>(G, Wg, k0);
        }
    }
    eigvals_kernel<<<dim3(BATCH * RK), 64, 0, stream>>>(dd, ee, lam);
    invit_kernel<<<BATCH, 64, 0, stream>>>(dd, ee, lam, scr);
    orthbt_kernel<<<BATCH, 384, 0, stream>>>(yarr, G, tt, Qp);
    // ---- projections (dual), Procrustes, output ----
    proj_kernel<<<dim3(2, 128), 256, 0, stream>>>(SW, Qp, Spp, TW, Qp, Tpp);
    polar_kernel<<<BATCH, 256, 0, stream>>>(Spp, Tpp, Rp);
    align_kernel<<<dim3(8, BATCH), 256, 0, stream>>>(SW, Spp, Rp, Qp, out);
    hipMemsetAsync((void*)accp, 0, 4, stream);
    cos_kernel<<<dim3(8192), 256, 0, stream>>>(out, tgt, accp);
    finalize_kernel<<<1, 1, 0, stream>>>(accp, out + (long)BATCH * NR * ND);
    (void)in_sizes; (void)n_in; (void)out_size; (void)ws_size;
}